// Round 3
// baseline (808.533 us; speedup 1.0000x reference)
//
#include <hip/hip_runtime.h>
#include <hip/hip_bf16.h>
#include <math.h>

#define NEG_SLOPE 0.2f

// ---------------------------------------------------------------- CSR build
__global__ void degree_kernel(const int* __restrict__ ei, int E, int n,
                              int* __restrict__ deg) {
    int e = blockIdx.x * 256 + threadIdx.x;
    int tot = E + n;
    if (e >= tot) return;
    int d = (e < E) ? ei[E + e] : (e - E);
    atomicAdd(&deg[d], 1);
}

__global__ __launch_bounds__(1024) void scan_block(const int* __restrict__ deg,
                                                   int* __restrict__ row_off,
                                                   int* __restrict__ bsums, int n) {
    __shared__ int tmp[1024];
    int t = threadIdx.x;
    int idx = blockIdx.x * 1024 + t;
    int v = (idx < n) ? deg[idx] : 0;
    tmp[t] = v;
    __syncthreads();
    #pragma unroll
    for (int off = 1; off < 1024; off <<= 1) {
        int x = (t >= off) ? tmp[t - off] : 0;
        __syncthreads();
        tmp[t] += x;
        __syncthreads();
    }
    if (idx < n) row_off[idx] = tmp[t] - v;
    if (t == 1023) bsums[blockIdx.x] = tmp[1023];
}

__global__ __launch_bounds__(64) void scan_sums(int* __restrict__ bsums, int nb,
                                                int* __restrict__ row_off, int n) {
    int lane = threadIdx.x;
    int carry = 0;
    for (int base = 0; base < nb; base += 64) {
        int i = base + lane;
        int o = (i < nb) ? bsums[i] : 0;
        int v = o;
        #pragma unroll
        for (int off = 1; off < 64; off <<= 1) {
            int x = __shfl_up(v, off, 64);
            if (lane >= off) v += x;
        }
        if (i < nb) bsums[i] = carry + v - o;
        int tot = __shfl(v, 63, 64);
        carry += tot;
    }
    if (lane == 0) row_off[n] = carry;
}

__global__ __launch_bounds__(1024) void scan_add(int* __restrict__ row_off,
                                                 const int* __restrict__ bsums,
                                                 int* __restrict__ cursor, int n) {
    int idx = blockIdx.x * 1024 + threadIdx.x;
    if (idx < n) {
        int v = row_off[idx] + bsums[blockIdx.x];
        row_off[idx] = v;
        cursor[idx] = v;
    }
}

__global__ void scatter_kernel(const int* __restrict__ ei, int E, int n,
                               int* __restrict__ cursor, int* __restrict__ csr_src) {
    int e = blockIdx.x * 256 + threadIdx.x;
    int tot = E + n;
    if (e >= tot) return;
    int s, d;
    if (e < E) { s = ei[e]; d = ei[E + e]; } else { s = d = e - E; }
    int pos = atomicAdd(&cursor[d], 1);
    csr_src[pos] = s;
}

// ---------------------------------------------------------------- fp32 GEMM
__global__ __launch_bounds__(256) void gemm_kernel(const float* __restrict__ A,
                                                   const float* __restrict__ B,
                                                   float* __restrict__ C,
                                                   int M, int N, int K) {
    __shared__ float As[16][132];
    __shared__ float Bs[16][128];
    int t = threadIdx.x;
    int row0 = blockIdx.x * 128;
    int col0 = blockIdx.y * 128;
    int tr = (t >> 4) * 8;
    int tc = (t & 15) * 8;
    float acc[8][8] = {};
    for (int k0 = 0; k0 < K; k0 += 16) {
        #pragma unroll
        for (int i = 0; i < 2; i++) {
            int f = t + i * 256;
            int m = f >> 2;
            int kg = (f & 3) * 4;
            int grow = row0 + m;
            float4 v = make_float4(0.f, 0.f, 0.f, 0.f);
            if (grow < M) v = *(const float4*)(A + (size_t)grow * K + k0 + kg);
            As[kg + 0][m] = v.x; As[kg + 1][m] = v.y;
            As[kg + 2][m] = v.z; As[kg + 3][m] = v.w;
        }
        #pragma unroll
        for (int i = 0; i < 2; i++) {
            int f = t + i * 256;
            int kk = f >> 5;
            int c = (f & 31) * 4;
            int gc = col0 + c;
            float4 v = make_float4(0.f, 0.f, 0.f, 0.f);
            if (gc + 3 < N) {
                v = *(const float4*)(B + (size_t)(k0 + kk) * N + gc);
            } else {
                float tv[4] = {0.f, 0.f, 0.f, 0.f};
                for (int j = 0; j < 4; j++)
                    if (gc + j < N) tv[j] = B[(size_t)(k0 + kk) * N + gc + j];
                v = make_float4(tv[0], tv[1], tv[2], tv[3]);
            }
            *(float4*)&Bs[kk][c] = v;
        }
        __syncthreads();
        #pragma unroll
        for (int kk = 0; kk < 16; kk++) {
            float a[8], b[8];
            *(float4*)&a[0] = *(const float4*)&As[kk][tr];
            *(float4*)&a[4] = *(const float4*)&As[kk][tr + 4];
            *(float4*)&b[0] = *(const float4*)&Bs[kk][tc];
            *(float4*)&b[4] = *(const float4*)&Bs[kk][tc + 4];
            #pragma unroll
            for (int i = 0; i < 8; i++)
                #pragma unroll
                for (int j = 0; j < 8; j++)
                    acc[i][j] = fmaf(a[i], b[j], acc[i][j]);
        }
        __syncthreads();
    }
    for (int i = 0; i < 8; i++) {
        int r = row0 + tr + i;
        if (r >= M) continue;
        for (int j = 0; j < 8; j += 4) {
            int c = col0 + tc + j;
            if (c + 3 < N) {
                *(float4*)(C + (size_t)r * N + c) =
                    make_float4(acc[i][j], acc[i][j + 1], acc[i][j + 2], acc[i][j + 3]);
            } else {
                for (int jj = 0; jj < 4; jj++)
                    if (c + jj < N) C[(size_t)r * N + c + jj] = acc[i][j + jj];
            }
        }
    }
}

// ---------------------------------------------------------------- attention coefs
template <int C>
__global__ __launch_bounds__(256) void coef_kernel(const float* __restrict__ h,
                                                   const float* __restrict__ a_src,
                                                   const float* __restrict__ a_dst,
                                                   float* __restrict__ als,
                                                   float* __restrict__ ald, int n) {
    int wave = threadIdx.x >> 6;
    int lane = threadIdx.x & 63;
    int node = blockIdx.x * 4 + wave;
    if (node >= n) return;
    const float* hr = h + (size_t)node * (4 * C);
    float ps[4], pd[4];
    #pragma unroll
    for (int hh = 0; hh < 4; hh++) {
        float hv = (lane < C) ? hr[hh * C + lane] : 0.f;
        float as_ = (lane < C) ? a_src[hh * C + lane] : 0.f;
        float ad_ = (lane < C) ? a_dst[hh * C + lane] : 0.f;
        ps[hh] = hv * as_;
        pd[hh] = hv * ad_;
    }
    #pragma unroll
    for (int off = 32; off >= 1; off >>= 1) {
        #pragma unroll
        for (int hh = 0; hh < 4; hh++) {
            ps[hh] += __shfl_xor(ps[hh], off, 64);
            pd[hh] += __shfl_xor(pd[hh], off, 64);
        }
    }
    if (lane == 0) {
        #pragma unroll
        for (int hh = 0; hh < 4; hh++) {
            als[node * 4 + hh] = ps[hh];
            ald[node * 4 + hh] = pd[hh];
        }
    }
}

// ---------------------------------------------------------------- softmax weights
// 16 lanes per node, 16 nodes per block. Writes per-edge w[e][4] = exp(l - max)
// and per-node den[4]. als/ald tables are L2-resident (800 KB).
__global__ __launch_bounds__(256) void maxden_kernel(const float* __restrict__ als,
                                                     const float* __restrict__ ald,
                                                     const int* __restrict__ row_off,
                                                     const int* __restrict__ csr_src,
                                                     float* __restrict__ w,
                                                     float* __restrict__ den, int n) {
    int wave = threadIdx.x >> 6;
    int lane = threadIdx.x & 63;
    int sl = lane & 15;
    int sub = lane >> 4;
    int node = (blockIdx.x * 4 + wave) * 4 + sub;
    bool act = node < n;
    int rs = act ? row_off[node] : 0;
    int re = act ? row_off[node + 1] : 0;
    float4 ald4 = make_float4(0.f, 0.f, 0.f, 0.f);
    if (act) ald4 = *(const float4*)(ald + (size_t)node * 4);

    float m0 = -INFINITY, m1 = -INFINITY, m2 = -INFINITY, m3 = -INFINITY;
    for (int i = rs + sl; i < re; i += 16) {
        int s = csr_src[i];
        float4 a = *(const float4*)(als + (size_t)s * 4);
        float l0 = a.x + ald4.x; l0 = (l0 > 0.f) ? l0 : NEG_SLOPE * l0;
        float l1 = a.y + ald4.y; l1 = (l1 > 0.f) ? l1 : NEG_SLOPE * l1;
        float l2 = a.z + ald4.z; l2 = (l2 > 0.f) ? l2 : NEG_SLOPE * l2;
        float l3 = a.w + ald4.w; l3 = (l3 > 0.f) ? l3 : NEG_SLOPE * l3;
        m0 = fmaxf(m0, l0); m1 = fmaxf(m1, l1);
        m2 = fmaxf(m2, l2); m3 = fmaxf(m3, l3);
    }
    #pragma unroll
    for (int off = 8; off >= 1; off >>= 1) {
        m0 = fmaxf(m0, __shfl_xor(m0, off, 64));
        m1 = fmaxf(m1, __shfl_xor(m1, off, 64));
        m2 = fmaxf(m2, __shfl_xor(m2, off, 64));
        m3 = fmaxf(m3, __shfl_xor(m3, off, 64));
    }

    float d0 = 0.f, d1 = 0.f, d2 = 0.f, d3 = 0.f;
    for (int i = rs + sl; i < re; i += 16) {
        int s = csr_src[i];
        float4 a = *(const float4*)(als + (size_t)s * 4);
        float l0 = a.x + ald4.x; l0 = (l0 > 0.f) ? l0 : NEG_SLOPE * l0;
        float l1 = a.y + ald4.y; l1 = (l1 > 0.f) ? l1 : NEG_SLOPE * l1;
        float l2 = a.z + ald4.z; l2 = (l2 > 0.f) ? l2 : NEG_SLOPE * l2;
        float l3 = a.w + ald4.w; l3 = (l3 > 0.f) ? l3 : NEG_SLOPE * l3;
        float e0 = __expf(l0 - m0), e1 = __expf(l1 - m1);
        float e2 = __expf(l2 - m2), e3 = __expf(l3 - m3);
        d0 += e0; d1 += e1; d2 += e2; d3 += e3;
        *(float4*)(w + (size_t)i * 4) = make_float4(e0, e1, e2, e3);
    }
    #pragma unroll
    for (int off = 8; off >= 1; off >>= 1) {
        d0 += __shfl_xor(d0, off, 64);
        d1 += __shfl_xor(d1, off, 64);
        d2 += __shfl_xor(d2, off, 64);
        d3 += __shfl_xor(d3, off, 64);
    }
    if (act && sl == 0)
        *(float4*)(den + (size_t)node * 4) = make_float4(d0, d1, d2, d3);
}

// ---------------------------------------------------------------- aggregation
// Pure gather+FMA: one wave per node, lane owns 4 consecutive channels of one
// head; 4-way manual unroll for MLP. Weights precomputed by maxden_kernel.
// MODE 0: elu(v+bias)  MODE 1: elu(v+bias+res)  MODE 2: mean_h(v)+bias (C=40)
template <int C, int MODE>
__global__ __launch_bounds__(256) void agg_kernel(const float* __restrict__ hfeat,
                                                  const float* __restrict__ w,
                                                  const float* __restrict__ den,
                                                  const int* __restrict__ row_off,
                                                  const int* __restrict__ csr_src,
                                                  const float* __restrict__ bias,
                                                  const float* __restrict__ res,
                                                  float* __restrict__ out, int n) {
    constexpr int HC = 4 * C;
    constexpr int LPN = HC / 4;      // active lanes (64 or 40)
    constexpr int LPH = C / 4;       // lanes per head (16 or 10)
    int wave = threadIdx.x >> 6;
    int lane = threadIdx.x & 63;
    int node = blockIdx.x * 4 + wave;
    if (node >= n) return;
    int rs = row_off[node];
    int re = row_off[node + 1];
    int g = lane / LPH; if (g > 3) g = 3;
    const bool active = (LPN == 64) || (lane < LPN);

    float4 acc = make_float4(0.f, 0.f, 0.f, 0.f);
    int j = rs;
    for (; j + 4 <= re; j += 4) {
        int s0 = csr_src[j + 0];
        int s1 = csr_src[j + 1];
        int s2 = csr_src[j + 2];
        int s3 = csr_src[j + 3];
        float w0 = w[(size_t)(j + 0) * 4 + g];
        float w1 = w[(size_t)(j + 1) * 4 + g];
        float w2 = w[(size_t)(j + 2) * 4 + g];
        float w3 = w[(size_t)(j + 3) * 4 + g];
        if (active) {
            float4 h0 = *(const float4*)(hfeat + (size_t)s0 * HC + lane * 4);
            float4 h1 = *(const float4*)(hfeat + (size_t)s1 * HC + lane * 4);
            float4 h2 = *(const float4*)(hfeat + (size_t)s2 * HC + lane * 4);
            float4 h3 = *(const float4*)(hfeat + (size_t)s3 * HC + lane * 4);
            acc.x = fmaf(w0, h0.x, acc.x); acc.y = fmaf(w0, h0.y, acc.y);
            acc.z = fmaf(w0, h0.z, acc.z); acc.w = fmaf(w0, h0.w, acc.w);
            acc.x = fmaf(w1, h1.x, acc.x); acc.y = fmaf(w1, h1.y, acc.y);
            acc.z = fmaf(w1, h1.z, acc.z); acc.w = fmaf(w1, h1.w, acc.w);
            acc.x = fmaf(w2, h2.x, acc.x); acc.y = fmaf(w2, h2.y, acc.y);
            acc.z = fmaf(w2, h2.z, acc.z); acc.w = fmaf(w2, h2.w, acc.w);
            acc.x = fmaf(w3, h3.x, acc.x); acc.y = fmaf(w3, h3.y, acc.y);
            acc.z = fmaf(w3, h3.z, acc.z); acc.w = fmaf(w3, h3.w, acc.w);
        }
    }
    for (; j < re; ++j) {
        int s = csr_src[j];
        float ww = w[(size_t)j * 4 + g];
        if (active) {
            float4 hv = *(const float4*)(hfeat + (size_t)s * HC + lane * 4);
            acc.x = fmaf(ww, hv.x, acc.x); acc.y = fmaf(ww, hv.y, acc.y);
            acc.z = fmaf(ww, hv.z, acc.z); acc.w = fmaf(ww, hv.w, acc.w);
        }
    }

    float dg = den[(size_t)node * 4 + g];
    float inv = 1.f / (dg + 1e-16f);
    float4 v = make_float4(acc.x * inv, acc.y * inv, acc.z * inv, acc.w * inv);

    if (MODE == 2) {
        float4 vs = v;
        #pragma unroll
        for (int k = 1; k < 4; k++) {
            int srcl = lane + k * LPH;
            vs.x += __shfl(v.x, srcl, 64);
            vs.y += __shfl(v.y, srcl, 64);
            vs.z += __shfl(v.z, srcl, 64);
            vs.w += __shfl(v.w, srcl, 64);
        }
        if (lane < LPH) {
            float4 b4 = *(const float4*)(bias + lane * 4);
            float4 o = make_float4(vs.x * 0.25f + b4.x, vs.y * 0.25f + b4.y,
                                   vs.z * 0.25f + b4.z, vs.w * 0.25f + b4.w);
            *(float4*)(out + (size_t)node * C + lane * 4) = o;
        }
    } else {
        if (active) {
            float4 b4 = *(const float4*)(bias + lane * 4);
            float4 o = make_float4(v.x + b4.x, v.y + b4.y, v.z + b4.z, v.w + b4.w);
            if (MODE == 1) {
                float4 r4 = *(const float4*)(res + (size_t)node * HC + lane * 4);
                o.x += r4.x; o.y += r4.y; o.z += r4.z; o.w += r4.w;
            }
            o.x = (o.x > 0.f) ? o.x : expm1f(o.x);
            o.y = (o.y > 0.f) ? o.y : expm1f(o.y);
            o.z = (o.z > 0.f) ? o.z : expm1f(o.z);
            o.w = (o.w > 0.f) ? o.w : expm1f(o.w);
            *(float4*)(out + (size_t)node * HC + lane * 4) = o;
        }
    }
}

// ---------------------------------------------------------------- launch
extern "C" void kernel_launch(void* const* d_in, const int* in_sizes, int n_in,
                              void* d_out, int out_size, void* d_ws, size_t ws_size,
                              hipStream_t stream) {
    const float* x   = (const float*)d_in[0];
    const int*   ei  = (const int*)d_in[1];
    const float* W1  = (const float*)d_in[2];
    const float* a1s = (const float*)d_in[3];
    const float* a1d = (const float*)d_in[4];
    const float* b1  = (const float*)d_in[5];
    const float* W2  = (const float*)d_in[6];
    const float* a2s = (const float*)d_in[7];
    const float* a2d = (const float*)d_in[8];
    const float* b2  = (const float*)d_in[9];
    const float* W3  = (const float*)d_in[10];
    const float* a3s = (const float*)d_in[11];
    const float* a3d = (const float*)d_in[12];
    const float* b3  = (const float*)d_in[13];
    float* out = (float*)d_out;

    int N = in_sizes[0] / 128;
    int E = in_sizes[1] / 2;

    char* ws = (char*)d_ws;
    size_t off = 0;
    auto alloc = [&](size_t bytes) -> void* {
        void* p = ws + off;
        off += (bytes + 255) & ~(size_t)255;
        return p;
    };
    float* hbuf = (float*)alloc((size_t)N * 256 * 4);
    float* x1   = (float*)alloc((size_t)N * 256 * 4);
    float* x2   = (float*)alloc((size_t)N * 256 * 4);
    float* als  = (float*)alloc((size_t)N * 4 * 4);
    float* ald  = (float*)alloc((size_t)N * 4 * 4);
    float* wbuf = (float*)alloc((size_t)(E + N) * 4 * 4);
    float* den  = (float*)alloc((size_t)N * 4 * 4);
    int* deg     = (int*)alloc((size_t)N * 4);
    int* row_off = (int*)alloc((size_t)(N + 1) * 4);
    int* cursor  = (int*)alloc((size_t)N * 4);
    int* csr     = (int*)alloc((size_t)(E + N) * 4);
    int* bsums   = (int*)alloc(1024 * 4);

    int tot = E + N;
    int nb = (N + 1023) / 1024;
    hipMemsetAsync(deg, 0, (size_t)N * 4, stream);
    degree_kernel<<<(tot + 255) / 256, 256, 0, stream>>>(ei, E, N, deg);
    scan_block<<<nb, 1024, 0, stream>>>(deg, row_off, bsums, N);
    scan_sums<<<1, 64, 0, stream>>>(bsums, nb, row_off, N);
    scan_add<<<nb, 1024, 0, stream>>>(row_off, bsums, cursor, N);
    scatter_kernel<<<(tot + 255) / 256, 256, 0, stream>>>(ei, E, N, cursor, csr);

    int nodeBlocks = (N + 3) / 4;        // agg/coef: 4 nodes per block
    int mdBlocks   = (N + 15) / 16;      // maxden: 16 nodes per block
    dim3 blk(256);

    // layer 1
    {
        dim3 grid((N + 127) / 128, 2);
        gemm_kernel<<<grid, blk, 0, stream>>>(x, W1, hbuf, N, 256, 128);
        coef_kernel<64><<<nodeBlocks, blk, 0, stream>>>(hbuf, a1s, a1d, als, ald, N);
        maxden_kernel<<<mdBlocks, blk, 0, stream>>>(als, ald, row_off, csr, wbuf, den, N);
        agg_kernel<64, 0><<<nodeBlocks, blk, 0, stream>>>(hbuf, wbuf, den, row_off, csr,
                                                          b1, nullptr, x1, N);
    }
    // layer 2
    {
        dim3 grid((N + 127) / 128, 2);
        gemm_kernel<<<grid, blk, 0, stream>>>(x1, W2, hbuf, N, 256, 256);
        coef_kernel<64><<<nodeBlocks, blk, 0, stream>>>(hbuf, a2s, a2d, als, ald, N);
        maxden_kernel<<<mdBlocks, blk, 0, stream>>>(als, ald, row_off, csr, wbuf, den, N);
        agg_kernel<64, 1><<<nodeBlocks, blk, 0, stream>>>(hbuf, wbuf, den, row_off, csr,
                                                          b2, x1, x2, N);
    }
    // layer 3
    {
        dim3 grid((N + 127) / 128, 2);
        gemm_kernel<<<grid, blk, 0, stream>>>(x2, W3, hbuf, N, 160, 256);
        coef_kernel<40><<<nodeBlocks, blk, 0, stream>>>(hbuf, a3s, a3d, als, ald, N);
        maxden_kernel<<<mdBlocks, blk, 0, stream>>>(als, ald, row_off, csr, wbuf, den, N);
        agg_kernel<40, 2><<<nodeBlocks, blk, 0, stream>>>(hbuf, wbuf, den, row_off, csr,
                                                          b3, nullptr, out, N);
    }
}

// Round 4
// 676.906 us; speedup vs baseline: 1.1945x; 1.1945x over previous
//
#include <hip/hip_runtime.h>
#include <hip/hip_bf16.h>
#include <hip/hip_fp16.h>
#include <math.h>

#define NEG_SLOPE 0.2f

struct h2x2 { __half2 a, b; };   // 4 halves, 8 bytes

// ---------------------------------------------------------------- CSR build
__global__ void degree_kernel(const int* __restrict__ ei, int E, int n,
                              int* __restrict__ deg) {
    int e = blockIdx.x * 256 + threadIdx.x;
    int tot = E + n;
    if (e >= tot) return;
    int d = (e < E) ? ei[E + e] : (e - E);
    atomicAdd(&deg[d], 1);
}

__global__ __launch_bounds__(1024) void scan_block(const int* __restrict__ deg,
                                                   int* __restrict__ row_off,
                                                   int* __restrict__ bsums, int n) {
    __shared__ int tmp[1024];
    int t = threadIdx.x;
    int idx = blockIdx.x * 1024 + t;
    int v = (idx < n) ? deg[idx] : 0;
    tmp[t] = v;
    __syncthreads();
    #pragma unroll
    for (int off = 1; off < 1024; off <<= 1) {
        int x = (t >= off) ? tmp[t - off] : 0;
        __syncthreads();
        tmp[t] += x;
        __syncthreads();
    }
    if (idx < n) row_off[idx] = tmp[t] - v;
    if (t == 1023) bsums[blockIdx.x] = tmp[1023];
}

__global__ __launch_bounds__(64) void scan_sums(int* __restrict__ bsums, int nb,
                                                int* __restrict__ row_off, int n) {
    int lane = threadIdx.x;
    int carry = 0;
    for (int base = 0; base < nb; base += 64) {
        int i = base + lane;
        int o = (i < nb) ? bsums[i] : 0;
        int v = o;
        #pragma unroll
        for (int off = 1; off < 64; off <<= 1) {
            int x = __shfl_up(v, off, 64);
            if (lane >= off) v += x;
        }
        if (i < nb) bsums[i] = carry + v - o;
        int tot = __shfl(v, 63, 64);
        carry += tot;
    }
    if (lane == 0) row_off[n] = carry;
}

__global__ __launch_bounds__(1024) void scan_add(int* __restrict__ row_off,
                                                 const int* __restrict__ bsums,
                                                 int* __restrict__ cursor, int n) {
    int idx = blockIdx.x * 1024 + threadIdx.x;
    if (idx < n) {
        int v = row_off[idx] + bsums[blockIdx.x];
        row_off[idx] = v;
        cursor[idx] = v;
    }
}

__global__ void scatter_kernel(const int* __restrict__ ei, int E, int n,
                               int* __restrict__ cursor, int* __restrict__ csr_src) {
    int e = blockIdx.x * 256 + threadIdx.x;
    int tot = E + n;
    if (e >= tot) return;
    int s, d;
    if (e < E) { s = ei[e]; d = ei[E + e]; } else { s = d = e - E; }
    int pos = atomicAdd(&cursor[d], 1);
    csr_src[pos] = s;
}

// ---------------------------------------------------------------- fp32 GEMM
// C[M,N] = A[M,K] @ B[K,N]; also writes fp16 shadow Ch (for the gather).
__global__ __launch_bounds__(256) void gemm_kernel(const float* __restrict__ A,
                                                   const float* __restrict__ B,
                                                   float* __restrict__ C,
                                                   __half* __restrict__ Ch,
                                                   int M, int N, int K) {
    __shared__ float As[16][132];
    __shared__ float Bs[16][128];
    int t = threadIdx.x;
    int row0 = blockIdx.x * 128;
    int col0 = blockIdx.y * 128;
    int tr = (t >> 4) * 8;
    int tc = (t & 15) * 8;
    float acc[8][8] = {};
    for (int k0 = 0; k0 < K; k0 += 16) {
        #pragma unroll
        for (int i = 0; i < 2; i++) {
            int f = t + i * 256;
            int m = f >> 2;
            int kg = (f & 3) * 4;
            int grow = row0 + m;
            float4 v = make_float4(0.f, 0.f, 0.f, 0.f);
            if (grow < M) v = *(const float4*)(A + (size_t)grow * K + k0 + kg);
            As[kg + 0][m] = v.x; As[kg + 1][m] = v.y;
            As[kg + 2][m] = v.z; As[kg + 3][m] = v.w;
        }
        #pragma unroll
        for (int i = 0; i < 2; i++) {
            int f = t + i * 256;
            int kk = f >> 5;
            int c = (f & 31) * 4;
            int gc = col0 + c;
            float4 v = make_float4(0.f, 0.f, 0.f, 0.f);
            if (gc + 3 < N) {
                v = *(const float4*)(B + (size_t)(k0 + kk) * N + gc);
            } else {
                float tv[4] = {0.f, 0.f, 0.f, 0.f};
                for (int j = 0; j < 4; j++)
                    if (gc + j < N) tv[j] = B[(size_t)(k0 + kk) * N + gc + j];
                v = make_float4(tv[0], tv[1], tv[2], tv[3]);
            }
            *(float4*)&Bs[kk][c] = v;
        }
        __syncthreads();
        #pragma unroll
        for (int kk = 0; kk < 16; kk++) {
            float a[8], b[8];
            *(float4*)&a[0] = *(const float4*)&As[kk][tr];
            *(float4*)&a[4] = *(const float4*)&As[kk][tr + 4];
            *(float4*)&b[0] = *(const float4*)&Bs[kk][tc];
            *(float4*)&b[4] = *(const float4*)&Bs[kk][tc + 4];
            #pragma unroll
            for (int i = 0; i < 8; i++)
                #pragma unroll
                for (int j = 0; j < 8; j++)
                    acc[i][j] = fmaf(a[i], b[j], acc[i][j]);
        }
        __syncthreads();
    }
    for (int i = 0; i < 8; i++) {
        int r = row0 + tr + i;
        if (r >= M) continue;
        for (int j = 0; j < 8; j += 4) {
            int c = col0 + tc + j;
            if (c + 3 < N) {
                *(float4*)(C + (size_t)r * N + c) =
                    make_float4(acc[i][j], acc[i][j + 1], acc[i][j + 2], acc[i][j + 3]);
                h2x2 hv;
                hv.a = __halves2half2(__float2half_rn(acc[i][j]),
                                      __float2half_rn(acc[i][j + 1]));
                hv.b = __halves2half2(__float2half_rn(acc[i][j + 2]),
                                      __float2half_rn(acc[i][j + 3]));
                *(h2x2*)(Ch + (size_t)r * N + c) = hv;
            } else {
                for (int jj = 0; jj < 4; jj++)
                    if (c + jj < N) {
                        C[(size_t)r * N + c + jj] = acc[i][j + jj];
                        Ch[(size_t)r * N + c + jj] = __float2half_rn(acc[i][j + jj]);
                    }
            }
        }
    }
}

// ---------------------------------------------------------------- attention coefs
template <int C>
__global__ __launch_bounds__(256) void coef_kernel(const float* __restrict__ h,
                                                   const float* __restrict__ a_src,
                                                   const float* __restrict__ a_dst,
                                                   float* __restrict__ als,
                                                   float* __restrict__ ald, int n) {
    int wave = threadIdx.x >> 6;
    int lane = threadIdx.x & 63;
    int node = blockIdx.x * 4 + wave;
    if (node >= n) return;
    const float* hr = h + (size_t)node * (4 * C);
    float ps[4], pd[4];
    #pragma unroll
    for (int hh = 0; hh < 4; hh++) {
        float hv = (lane < C) ? hr[hh * C + lane] : 0.f;
        float as_ = (lane < C) ? a_src[hh * C + lane] : 0.f;
        float ad_ = (lane < C) ? a_dst[hh * C + lane] : 0.f;
        ps[hh] = hv * as_;
        pd[hh] = hv * ad_;
    }
    #pragma unroll
    for (int off = 32; off >= 1; off >>= 1) {
        #pragma unroll
        for (int hh = 0; hh < 4; hh++) {
            ps[hh] += __shfl_xor(ps[hh], off, 64);
            pd[hh] += __shfl_xor(pd[hh], off, 64);
        }
    }
    if (lane == 0) {
        #pragma unroll
        for (int hh = 0; hh < 4; hh++) {
            als[node * 4 + hh] = ps[hh];
            ald[node * 4 + hh] = pd[hh];
        }
    }
}

// ---------------------------------------------------------------- softmax weights
__global__ __launch_bounds__(256) void maxden_kernel(const float* __restrict__ als,
                                                     const float* __restrict__ ald,
                                                     const int* __restrict__ row_off,
                                                     const int* __restrict__ csr_src,
                                                     float* __restrict__ w,
                                                     float* __restrict__ den, int n) {
    int wave = threadIdx.x >> 6;
    int lane = threadIdx.x & 63;
    int sl = lane & 15;
    int sub = lane >> 4;
    int node = (blockIdx.x * 4 + wave) * 4 + sub;
    bool act = node < n;
    int rs = act ? row_off[node] : 0;
    int re = act ? row_off[node + 1] : 0;
    float4 ald4 = make_float4(0.f, 0.f, 0.f, 0.f);
    if (act) ald4 = *(const float4*)(ald + (size_t)node * 4);

    float m0 = -INFINITY, m1 = -INFINITY, m2 = -INFINITY, m3 = -INFINITY;
    for (int i = rs + sl; i < re; i += 16) {
        int s = csr_src[i];
        float4 a = *(const float4*)(als + (size_t)s * 4);
        float l0 = a.x + ald4.x; l0 = (l0 > 0.f) ? l0 : NEG_SLOPE * l0;
        float l1 = a.y + ald4.y; l1 = (l1 > 0.f) ? l1 : NEG_SLOPE * l1;
        float l2 = a.z + ald4.z; l2 = (l2 > 0.f) ? l2 : NEG_SLOPE * l2;
        float l3 = a.w + ald4.w; l3 = (l3 > 0.f) ? l3 : NEG_SLOPE * l3;
        m0 = fmaxf(m0, l0); m1 = fmaxf(m1, l1);
        m2 = fmaxf(m2, l2); m3 = fmaxf(m3, l3);
    }
    #pragma unroll
    for (int off = 8; off >= 1; off >>= 1) {
        m0 = fmaxf(m0, __shfl_xor(m0, off, 64));
        m1 = fmaxf(m1, __shfl_xor(m1, off, 64));
        m2 = fmaxf(m2, __shfl_xor(m2, off, 64));
        m3 = fmaxf(m3, __shfl_xor(m3, off, 64));
    }

    float d0 = 0.f, d1 = 0.f, d2 = 0.f, d3 = 0.f;
    for (int i = rs + sl; i < re; i += 16) {
        int s = csr_src[i];
        float4 a = *(const float4*)(als + (size_t)s * 4);
        float l0 = a.x + ald4.x; l0 = (l0 > 0.f) ? l0 : NEG_SLOPE * l0;
        float l1 = a.y + ald4.y; l1 = (l1 > 0.f) ? l1 : NEG_SLOPE * l1;
        float l2 = a.z + ald4.z; l2 = (l2 > 0.f) ? l2 : NEG_SLOPE * l2;
        float l3 = a.w + ald4.w; l3 = (l3 > 0.f) ? l3 : NEG_SLOPE * l3;
        float e0 = __expf(l0 - m0), e1 = __expf(l1 - m1);
        float e2 = __expf(l2 - m2), e3 = __expf(l3 - m3);
        d0 += e0; d1 += e1; d2 += e2; d3 += e3;
        *(float4*)(w + (size_t)i * 4) = make_float4(e0, e1, e2, e3);
    }
    #pragma unroll
    for (int off = 8; off >= 1; off >>= 1) {
        d0 += __shfl_xor(d0, off, 64);
        d1 += __shfl_xor(d1, off, 64);
        d2 += __shfl_xor(d2, off, 64);
        d3 += __shfl_xor(d3, off, 64);
    }
    if (act && sl == 0)
        *(float4*)(den + (size_t)node * 4) = make_float4(d0, d1, d2, d3);
}

// ---------------------------------------------------------------- aggregation
// Gather fp16 rows (8 B/lane), accumulate fp32. 8-edge unroll for MLP.
template <int C, int MODE>
__global__ __launch_bounds__(256) void agg_kernel(const __half* __restrict__ hh,
                                                  const float* __restrict__ w,
                                                  const float* __restrict__ den,
                                                  const int* __restrict__ row_off,
                                                  const int* __restrict__ csr_src,
                                                  const float* __restrict__ bias,
                                                  const float* __restrict__ res,
                                                  float* __restrict__ out, int n) {
    constexpr int HC = 4 * C;
    constexpr int LPN = HC / 4;      // active lanes (64 or 40)
    constexpr int LPH = C / 4;       // lanes per head (16 or 10)
    int wave = threadIdx.x >> 6;
    int lane = threadIdx.x & 63;
    int node = blockIdx.x * 4 + wave;
    if (node >= n) return;
    int rs = row_off[node];
    int re = row_off[node + 1];
    int g = lane / LPH; if (g > 3) g = 3;
    const bool active = (LPN == 64) || (lane < LPN);

    float ax = 0.f, ay = 0.f, az = 0.f, aw = 0.f;
    int j = rs;
    for (; j + 8 <= re; j += 8) {
        int s[8];
        float wv[8];
        #pragma unroll
        for (int q = 0; q < 8; q++) {
            s[q] = csr_src[j + q];
            wv[q] = w[(size_t)(j + q) * 4 + g];
        }
        if (active) {
            h2x2 hv[8];
            #pragma unroll
            for (int q = 0; q < 8; q++)
                hv[q] = *(const h2x2*)(hh + (size_t)s[q] * HC + lane * 4);
            #pragma unroll
            for (int q = 0; q < 8; q++) {
                float2 f01 = __half22float2(hv[q].a);
                float2 f23 = __half22float2(hv[q].b);
                ax = fmaf(wv[q], f01.x, ax); ay = fmaf(wv[q], f01.y, ay);
                az = fmaf(wv[q], f23.x, az); aw = fmaf(wv[q], f23.y, aw);
            }
        }
    }
    for (; j < re; ++j) {
        int s = csr_src[j];
        float ww = w[(size_t)j * 4 + g];
        if (active) {
            h2x2 hv = *(const h2x2*)(hh + (size_t)s * HC + lane * 4);
            float2 f01 = __half22float2(hv.a);
            float2 f23 = __half22float2(hv.b);
            ax = fmaf(ww, f01.x, ax); ay = fmaf(ww, f01.y, ay);
            az = fmaf(ww, f23.x, az); aw = fmaf(ww, f23.y, aw);
        }
    }

    float dg = den[(size_t)node * 4 + g];
    float inv = 1.f / (dg + 1e-16f);
    float4 v = make_float4(ax * inv, ay * inv, az * inv, aw * inv);

    if (MODE == 2) {
        float4 vs = v;
        #pragma unroll
        for (int k = 1; k < 4; k++) {
            int srcl = lane + k * LPH;
            vs.x += __shfl(v.x, srcl, 64);
            vs.y += __shfl(v.y, srcl, 64);
            vs.z += __shfl(v.z, srcl, 64);
            vs.w += __shfl(v.w, srcl, 64);
        }
        if (lane < LPH) {
            float4 b4 = *(const float4*)(bias + lane * 4);
            float4 o = make_float4(vs.x * 0.25f + b4.x, vs.y * 0.25f + b4.y,
                                   vs.z * 0.25f + b4.z, vs.w * 0.25f + b4.w);
            *(float4*)(out + (size_t)node * C + lane * 4) = o;
        }
    } else {
        if (active) {
            float4 b4 = *(const float4*)(bias + lane * 4);
            float4 o = make_float4(v.x + b4.x, v.y + b4.y, v.z + b4.z, v.w + b4.w);
            if (MODE == 1) {
                float4 r4 = *(const float4*)(res + (size_t)node * HC + lane * 4);
                o.x += r4.x; o.y += r4.y; o.z += r4.z; o.w += r4.w;
            }
            o.x = (o.x > 0.f) ? o.x : expm1f(o.x);
            o.y = (o.y > 0.f) ? o.y : expm1f(o.y);
            o.z = (o.z > 0.f) ? o.z : expm1f(o.z);
            o.w = (o.w > 0.f) ? o.w : expm1f(o.w);
            *(float4*)(out + (size_t)node * HC + lane * 4) = o;
        }
    }
}

// ---------------------------------------------------------------- launch
extern "C" void kernel_launch(void* const* d_in, const int* in_sizes, int n_in,
                              void* d_out, int out_size, void* d_ws, size_t ws_size,
                              hipStream_t stream) {
    const float* x   = (const float*)d_in[0];
    const int*   ei  = (const int*)d_in[1];
    const float* W1  = (const float*)d_in[2];
    const float* a1s = (const float*)d_in[3];
    const float* a1d = (const float*)d_in[4];
    const float* b1  = (const float*)d_in[5];
    const float* W2  = (const float*)d_in[6];
    const float* a2s = (const float*)d_in[7];
    const float* a2d = (const float*)d_in[8];
    const float* b2  = (const float*)d_in[9];
    const float* W3  = (const float*)d_in[10];
    const float* a3s = (const float*)d_in[11];
    const float* a3d = (const float*)d_in[12];
    const float* b3  = (const float*)d_in[13];
    float* out = (float*)d_out;

    int N = in_sizes[0] / 128;
    int E = in_sizes[1] / 2;

    char* ws = (char*)d_ws;
    size_t off = 0;
    auto alloc = [&](size_t bytes) -> void* {
        void* p = ws + off;
        off += (bytes + 255) & ~(size_t)255;
        return p;
    };
    float*  hbuf  = (float*)alloc((size_t)N * 256 * 4);
    __half* hhalf = (__half*)alloc((size_t)N * 256 * 2);
    float*  x1    = (float*)alloc((size_t)N * 256 * 4);
    float*  x2    = (float*)alloc((size_t)N * 256 * 4);
    float*  als   = (float*)alloc((size_t)N * 4 * 4);
    float*  ald   = (float*)alloc((size_t)N * 4 * 4);
    float*  wbuf  = (float*)alloc((size_t)(E + N) * 4 * 4);
    float*  den   = (float*)alloc((size_t)N * 4 * 4);
    int* deg     = (int*)alloc((size_t)N * 4);
    int* row_off = (int*)alloc((size_t)(N + 1) * 4);
    int* cursor  = (int*)alloc((size_t)N * 4);
    int* csr     = (int*)alloc((size_t)(E + N) * 4);
    int* bsums   = (int*)alloc(1024 * 4);

    int tot = E + N;
    int nb = (N + 1023) / 1024;
    hipMemsetAsync(deg, 0, (size_t)N * 4, stream);
    degree_kernel<<<(tot + 255) / 256, 256, 0, stream>>>(ei, E, N, deg);
    scan_block<<<nb, 1024, 0, stream>>>(deg, row_off, bsums, N);
    scan_sums<<<1, 64, 0, stream>>>(bsums, nb, row_off, N);
    scan_add<<<nb, 1024, 0, stream>>>(row_off, bsums, cursor, N);
    scatter_kernel<<<(tot + 255) / 256, 256, 0, stream>>>(ei, E, N, cursor, csr);

    int nodeBlocks = (N + 3) / 4;
    int mdBlocks   = (N + 15) / 16;
    dim3 blk(256);

    // layer 1
    {
        dim3 grid((N + 127) / 128, 2);
        gemm_kernel<<<grid, blk, 0, stream>>>(x, W1, hbuf, hhalf, N, 256, 128);
        coef_kernel<64><<<nodeBlocks, blk, 0, stream>>>(hbuf, a1s, a1d, als, ald, N);
        maxden_kernel<<<mdBlocks, blk, 0, stream>>>(als, ald, row_off, csr, wbuf, den, N);
        agg_kernel<64, 0><<<nodeBlocks, blk, 0, stream>>>(hhalf, wbuf, den, row_off, csr,
                                                          b1, nullptr, x1, N);
    }
    // layer 2
    {
        dim3 grid((N + 127) / 128, 2);
        gemm_kernel<<<grid, blk, 0, stream>>>(x1, W2, hbuf, hhalf, N, 256, 256);
        coef_kernel<64><<<nodeBlocks, blk, 0, stream>>>(hbuf, a2s, a2d, als, ald, N);
        maxden_kernel<<<mdBlocks, blk, 0, stream>>>(als, ald, row_off, csr, wbuf, den, N);
        agg_kernel<64, 1><<<nodeBlocks, blk, 0, stream>>>(hhalf, wbuf, den, row_off, csr,
                                                          b2, x1, x2, N);
    }
    // layer 3
    {
        dim3 grid((N + 127) / 128, 2);
        gemm_kernel<<<grid, blk, 0, stream>>>(x2, W3, hbuf, hhalf, N, 160, 256);
        coef_kernel<40><<<nodeBlocks, blk, 0, stream>>>(hbuf, a3s, a3d, als, ald, N);
        maxden_kernel<<<mdBlocks, blk, 0, stream>>>(als, ald, row_off, csr, wbuf, den, N);
        agg_kernel<40, 2><<<nodeBlocks, blk, 0, stream>>>(hhalf, wbuf, den, row_off, csr,
                                                          b3, nullptr, out, N);
    }
}

// Round 5
// 590.309 us; speedup vs baseline: 1.3697x; 1.1467x over previous
//
#include <hip/hip_runtime.h>
#include <hip/hip_bf16.h>
#include <hip/hip_fp16.h>
#include <math.h>

#define NEG_SLOPE 0.2f

typedef _Float16 half8 __attribute__((ext_vector_type(8)));
typedef _Float16 half4 __attribute__((ext_vector_type(4)));
typedef float f32x4 __attribute__((ext_vector_type(4)));

struct h2x2 { __half2 a, b; };   // 4 halves, 8 bytes

// ---------------------------------------------------------------- CSR build
__global__ void degree_kernel(const int* __restrict__ ei, int E, int n,
                              int* __restrict__ deg) {
    int e = blockIdx.x * 256 + threadIdx.x;
    int tot = E + n;
    if (e >= tot) return;
    int d = (e < E) ? ei[E + e] : (e - E);
    atomicAdd(&deg[d], 1);
}

__global__ __launch_bounds__(1024) void scan_block(const int* __restrict__ deg,
                                                   int* __restrict__ row_off,
                                                   int* __restrict__ bsums, int n) {
    __shared__ int tmp[1024];
    int t = threadIdx.x;
    int idx = blockIdx.x * 1024 + t;
    int v = (idx < n) ? deg[idx] : 0;
    tmp[t] = v;
    __syncthreads();
    #pragma unroll
    for (int off = 1; off < 1024; off <<= 1) {
        int x = (t >= off) ? tmp[t - off] : 0;
        __syncthreads();
        tmp[t] += x;
        __syncthreads();
    }
    if (idx < n) row_off[idx] = tmp[t] - v;
    if (t == 1023) bsums[blockIdx.x] = tmp[1023];
}

__global__ __launch_bounds__(64) void scan_sums(int* __restrict__ bsums, int nb,
                                                int* __restrict__ row_off, int n) {
    int lane = threadIdx.x;
    int carry = 0;
    for (int base = 0; base < nb; base += 64) {
        int i = base + lane;
        int o = (i < nb) ? bsums[i] : 0;
        int v = o;
        #pragma unroll
        for (int off = 1; off < 64; off <<= 1) {
            int x = __shfl_up(v, off, 64);
            if (lane >= off) v += x;
        }
        if (i < nb) bsums[i] = carry + v - o;
        int tot = __shfl(v, 63, 64);
        carry += tot;
    }
    if (lane == 0) row_off[n] = carry;
}

__global__ __launch_bounds__(1024) void scan_add(int* __restrict__ row_off,
                                                 const int* __restrict__ bsums,
                                                 int* __restrict__ cursor, int n) {
    int idx = blockIdx.x * 1024 + threadIdx.x;
    if (idx < n) {
        int v = row_off[idx] + bsums[blockIdx.x];
        row_off[idx] = v;
        cursor[idx] = v;
    }
}

__global__ void scatter_kernel(const int* __restrict__ ei, int E, int n,
                               int* __restrict__ cursor, int* __restrict__ csr_src) {
    int e = blockIdx.x * 256 + threadIdx.x;
    int tot = E + n;
    if (e >= tot) return;
    int s, d;
    if (e < E) { s = ei[e]; d = ei[E + e]; } else { s = d = e - E; }
    int pos = atomicAdd(&cursor[d], 1);
    csr_src[pos] = s;
}

// ---------------------------------------------------------------- splits
// fp32 -> (hi fp16, lo fp16) planes, vectorized x4
__global__ void split_f32x4(const float* __restrict__ src, _Float16* __restrict__ hi,
                            _Float16* __restrict__ lo, int n4) {
    int i = blockIdx.x * 256 + threadIdx.x;
    if (i >= n4) return;
    float4 v = ((const float4*)src)[i];
    half4 h, l;
    h.x = (_Float16)v.x; l.x = (_Float16)(v.x - (float)h.x);
    h.y = (_Float16)v.y; l.y = (_Float16)(v.y - (float)h.y);
    h.z = (_Float16)v.z; l.z = (_Float16)(v.z - (float)h.z);
    h.w = (_Float16)v.w; l.w = (_Float16)(v.w - (float)h.w);
    ((half4*)hi)[i] = h;
    ((half4*)lo)[i] = l;
}

// W[K][N] fp32 -> Bt[n][k] hi/lo fp16, rows n>=N zero-padded to padN
__global__ void wt_split(const float* __restrict__ W, _Float16* __restrict__ bhi,
                         _Float16* __restrict__ blo, int K, int N, int padN) {
    int idx = blockIdx.x * 256 + threadIdx.x;
    if (idx >= padN * K) return;
    int n = idx / K, k = idx % K;
    float v = (n < N) ? W[(size_t)k * N + n] : 0.f;
    _Float16 h = (_Float16)v;
    bhi[idx] = h;
    blo[idx] = (_Float16)(v - (float)h);
}

// ---------------------------------------------------------------- MFMA GEMM
// C[M,N] = (Ahi+Alo)[M,K] @ (Bhi+Blo)[K,N] via 3-term fp16 split, fp32 acc.
// Bt* is [padN=256][K] row-major (pre-transposed). 128x128 tile, 4 waves 2x2,
// BK=32. A staged in LDS with XOR-swizzled layout (conflict-free b128 reads);
// B frags read directly from global (L2-resident).
__global__ __launch_bounds__(256) void gemm_mfma(const _Float16* __restrict__ Ahi,
                                                 const _Float16* __restrict__ Alo,
                                                 const _Float16* __restrict__ Bthi,
                                                 const _Float16* __restrict__ Btlo,
                                                 float* __restrict__ C,
                                                 _Float16* __restrict__ Ch,
                                                 int M, int N, int K) {
    __shared__ _Float16 Ah[2][128 * 32];
    int t = threadIdx.x;
    int wave = t >> 6, lane = t & 63;
    int row0 = blockIdx.x * 128, col0 = blockIdx.y * 128;
    int wr = wave >> 1, wc = wave & 1;

    f32x4 acc[4][4];
    #pragma unroll
    for (int i = 0; i < 4; i++)
        #pragma unroll
        for (int j = 0; j < 4; j++)
            acc[i][j] = (f32x4)0.f;

    // swizzled LDS offset (in halves) for (row m in [0,128), granule g0 in [0,4))
    // P = m>>1 (128B pair-rows), gp = (m&1)*4 + g0, slot = gp ^ (P&7)
    auto lds_off = [](int m, int g0) -> int {
        int P = m >> 1;
        int gp = ((m & 1) << 2) | g0;
        return P * 64 + ((gp ^ (P & 7)) << 3);
    };

    for (int k0 = 0; k0 < K; k0 += 32) {
        __syncthreads();
        #pragma unroll
        for (int i = 0; i < 2; i++) {
            int s = t + i * 256;          // slot in [0,512)
            int r = s >> 2, g0 = s & 3;
            int grow = row0 + r;
            half8 vh = {}, vl = {};
            if (grow < M) {
                vh = *(const half8*)(Ahi + (size_t)grow * K + k0 + g0 * 8);
                vl = *(const half8*)(Alo + (size_t)grow * K + k0 + g0 * 8);
            }
            int off = lds_off(r, g0);
            *(half8*)(&Ah[0][off]) = vh;
            *(half8*)(&Ah[1][off]) = vl;
        }
        __syncthreads();

        // B fragments direct from global (Bt[n][k] row-major)
        half8 bh[4], bl[4];
        #pragma unroll
        for (int nf = 0; nf < 4; nf++) {
            int n = col0 + wc * 64 + nf * 16 + (lane & 15);
            size_t bo = (size_t)n * K + k0 + (lane >> 4) * 8;
            bh[nf] = *(const half8*)(Bthi + bo);
            bl[nf] = *(const half8*)(Btlo + bo);
        }
        // A fragments from LDS
        half8 ah[4], al[4];
        #pragma unroll
        for (int mf = 0; mf < 4; mf++) {
            int m = wr * 64 + mf * 16 + (lane & 15);
            int off = lds_off(m, lane >> 4);
            ah[mf] = *(half8*)(&Ah[0][off]);
            al[mf] = *(half8*)(&Ah[1][off]);
        }
        #pragma unroll
        for (int mf = 0; mf < 4; mf++)
            #pragma unroll
            for (int nf = 0; nf < 4; nf++) {
                acc[mf][nf] = __builtin_amdgcn_mfma_f32_16x16x32_f16(
                    ah[mf], bh[nf], acc[mf][nf], 0, 0, 0);
                acc[mf][nf] = __builtin_amdgcn_mfma_f32_16x16x32_f16(
                    ah[mf], bl[nf], acc[mf][nf], 0, 0, 0);
                acc[mf][nf] = __builtin_amdgcn_mfma_f32_16x16x32_f16(
                    al[mf], bh[nf], acc[mf][nf], 0, 0, 0);
            }
    }

    // epilogue: C/D layout col = lane&15, row = (lane>>4)*4 + q
    #pragma unroll
    for (int mf = 0; mf < 4; mf++)
        #pragma unroll
        for (int nf = 0; nf < 4; nf++) {
            int col = col0 + wc * 64 + nf * 16 + (lane & 15);
            if (col >= N) continue;
            #pragma unroll
            for (int q = 0; q < 4; q++) {
                int row = row0 + wr * 64 + mf * 16 + (lane >> 4) * 4 + q;
                if (row < M) {
                    float v = acc[mf][nf][q];
                    C[(size_t)row * N + col] = v;
                    Ch[(size_t)row * N + col] = (_Float16)v;
                }
            }
        }
}

// ---------------------------------------------------------------- attention coefs
template <int C>
__global__ __launch_bounds__(256) void coef_kernel(const float* __restrict__ h,
                                                   const float* __restrict__ a_src,
                                                   const float* __restrict__ a_dst,
                                                   float* __restrict__ als,
                                                   float* __restrict__ ald, int n) {
    int wave = threadIdx.x >> 6;
    int lane = threadIdx.x & 63;
    int node = blockIdx.x * 4 + wave;
    if (node >= n) return;
    const float* hr = h + (size_t)node * (4 * C);
    float ps[4], pd[4];
    #pragma unroll
    for (int hh = 0; hh < 4; hh++) {
        float hv = (lane < C) ? hr[hh * C + lane] : 0.f;
        float as_ = (lane < C) ? a_src[hh * C + lane] : 0.f;
        float ad_ = (lane < C) ? a_dst[hh * C + lane] : 0.f;
        ps[hh] = hv * as_;
        pd[hh] = hv * ad_;
    }
    #pragma unroll
    for (int off = 32; off >= 1; off >>= 1) {
        #pragma unroll
        for (int hh = 0; hh < 4; hh++) {
            ps[hh] += __shfl_xor(ps[hh], off, 64);
            pd[hh] += __shfl_xor(pd[hh], off, 64);
        }
    }
    if (lane == 0) {
        #pragma unroll
        for (int hh = 0; hh < 4; hh++) {
            als[node * 4 + hh] = ps[hh];
            ald[node * 4 + hh] = pd[hh];
        }
    }
}

// ---------------------------------------------------------------- softmax weights
__global__ __launch_bounds__(256) void maxden_kernel(const float* __restrict__ als,
                                                     const float* __restrict__ ald,
                                                     const int* __restrict__ row_off,
                                                     const int* __restrict__ csr_src,
                                                     float* __restrict__ w,
                                                     float* __restrict__ den, int n) {
    int wave = threadIdx.x >> 6;
    int lane = threadIdx.x & 63;
    int sl = lane & 15;
    int sub = lane >> 4;
    int node = (blockIdx.x * 4 + wave) * 4 + sub;
    bool act = node < n;
    int rs = act ? row_off[node] : 0;
    int re = act ? row_off[node + 1] : 0;
    float4 ald4 = make_float4(0.f, 0.f, 0.f, 0.f);
    if (act) ald4 = *(const float4*)(ald + (size_t)node * 4);

    float m0 = -INFINITY, m1 = -INFINITY, m2 = -INFINITY, m3 = -INFINITY;
    for (int i = rs + sl; i < re; i += 16) {
        int s = csr_src[i];
        float4 a = *(const float4*)(als + (size_t)s * 4);
        float l0 = a.x + ald4.x; l0 = (l0 > 0.f) ? l0 : NEG_SLOPE * l0;
        float l1 = a.y + ald4.y; l1 = (l1 > 0.f) ? l1 : NEG_SLOPE * l1;
        float l2 = a.z + ald4.z; l2 = (l2 > 0.f) ? l2 : NEG_SLOPE * l2;
        float l3 = a.w + ald4.w; l3 = (l3 > 0.f) ? l3 : NEG_SLOPE * l3;
        m0 = fmaxf(m0, l0); m1 = fmaxf(m1, l1);
        m2 = fmaxf(m2, l2); m3 = fmaxf(m3, l3);
    }
    #pragma unroll
    for (int off = 8; off >= 1; off >>= 1) {
        m0 = fmaxf(m0, __shfl_xor(m0, off, 64));
        m1 = fmaxf(m1, __shfl_xor(m1, off, 64));
        m2 = fmaxf(m2, __shfl_xor(m2, off, 64));
        m3 = fmaxf(m3, __shfl_xor(m3, off, 64));
    }

    float d0 = 0.f, d1 = 0.f, d2 = 0.f, d3 = 0.f;
    for (int i = rs + sl; i < re; i += 16) {
        int s = csr_src[i];
        float4 a = *(const float4*)(als + (size_t)s * 4);
        float l0 = a.x + ald4.x; l0 = (l0 > 0.f) ? l0 : NEG_SLOPE * l0;
        float l1 = a.y + ald4.y; l1 = (l1 > 0.f) ? l1 : NEG_SLOPE * l1;
        float l2 = a.z + ald4.z; l2 = (l2 > 0.f) ? l2 : NEG_SLOPE * l2;
        float l3 = a.w + ald4.w; l3 = (l3 > 0.f) ? l3 : NEG_SLOPE * l3;
        float e0 = __expf(l0 - m0), e1 = __expf(l1 - m1);
        float e2 = __expf(l2 - m2), e3 = __expf(l3 - m3);
        d0 += e0; d1 += e1; d2 += e2; d3 += e3;
        *(float4*)(w + (size_t)i * 4) = make_float4(e0, e1, e2, e3);
    }
    #pragma unroll
    for (int off = 8; off >= 1; off >>= 1) {
        d0 += __shfl_xor(d0, off, 64);
        d1 += __shfl_xor(d1, off, 64);
        d2 += __shfl_xor(d2, off, 64);
        d3 += __shfl_xor(d3, off, 64);
    }
    if (act && sl == 0)
        *(float4*)(den + (size_t)node * 4) = make_float4(d0, d1, d2, d3);
}

// ---------------------------------------------------------------- aggregation
// MODE 0: x1 = elu(v+bias)          -> hi/lo fp16 planes
// MODE 1: x2 = elu(v+bias+res)      -> hi/lo planes; res from rh/rl planes
// MODE 2: out = mean_h(v)+bias      -> fp32 d_out (C=40)
template <int C, int MODE>
__global__ __launch_bounds__(256) void agg_kernel(const __half* __restrict__ hh,
                                                  const float* __restrict__ w,
                                                  const float* __restrict__ den,
                                                  const int* __restrict__ row_off,
                                                  const int* __restrict__ csr_src,
                                                  const float* __restrict__ bias,
                                                  const _Float16* __restrict__ rh,
                                                  const _Float16* __restrict__ rl,
                                                  float* __restrict__ outf,
                                                  _Float16* __restrict__ oh,
                                                  _Float16* __restrict__ ol, int n) {
    constexpr int HC = 4 * C;
    constexpr int LPN = HC / 4;      // active lanes (64 or 40)
    constexpr int LPH = C / 4;       // lanes per head (16 or 10)
    int wave = threadIdx.x >> 6;
    int lane = threadIdx.x & 63;
    int node = blockIdx.x * 4 + wave;
    if (node >= n) return;
    int rs = row_off[node];
    int re = row_off[node + 1];
    int g = lane / LPH; if (g > 3) g = 3;
    const bool active = (LPN == 64) || (lane < LPN);

    float ax = 0.f, ay = 0.f, az = 0.f, aw = 0.f;
    int j = rs;
    for (; j + 8 <= re; j += 8) {
        int s[8];
        float wv[8];
        #pragma unroll
        for (int q = 0; q < 8; q++) {
            s[q] = csr_src[j + q];
            wv[q] = w[(size_t)(j + q) * 4 + g];
        }
        if (active) {
            h2x2 hv[8];
            #pragma unroll
            for (int q = 0; q < 8; q++)
                hv[q] = *(const h2x2*)(hh + (size_t)s[q] * HC + lane * 4);
            #pragma unroll
            for (int q = 0; q < 8; q++) {
                float2 f01 = __half22float2(hv[q].a);
                float2 f23 = __half22float2(hv[q].b);
                ax = fmaf(wv[q], f01.x, ax); ay = fmaf(wv[q], f01.y, ay);
                az = fmaf(wv[q], f23.x, az); aw = fmaf(wv[q], f23.y, aw);
            }
        }
    }
    for (; j < re; ++j) {
        int s = csr_src[j];
        float ww = w[(size_t)j * 4 + g];
        if (active) {
            h2x2 hv = *(const h2x2*)(hh + (size_t)s * HC + lane * 4);
            float2 f01 = __half22float2(hv.a);
            float2 f23 = __half22float2(hv.b);
            ax = fmaf(ww, f01.x, ax); ay = fmaf(ww, f01.y, ay);
            az = fmaf(ww, f23.x, az); aw = fmaf(ww, f23.y, aw);
        }
    }

    float dg = den[(size_t)node * 4 + g];
    float inv = 1.f / (dg + 1e-16f);
    float4 v = make_float4(ax * inv, ay * inv, az * inv, aw * inv);

    if (MODE == 2) {
        float4 vs = v;
        #pragma unroll
        for (int k = 1; k < 4; k++) {
            int srcl = lane + k * LPH;
            vs.x += __shfl(v.x, srcl, 64);
            vs.y += __shfl(v.y, srcl, 64);
            vs.z += __shfl(v.z, srcl, 64);
            vs.w += __shfl(v.w, srcl, 64);
        }
        if (lane < LPH) {
            float4 b4 = *(const float4*)(bias + lane * 4);
            float4 o = make_float4(vs.x * 0.25f + b4.x, vs.y * 0.25f + b4.y,
                                   vs.z * 0.25f + b4.z, vs.w * 0.25f + b4.w);
            *(float4*)(outf + (size_t)node * C + lane * 4) = o;
        }
    } else {
        if (active) {
            float4 b4 = *(const float4*)(bias + lane * 4);
            float4 o = make_float4(v.x + b4.x, v.y + b4.y, v.z + b4.z, v.w + b4.w);
            if (MODE == 1) {
                size_t ridx = (size_t)node * HC + lane * 4;
                half4 r_h = *(const half4*)(rh + ridx);
                half4 r_l = *(const half4*)(rl + ridx);
                o.x += (float)r_h.x + (float)r_l.x;
                o.y += (float)r_h.y + (float)r_l.y;
                o.z += (float)r_h.z + (float)r_l.z;
                o.w += (float)r_h.w + (float)r_l.w;
            }
            o.x = (o.x > 0.f) ? o.x : expm1f(o.x);
            o.y = (o.y > 0.f) ? o.y : expm1f(o.y);
            o.z = (o.z > 0.f) ? o.z : expm1f(o.z);
            o.w = (o.w > 0.f) ? o.w : expm1f(o.w);
            half4 hv4, lv4;
            hv4.x = (_Float16)o.x; lv4.x = (_Float16)(o.x - (float)hv4.x);
            hv4.y = (_Float16)o.y; lv4.y = (_Float16)(o.y - (float)hv4.y);
            hv4.z = (_Float16)o.z; lv4.z = (_Float16)(o.z - (float)hv4.z);
            hv4.w = (_Float16)o.w; lv4.w = (_Float16)(o.w - (float)hv4.w);
            size_t oidx = (size_t)node * HC + lane * 4;
            *(half4*)(oh + oidx) = hv4;
            *(half4*)(ol + oidx) = lv4;
        }
    }
}

// ---------------------------------------------------------------- launch
extern "C" void kernel_launch(void* const* d_in, const int* in_sizes, int n_in,
                              void* d_out, int out_size, void* d_ws, size_t ws_size,
                              hipStream_t stream) {
    const float* x   = (const float*)d_in[0];
    const int*   ei  = (const int*)d_in[1];
    const float* W1  = (const float*)d_in[2];
    const float* a1s = (const float*)d_in[3];
    const float* a1d = (const float*)d_in[4];
    const float* b1  = (const float*)d_in[5];
    const float* W2  = (const float*)d_in[6];
    const float* a2s = (const float*)d_in[7];
    const float* a2d = (const float*)d_in[8];
    const float* b2  = (const float*)d_in[9];
    const float* W3  = (const float*)d_in[10];
    const float* a3s = (const float*)d_in[11];
    const float* a3d = (const float*)d_in[12];
    const float* b3  = (const float*)d_in[13];
    float* out = (float*)d_out;

    int N = in_sizes[0] / 128;
    int E = in_sizes[1] / 2;

    char* ws = (char*)d_ws;
    size_t off = 0;
    auto alloc = [&](size_t bytes) -> void* {
        void* p = ws + off;
        off += (bytes + 255) & ~(size_t)255;
        return p;
    };
    float*    hbuf  = (float*)alloc((size_t)N * 256 * 4);      // GEMM C (fp32)
    _Float16* hhalf = (_Float16*)alloc((size_t)N * 256 * 2);   // GEMM Ch (fp16)
    _Float16* pA_hi = (_Float16*)alloc((size_t)N * 256 * 2);   // x planes / x2 planes
    _Float16* pA_lo = (_Float16*)alloc((size_t)N * 256 * 2);
    _Float16* pB_hi = (_Float16*)alloc((size_t)N * 256 * 2);   // x1 planes
    _Float16* pB_lo = (_Float16*)alloc((size_t)N * 256 * 2);
    float*    als   = (float*)alloc((size_t)N * 4 * 4);
    float*    ald   = (float*)alloc((size_t)N * 4 * 4);
    float*    wbuf  = (float*)alloc((size_t)(E + N) * 4 * 4);
    float*    den   = (float*)alloc((size_t)N * 4 * 4);
    _Float16* bt1h  = (_Float16*)alloc(256 * 128 * 2);
    _Float16* bt1l  = (_Float16*)alloc(256 * 128 * 2);
    _Float16* bt2h  = (_Float16*)alloc(256 * 256 * 2);
    _Float16* bt2l  = (_Float16*)alloc(256 * 256 * 2);
    _Float16* bt3h  = (_Float16*)alloc(256 * 256 * 2);
    _Float16* bt3l  = (_Float16*)alloc(256 * 256 * 2);
    int* deg     = (int*)alloc((size_t)N * 4);
    int* row_off = (int*)alloc((size_t)(N + 1) * 4);
    int* cursor  = (int*)alloc((size_t)N * 4);
    int* csr     = (int*)alloc((size_t)(E + N) * 4);
    int* bsums   = (int*)alloc(1024 * 4);

    int tot = E + N;
    int nb = (N + 1023) / 1024;
    hipMemsetAsync(deg, 0, (size_t)N * 4, stream);
    degree_kernel<<<(tot + 255) / 256, 256, 0, stream>>>(ei, E, N, deg);
    scan_block<<<nb, 1024, 0, stream>>>(deg, row_off, bsums, N);
    scan_sums<<<1, 64, 0, stream>>>(bsums, nb, row_off, N);
    scan_add<<<nb, 1024, 0, stream>>>(row_off, bsums, cursor, N);
    scatter_kernel<<<(tot + 255) / 256, 256, 0, stream>>>(ei, E, N, cursor, csr);

    // input + weight splits
    {
        int n4 = N * 128 / 4;
        split_f32x4<<<(n4 + 255) / 256, 256, 0, stream>>>(x, pA_hi, pA_lo, n4);
        wt_split<<<(256 * 128 + 255) / 256, 256, 0, stream>>>(W1, bt1h, bt1l, 128, 256, 256);
        wt_split<<<(256 * 256 + 255) / 256, 256, 0, stream>>>(W2, bt2h, bt2l, 256, 256, 256);
        wt_split<<<(256 * 256 + 255) / 256, 256, 0, stream>>>(W3, bt3h, bt3l, 256, 160, 256);
    }

    int nodeBlocks = (N + 3) / 4;
    int mdBlocks   = (N + 15) / 16;
    dim3 blk(256);
    dim3 ggrid((N + 127) / 128, 2);

    // layer 1: h = x @ W1  (K=128, N=256)
    gemm_mfma<<<ggrid, blk, 0, stream>>>(pA_hi, pA_lo, bt1h, bt1l, hbuf, hhalf, N, 256, 128);
    coef_kernel<64><<<nodeBlocks, blk, 0, stream>>>(hbuf, a1s, a1d, als, ald, N);
    maxden_kernel<<<mdBlocks, blk, 0, stream>>>(als, ald, row_off, csr, wbuf, den, N);
    agg_kernel<64, 0><<<nodeBlocks, blk, 0, stream>>>((const __half*)hhalf, wbuf, den,
        row_off, csr, b1, nullptr, nullptr, nullptr, pB_hi, pB_lo, N);

    // layer 2: h = x1 @ W2  (K=256, N=256); residual = x1 (pB planes)
    gemm_mfma<<<ggrid, blk, 0, stream>>>(pB_hi, pB_lo, bt2h, bt2l, hbuf, hhalf, N, 256, 256);
    coef_kernel<64><<<nodeBlocks, blk, 0, stream>>>(hbuf, a2s, a2d, als, ald, N);
    maxden_kernel<<<mdBlocks, blk, 0, stream>>>(als, ald, row_off, csr, wbuf, den, N);
    agg_kernel<64, 1><<<nodeBlocks, blk, 0, stream>>>((const __half*)hhalf, wbuf, den,
        row_off, csr, b2, pB_hi, pB_lo, nullptr, pA_hi, pA_lo, N);

    // layer 3: h = x2 @ W3  (K=256, N=160)
    gemm_mfma<<<ggrid, blk, 0, stream>>>(pA_hi, pA_lo, bt3h, bt3l, hbuf, hhalf, N, 160, 256);
    coef_kernel<40><<<nodeBlocks, blk, 0, stream>>>(hbuf, a3s, a3d, als, ald, N);
    maxden_kernel<<<mdBlocks, blk, 0, stream>>>(als, ald, row_off, csr, wbuf, den, N);
    agg_kernel<40, 2><<<nodeBlocks, blk, 0, stream>>>((const __half*)hhalf, wbuf, den,
        row_off, csr, b3, nullptr, nullptr, out, nullptr, nullptr, N);
}

// Round 6
// 551.189 us; speedup vs baseline: 1.4669x; 1.0710x over previous
//
#include <hip/hip_runtime.h>
#include <hip/hip_bf16.h>
#include <hip/hip_fp16.h>
#include <math.h>

#define NEG_SLOPE 0.2f

typedef _Float16 half8 __attribute__((ext_vector_type(8)));
typedef _Float16 half4 __attribute__((ext_vector_type(4)));
typedef float f32x4 __attribute__((ext_vector_type(4)));

struct h2x2 { __half2 a, b; };   // 4 halves, 8 bytes

// ---------------------------------------------------------------- CSR build
__global__ void degree_kernel(const int* __restrict__ ei, int E, int n,
                              int* __restrict__ deg) {
    int e = blockIdx.x * 256 + threadIdx.x;
    int tot = E + n;
    if (e >= tot) return;
    int d = (e < E) ? ei[E + e] : (e - E);
    atomicAdd(&deg[d], 1);
}

__global__ __launch_bounds__(1024) void scan_block(const int* __restrict__ deg,
                                                   int* __restrict__ row_off,
                                                   int* __restrict__ bsums, int n) {
    __shared__ int tmp[1024];
    int t = threadIdx.x;
    int idx = blockIdx.x * 1024 + t;
    int v = (idx < n) ? deg[idx] : 0;
    tmp[t] = v;
    __syncthreads();
    #pragma unroll
    for (int off = 1; off < 1024; off <<= 1) {
        int x = (t >= off) ? tmp[t - off] : 0;
        __syncthreads();
        tmp[t] += x;
        __syncthreads();
    }
    if (idx < n) row_off[idx] = tmp[t] - v;
    if (t == 1023) bsums[blockIdx.x] = tmp[1023];
}

__global__ __launch_bounds__(64) void scan_sums(int* __restrict__ bsums, int nb,
                                                int* __restrict__ row_off, int n) {
    int lane = threadIdx.x;
    int carry = 0;
    for (int base = 0; base < nb; base += 64) {
        int i = base + lane;
        int o = (i < nb) ? bsums[i] : 0;
        int v = o;
        #pragma unroll
        for (int off = 1; off < 64; off <<= 1) {
            int x = __shfl_up(v, off, 64);
            if (lane >= off) v += x;
        }
        if (i < nb) bsums[i] = carry + v - o;
        int tot = __shfl(v, 63, 64);
        carry += tot;
    }
    if (lane == 0) row_off[n] = carry;
}

__global__ __launch_bounds__(1024) void scan_add(int* __restrict__ row_off,
                                                 const int* __restrict__ bsums,
                                                 int* __restrict__ cursor, int n) {
    int idx = blockIdx.x * 1024 + threadIdx.x;
    if (idx < n) {
        int v = row_off[idx] + bsums[blockIdx.x];
        row_off[idx] = v;
        cursor[idx] = v;
    }
}

__global__ void scatter_kernel(const int* __restrict__ ei, int E, int n,
                               int* __restrict__ cursor, int* __restrict__ csr_src) {
    int e = blockIdx.x * 256 + threadIdx.x;
    int tot = E + n;
    if (e >= tot) return;
    int s, d;
    if (e < E) { s = ei[e]; d = ei[E + e]; } else { s = d = e - E; }
    int pos = atomicAdd(&cursor[d], 1);
    csr_src[pos] = s;
}

// ---------------------------------------------------------------- splits
__global__ void split_f32x4(const float* __restrict__ src, _Float16* __restrict__ hi,
                            _Float16* __restrict__ lo, int n4) {
    int i = blockIdx.x * 256 + threadIdx.x;
    if (i >= n4) return;
    float4 v = ((const float4*)src)[i];
    half4 h, l;
    h.x = (_Float16)v.x; l.x = (_Float16)(v.x - (float)h.x);
    h.y = (_Float16)v.y; l.y = (_Float16)(v.y - (float)h.y);
    h.z = (_Float16)v.z; l.z = (_Float16)(v.z - (float)h.z);
    h.w = (_Float16)v.w; l.w = (_Float16)(v.w - (float)h.w);
    ((half4*)hi)[i] = h;
    ((half4*)lo)[i] = l;
}

__global__ void wt_split(const float* __restrict__ W, _Float16* __restrict__ bhi,
                         _Float16* __restrict__ blo, int K, int N, int padN) {
    int idx = blockIdx.x * 256 + threadIdx.x;
    if (idx >= padN * K) return;
    int n = idx / K, k = idx % K;
    float v = (n < N) ? W[(size_t)k * N + n] : 0.f;
    _Float16 h = (_Float16)v;
    bhi[idx] = h;
    blo[idx] = (_Float16)(v - (float)h);
}

// ---------------------------------------------------------------- MFMA GEMM
// C = (Ahi+Alo) @ (Bhi+Blo), 3-term fp16 split, fp32 acc. 128x128 tile,
// 4 waves 2x2, BK=32. Optional fused attention-coef epilogue (C=64 head
// layout: head = blockIdx.y*2 + wc, cols of head fully inside one wave).
__global__ __launch_bounds__(256) void gemm_mfma(const _Float16* __restrict__ Ahi,
                                                 const _Float16* __restrict__ Alo,
                                                 const _Float16* __restrict__ Bthi,
                                                 const _Float16* __restrict__ Btlo,
                                                 float* __restrict__ C,
                                                 _Float16* __restrict__ Ch,
                                                 const float* __restrict__ a_src,
                                                 const float* __restrict__ a_dst,
                                                 float* __restrict__ als,
                                                 float* __restrict__ ald,
                                                 int M, int N, int K) {
    __shared__ _Float16 Ah[2][128 * 32];
    int t = threadIdx.x;
    int wave = t >> 6, lane = t & 63;
    int row0 = blockIdx.x * 128, col0 = blockIdx.y * 128;
    int wr = wave >> 1, wc = wave & 1;

    f32x4 acc[4][4];
    #pragma unroll
    for (int i = 0; i < 4; i++)
        #pragma unroll
        for (int j = 0; j < 4; j++)
            acc[i][j] = (f32x4)0.f;

    auto lds_off = [](int m, int g0) -> int {
        int P = m >> 1;
        int gp = ((m & 1) << 2) | g0;
        return P * 64 + ((gp ^ (P & 7)) << 3);
    };

    for (int k0 = 0; k0 < K; k0 += 32) {
        __syncthreads();
        #pragma unroll
        for (int i = 0; i < 2; i++) {
            int s = t + i * 256;
            int r = s >> 2, g0 = s & 3;
            int grow = row0 + r;
            half8 vh = {}, vl = {};
            if (grow < M) {
                vh = *(const half8*)(Ahi + (size_t)grow * K + k0 + g0 * 8);
                vl = *(const half8*)(Alo + (size_t)grow * K + k0 + g0 * 8);
            }
            int off = lds_off(r, g0);
            *(half8*)(&Ah[0][off]) = vh;
            *(half8*)(&Ah[1][off]) = vl;
        }
        __syncthreads();

        half8 bh[4], bl[4];
        #pragma unroll
        for (int nf = 0; nf < 4; nf++) {
            int n = col0 + wc * 64 + nf * 16 + (lane & 15);
            size_t bo = (size_t)n * K + k0 + (lane >> 4) * 8;
            bh[nf] = *(const half8*)(Bthi + bo);
            bl[nf] = *(const half8*)(Btlo + bo);
        }
        half8 ah[4], al[4];
        #pragma unroll
        for (int mf = 0; mf < 4; mf++) {
            int m = wr * 64 + mf * 16 + (lane & 15);
            int off = lds_off(m, lane >> 4);
            ah[mf] = *(half8*)(&Ah[0][off]);
            al[mf] = *(half8*)(&Ah[1][off]);
        }
        #pragma unroll
        for (int mf = 0; mf < 4; mf++)
            #pragma unroll
            for (int nf = 0; nf < 4; nf++) {
                acc[mf][nf] = __builtin_amdgcn_mfma_f32_16x16x32_f16(
                    ah[mf], bh[nf], acc[mf][nf], 0, 0, 0);
                acc[mf][nf] = __builtin_amdgcn_mfma_f32_16x16x32_f16(
                    ah[mf], bl[nf], acc[mf][nf], 0, 0, 0);
                acc[mf][nf] = __builtin_amdgcn_mfma_f32_16x16x32_f16(
                    al[mf], bh[nf], acc[mf][nf], 0, 0, 0);
            }
    }

    // main store: C/D layout col = lane&15, row = (lane>>4)*4 + q
    #pragma unroll
    for (int mf = 0; mf < 4; mf++)
        #pragma unroll
        for (int nf = 0; nf < 4; nf++) {
            int col = col0 + wc * 64 + nf * 16 + (lane & 15);
            if (col >= N) continue;
            #pragma unroll
            for (int q = 0; q < 4; q++) {
                int row = row0 + wr * 64 + mf * 16 + (lane >> 4) * 4 + q;
                if (row < M) {
                    float v = acc[mf][nf][q];
                    if (C) C[(size_t)row * N + col] = v;
                    Ch[(size_t)row * N + col] = (_Float16)v;
                }
            }
        }

    // fused attention coefficients (C=64 layers): head fully inside this wave
    if (a_src) {
        int hblk = blockIdx.y * 2 + wc;
        float asv[4], adv[4];
        #pragma unroll
        for (int nf = 0; nf < 4; nf++) {
            int cih = nf * 16 + (lane & 15);
            asv[nf] = a_src[hblk * 64 + cih];
            adv[nf] = a_dst[hblk * 64 + cih];
        }
        #pragma unroll
        for (int mf = 0; mf < 4; mf++)
            #pragma unroll
            for (int q = 0; q < 4; q++) {
                float ss = 0.f, sd = 0.f;
                #pragma unroll
                for (int nf = 0; nf < 4; nf++) {
                    float v = acc[mf][nf][q];
                    ss = fmaf(v, asv[nf], ss);
                    sd = fmaf(v, adv[nf], sd);
                }
                #pragma unroll
                for (int off = 8; off >= 1; off >>= 1) {
                    ss += __shfl_xor(ss, off, 64);
                    sd += __shfl_xor(sd, off, 64);
                }
                int row = row0 + wr * 64 + mf * 16 + (lane >> 4) * 4 + q;
                if ((lane & 15) == 0 && row < M) {
                    als[row * 4 + hblk] = ss;
                    ald[row * 4 + hblk] = sd;
                }
            }
    }
}

// ---------------------------------------------------------------- attention coefs (layer 3 only)
template <int C>
__global__ __launch_bounds__(256) void coef_kernel(const float* __restrict__ h,
                                                   const float* __restrict__ a_src,
                                                   const float* __restrict__ a_dst,
                                                   float* __restrict__ als,
                                                   float* __restrict__ ald, int n) {
    int wave = threadIdx.x >> 6;
    int lane = threadIdx.x & 63;
    int node = blockIdx.x * 4 + wave;
    if (node >= n) return;
    const float* hr = h + (size_t)node * (4 * C);
    float ps[4], pd[4];
    #pragma unroll
    for (int hh = 0; hh < 4; hh++) {
        float hv = (lane < C) ? hr[hh * C + lane] : 0.f;
        float as_ = (lane < C) ? a_src[hh * C + lane] : 0.f;
        float ad_ = (lane < C) ? a_dst[hh * C + lane] : 0.f;
        ps[hh] = hv * as_;
        pd[hh] = hv * ad_;
    }
    #pragma unroll
    for (int off = 32; off >= 1; off >>= 1) {
        #pragma unroll
        for (int hh = 0; hh < 4; hh++) {
            ps[hh] += __shfl_xor(ps[hh], off, 64);
            pd[hh] += __shfl_xor(pd[hh], off, 64);
        }
    }
    if (lane == 0) {
        #pragma unroll
        for (int hh = 0; hh < 4; hh++) {
            als[node * 4 + hh] = ps[hh];
            ald[node * 4 + hh] = pd[hh];
        }
    }
}

// ---------------------------------------------------------------- softmax weights
__global__ __launch_bounds__(256) void maxden_kernel(const float* __restrict__ als,
                                                     const float* __restrict__ ald,
                                                     const int* __restrict__ row_off,
                                                     const int* __restrict__ csr_src,
                                                     float* __restrict__ w,
                                                     float* __restrict__ den, int n) {
    int wave = threadIdx.x >> 6;
    int lane = threadIdx.x & 63;
    int sl = lane & 15;
    int sub = lane >> 4;
    int node = (blockIdx.x * 4 + wave) * 4 + sub;
    bool act = node < n;
    int rs = act ? row_off[node] : 0;
    int re = act ? row_off[node + 1] : 0;
    float4 ald4 = make_float4(0.f, 0.f, 0.f, 0.f);
    if (act) ald4 = *(const float4*)(ald + (size_t)node * 4);

    float m0 = -INFINITY, m1 = -INFINITY, m2 = -INFINITY, m3 = -INFINITY;
    for (int i = rs + sl; i < re; i += 16) {
        int s = csr_src[i];
        float4 a = *(const float4*)(als + (size_t)s * 4);
        float l0 = a.x + ald4.x; l0 = (l0 > 0.f) ? l0 : NEG_SLOPE * l0;
        float l1 = a.y + ald4.y; l1 = (l1 > 0.f) ? l1 : NEG_SLOPE * l1;
        float l2 = a.z + ald4.z; l2 = (l2 > 0.f) ? l2 : NEG_SLOPE * l2;
        float l3 = a.w + ald4.w; l3 = (l3 > 0.f) ? l3 : NEG_SLOPE * l3;
        m0 = fmaxf(m0, l0); m1 = fmaxf(m1, l1);
        m2 = fmaxf(m2, l2); m3 = fmaxf(m3, l3);
    }
    #pragma unroll
    for (int off = 8; off >= 1; off >>= 1) {
        m0 = fmaxf(m0, __shfl_xor(m0, off, 64));
        m1 = fmaxf(m1, __shfl_xor(m1, off, 64));
        m2 = fmaxf(m2, __shfl_xor(m2, off, 64));
        m3 = fmaxf(m3, __shfl_xor(m3, off, 64));
    }

    float d0 = 0.f, d1 = 0.f, d2 = 0.f, d3 = 0.f;
    for (int i = rs + sl; i < re; i += 16) {
        int s = csr_src[i];
        float4 a = *(const float4*)(als + (size_t)s * 4);
        float l0 = a.x + ald4.x; l0 = (l0 > 0.f) ? l0 : NEG_SLOPE * l0;
        float l1 = a.y + ald4.y; l1 = (l1 > 0.f) ? l1 : NEG_SLOPE * l1;
        float l2 = a.z + ald4.z; l2 = (l2 > 0.f) ? l2 : NEG_SLOPE * l2;
        float l3 = a.w + ald4.w; l3 = (l3 > 0.f) ? l3 : NEG_SLOPE * l3;
        float e0 = __expf(l0 - m0), e1 = __expf(l1 - m1);
        float e2 = __expf(l2 - m2), e3 = __expf(l3 - m3);
        d0 += e0; d1 += e1; d2 += e2; d3 += e3;
        *(float4*)(w + (size_t)i * 4) = make_float4(e0, e1, e2, e3);
    }
    #pragma unroll
    for (int off = 8; off >= 1; off >>= 1) {
        d0 += __shfl_xor(d0, off, 64);
        d1 += __shfl_xor(d1, off, 64);
        d2 += __shfl_xor(d2, off, 64);
        d3 += __shfl_xor(d3, off, 64);
    }
    if (act && sl == 0)
        *(float4*)(den + (size_t)node * 4) = make_float4(d0, d1, d2, d3);
}

// ---------------------------------------------------------------- aggregation
// Double-buffered 8-edge gather batches: batch B's 8 row-gathers are in
// flight while batch A's FMAs run.
template <int C, int MODE>
__global__ __launch_bounds__(256) void agg_kernel(const __half* __restrict__ hh,
                                                  const float* __restrict__ w,
                                                  const float* __restrict__ den,
                                                  const int* __restrict__ row_off,
                                                  const int* __restrict__ csr_src,
                                                  const float* __restrict__ bias,
                                                  const _Float16* __restrict__ rh,
                                                  const _Float16* __restrict__ rl,
                                                  float* __restrict__ outf,
                                                  _Float16* __restrict__ oh,
                                                  _Float16* __restrict__ ol, int n) {
    constexpr int HC = 4 * C;
    constexpr int LPN = HC / 4;
    constexpr int LPH = C / 4;
    int wave = threadIdx.x >> 6;
    int lane = threadIdx.x & 63;
    int node = blockIdx.x * 4 + wave;
    if (node >= n) return;
    int rs = row_off[node];
    int re = row_off[node + 1];
    int g = lane / LPH; if (g > 3) g = 3;

    float ax = 0.f, ay = 0.f, az = 0.f, aw = 0.f;
    int j = rs;
    if (re - rs >= 8) {
        float wA[8];
        h2x2 hA[8];
        {
            int sA[8];
            #pragma unroll
            for (int q = 0; q < 8; q++) {
                sA[q] = csr_src[j + q];
                wA[q] = w[(size_t)(j + q) * 4 + g];
            }
            #pragma unroll
            for (int q = 0; q < 8; q++)
                hA[q] = *(const h2x2*)(hh + (size_t)sA[q] * HC + lane * 4);
        }
        j += 8;
        for (; j + 8 <= re; j += 8) {
            int sB[8];
            float wB[8];
            #pragma unroll
            for (int q = 0; q < 8; q++) {
                sB[q] = csr_src[j + q];
                wB[q] = w[(size_t)(j + q) * 4 + g];
            }
            h2x2 hB[8];
            #pragma unroll
            for (int q = 0; q < 8; q++)
                hB[q] = *(const h2x2*)(hh + (size_t)sB[q] * HC + lane * 4);
            #pragma unroll
            for (int q = 0; q < 8; q++) {
                float2 f01 = __half22float2(hA[q].a);
                float2 f23 = __half22float2(hA[q].b);
                ax = fmaf(wA[q], f01.x, ax); ay = fmaf(wA[q], f01.y, ay);
                az = fmaf(wA[q], f23.x, az); aw = fmaf(wA[q], f23.y, aw);
            }
            #pragma unroll
            for (int q = 0; q < 8; q++) { hA[q] = hB[q]; wA[q] = wB[q]; }
        }
        #pragma unroll
        for (int q = 0; q < 8; q++) {
            float2 f01 = __half22float2(hA[q].a);
            float2 f23 = __half22float2(hA[q].b);
            ax = fmaf(wA[q], f01.x, ax); ay = fmaf(wA[q], f01.y, ay);
            az = fmaf(wA[q], f23.x, az); aw = fmaf(wA[q], f23.y, aw);
        }
    }
    for (; j < re; ++j) {
        int s = csr_src[j];
        float ww = w[(size_t)j * 4 + g];
        h2x2 hv = *(const h2x2*)(hh + (size_t)s * HC + lane * 4);
        float2 f01 = __half22float2(hv.a);
        float2 f23 = __half22float2(hv.b);
        ax = fmaf(ww, f01.x, ax); ay = fmaf(ww, f01.y, ay);
        az = fmaf(ww, f23.x, az); aw = fmaf(ww, f23.y, aw);
    }

    float dg = den[(size_t)node * 4 + g];
    float inv = 1.f / (dg + 1e-16f);
    float4 v = make_float4(ax * inv, ay * inv, az * inv, aw * inv);

    if (MODE == 2) {
        float4 vs = v;
        #pragma unroll
        for (int k = 1; k < 4; k++) {
            int srcl = lane + k * LPH;
            vs.x += __shfl(v.x, srcl, 64);
            vs.y += __shfl(v.y, srcl, 64);
            vs.z += __shfl(v.z, srcl, 64);
            vs.w += __shfl(v.w, srcl, 64);
        }
        if (lane < LPH) {
            float4 b4 = *(const float4*)(bias + lane * 4);
            float4 o = make_float4(vs.x * 0.25f + b4.x, vs.y * 0.25f + b4.y,
                                   vs.z * 0.25f + b4.z, vs.w * 0.25f + b4.w);
            *(float4*)(outf + (size_t)node * C + lane * 4) = o;
        }
    } else {
        if ((LPN == 64) || (lane < LPN)) {
            float4 b4 = *(const float4*)(bias + lane * 4);
            float4 o = make_float4(v.x + b4.x, v.y + b4.y, v.z + b4.z, v.w + b4.w);
            if (MODE == 1) {
                size_t ridx = (size_t)node * HC + lane * 4;
                half4 r_h = *(const half4*)(rh + ridx);
                half4 r_l = *(const half4*)(rl + ridx);
                o.x += (float)r_h.x + (float)r_l.x;
                o.y += (float)r_h.y + (float)r_l.y;
                o.z += (float)r_h.z + (float)r_l.z;
                o.w += (float)r_h.w + (float)r_l.w;
            }
            o.x = (o.x > 0.f) ? o.x : expm1f(o.x);
            o.y = (o.y > 0.f) ? o.y : expm1f(o.y);
            o.z = (o.z > 0.f) ? o.z : expm1f(o.z);
            o.w = (o.w > 0.f) ? o.w : expm1f(o.w);
            half4 hv4, lv4;
            hv4.x = (_Float16)o.x; lv4.x = (_Float16)(o.x - (float)hv4.x);
            hv4.y = (_Float16)o.y; lv4.y = (_Float16)(o.y - (float)hv4.y);
            hv4.z = (_Float16)o.z; lv4.z = (_Float16)(o.z - (float)hv4.z);
            hv4.w = (_Float16)o.w; lv4.w = (_Float16)(o.w - (float)hv4.w);
            size_t oidx = (size_t)node * HC + lane * 4;
            *(half4*)(oh + oidx) = hv4;
            *(half4*)(ol + oidx) = lv4;
        }
    }
}

// ---------------------------------------------------------------- launch
extern "C" void kernel_launch(void* const* d_in, const int* in_sizes, int n_in,
                              void* d_out, int out_size, void* d_ws, size_t ws_size,
                              hipStream_t stream) {
    const float* x   = (const float*)d_in[0];
    const int*   ei  = (const int*)d_in[1];
    const float* W1  = (const float*)d_in[2];
    const float* a1s = (const float*)d_in[3];
    const float* a1d = (const float*)d_in[4];
    const float* b1  = (const float*)d_in[5];
    const float* W2  = (const float*)d_in[6];
    const float* a2s = (const float*)d_in[7];
    const float* a2d = (const float*)d_in[8];
    const float* b2  = (const float*)d_in[9];
    const float* W3  = (const float*)d_in[10];
    const float* a3s = (const float*)d_in[11];
    const float* a3d = (const float*)d_in[12];
    const float* b3  = (const float*)d_in[13];
    float* out = (float*)d_out;

    int N = in_sizes[0] / 128;
    int E = in_sizes[1] / 2;

    char* ws = (char*)d_ws;
    size_t off = 0;
    auto alloc = [&](size_t bytes) -> void* {
        void* p = ws + off;
        off += (bytes + 255) & ~(size_t)255;
        return p;
    };
    float*    hbuf  = (float*)alloc((size_t)N * 256 * 4);      // layer-3 fp32 C
    _Float16* hhalf = (_Float16*)alloc((size_t)N * 256 * 2);
    _Float16* pA_hi = (_Float16*)alloc((size_t)N * 256 * 2);   // x planes / x2 planes
    _Float16* pA_lo = (_Float16*)alloc((size_t)N * 256 * 2);
    _Float16* pB_hi = (_Float16*)alloc((size_t)N * 256 * 2);   // x1 planes
    _Float16* pB_lo = (_Float16*)alloc((size_t)N * 256 * 2);
    float*    als   = (float*)alloc((size_t)N * 4 * 4);
    float*    ald   = (float*)alloc((size_t)N * 4 * 4);
    float*    wbuf  = (float*)alloc((size_t)(E + N) * 4 * 4);
    float*    den   = (float*)alloc((size_t)N * 4 * 4);
    _Float16* bt1h  = (_Float16*)alloc(256 * 128 * 2);
    _Float16* bt1l  = (_Float16*)alloc(256 * 128 * 2);
    _Float16* bt2h  = (_Float16*)alloc(256 * 256 * 2);
    _Float16* bt2l  = (_Float16*)alloc(256 * 256 * 2);
    _Float16* bt3h  = (_Float16*)alloc(256 * 256 * 2);
    _Float16* bt3l  = (_Float16*)alloc(256 * 256 * 2);
    int* deg     = (int*)alloc((size_t)N * 4);
    int* row_off = (int*)alloc((size_t)(N + 1) * 4);
    int* cursor  = (int*)alloc((size_t)N * 4);
    int* csr     = (int*)alloc((size_t)(E + N) * 4);
    int* bsums   = (int*)alloc(1024 * 4);

    int tot = E + N;
    int nb = (N + 1023) / 1024;
    hipMemsetAsync(deg, 0, (size_t)N * 4, stream);
    degree_kernel<<<(tot + 255) / 256, 256, 0, stream>>>(ei, E, N, deg);
    scan_block<<<nb, 1024, 0, stream>>>(deg, row_off, bsums, N);
    scan_sums<<<1, 64, 0, stream>>>(bsums, nb, row_off, N);
    scan_add<<<nb, 1024, 0, stream>>>(row_off, bsums, cursor, N);
    scatter_kernel<<<(tot + 255) / 256, 256, 0, stream>>>(ei, E, N, cursor, csr);

    {
        int n4 = N * 128 / 4;
        split_f32x4<<<(n4 + 255) / 256, 256, 0, stream>>>(x, pA_hi, pA_lo, n4);
        wt_split<<<(256 * 128 + 255) / 256, 256, 0, stream>>>(W1, bt1h, bt1l, 128, 256, 256);
        wt_split<<<(256 * 256 + 255) / 256, 256, 0, stream>>>(W2, bt2h, bt2l, 256, 256, 256);
        wt_split<<<(256 * 256 + 255) / 256, 256, 0, stream>>>(W3, bt3h, bt3l, 256, 160, 256);
    }

    int nodeBlocks = (N + 3) / 4;
    int mdBlocks   = (N + 15) / 16;
    dim3 blk(256);
    dim3 ggrid((N + 127) / 128, 2);

    // layer 1: h = x @ W1 (K=128); coef fused; no fp32 C
    gemm_mfma<<<ggrid, blk, 0, stream>>>(pA_hi, pA_lo, bt1h, bt1l, nullptr, hhalf,
                                         a1s, a1d, als, ald, N, 256, 128);
    maxden_kernel<<<mdBlocks, blk, 0, stream>>>(als, ald, row_off, csr, wbuf, den, N);
    agg_kernel<64, 0><<<nodeBlocks, blk, 0, stream>>>((const __half*)hhalf, wbuf, den,
        row_off, csr, b1, nullptr, nullptr, nullptr, pB_hi, pB_lo, N);

    // layer 2: h = x1 @ W2 (K=256); coef fused; residual = x1 planes
    gemm_mfma<<<ggrid, blk, 0, stream>>>(pB_hi, pB_lo, bt2h, bt2l, nullptr, hhalf,
                                         a2s, a2d, als, ald, N, 256, 256);
    maxden_kernel<<<mdBlocks, blk, 0, stream>>>(als, ald, row_off, csr, wbuf, den, N);
    agg_kernel<64, 1><<<nodeBlocks, blk, 0, stream>>>((const __half*)hhalf, wbuf, den,
        row_off, csr, b2, pB_hi, pB_lo, nullptr, pA_hi, pA_lo, N);

    // layer 3: h = x2 @ W3 (K=256, N=160); unfused coef (heads straddle tiles)
    gemm_mfma<<<ggrid, blk, 0, stream>>>(pA_hi, pA_lo, bt3h, bt3l, hbuf, hhalf,
                                         nullptr, nullptr, nullptr, nullptr, N, 160, 256);
    coef_kernel<40><<<nodeBlocks, blk, 0, stream>>>(hbuf, a3s, a3d, als, ald, N);
    maxden_kernel<<<mdBlocks, blk, 0, stream>>>(als, ald, row_off, csr, wbuf, den, N);
    agg_kernel<40, 2><<<nodeBlocks, blk, 0, stream>>>((const __half*)hhalf, wbuf, den,
        row_off, csr, b3, nullptr, nullptr, out, nullptr, nullptr, N);
}

// Round 7
// 492.713 us; speedup vs baseline: 1.6410x; 1.1187x over previous
//
#include <hip/hip_runtime.h>
#include <hip/hip_bf16.h>
#include <hip/hip_fp16.h>
#include <math.h>

#define NEG_SLOPE 0.2f

typedef _Float16 half8 __attribute__((ext_vector_type(8)));
typedef _Float16 half4 __attribute__((ext_vector_type(4)));
typedef float f32x4 __attribute__((ext_vector_type(4)));

// ---------------------------------------------------------------- CSR build
__global__ void degree_kernel(const int* __restrict__ ei, int E, int n,
                              int* __restrict__ deg) {
    int e = blockIdx.x * 256 + threadIdx.x;
    int tot = E + n;
    if (e >= tot) return;
    int d = (e < E) ? ei[E + e] : (e - E);
    atomicAdd(&deg[d], 1);
}

__global__ __launch_bounds__(1024) void scan_block(const int* __restrict__ deg,
                                                   int* __restrict__ row_off,
                                                   int* __restrict__ bsums, int n) {
    __shared__ int tmp[1024];
    int t = threadIdx.x;
    int idx = blockIdx.x * 1024 + t;
    int v = (idx < n) ? deg[idx] : 0;
    tmp[t] = v;
    __syncthreads();
    #pragma unroll
    for (int off = 1; off < 1024; off <<= 1) {
        int x = (t >= off) ? tmp[t - off] : 0;
        __syncthreads();
        tmp[t] += x;
        __syncthreads();
    }
    if (idx < n) row_off[idx] = tmp[t] - v;
    if (t == 1023) bsums[blockIdx.x] = tmp[1023];
}

__global__ __launch_bounds__(64) void scan_sums(int* __restrict__ bsums, int nb,
                                                int* __restrict__ row_off, int n) {
    int lane = threadIdx.x;
    int carry = 0;
    for (int base = 0; base < nb; base += 64) {
        int i = base + lane;
        int o = (i < nb) ? bsums[i] : 0;
        int v = o;
        #pragma unroll
        for (int off = 1; off < 64; off <<= 1) {
            int x = __shfl_up(v, off, 64);
            if (lane >= off) v += x;
        }
        if (i < nb) bsums[i] = carry + v - o;
        int tot = __shfl(v, 63, 64);
        carry += tot;
    }
    if (lane == 0) row_off[n] = carry;
}

__global__ __launch_bounds__(1024) void scan_add(int* __restrict__ row_off,
                                                 const int* __restrict__ bsums,
                                                 int* __restrict__ cursor, int n) {
    int idx = blockIdx.x * 1024 + threadIdx.x;
    if (idx < n) {
        int v = row_off[idx] + bsums[blockIdx.x];
        row_off[idx] = v;
        cursor[idx] = v;
    }
}

__global__ void scatter_kernel(const int* __restrict__ ei, int E, int n,
                               int* __restrict__ cursor, int* __restrict__ csr_src) {
    int e = blockIdx.x * 256 + threadIdx.x;
    int tot = E + n;
    if (e >= tot) return;
    int s, d;
    if (e < E) { s = ei[e]; d = ei[E + e]; } else { s = d = e - E; }
    int pos = atomicAdd(&cursor[d], 1);
    csr_src[pos] = s;
}

// ---------------------------------------------------------------- splits
__global__ void split_f32x4(const float* __restrict__ src, _Float16* __restrict__ hi,
                            _Float16* __restrict__ lo, int n4) {
    int i = blockIdx.x * 256 + threadIdx.x;
    if (i >= n4) return;
    float4 v = ((const float4*)src)[i];
    half4 h, l;
    h.x = (_Float16)v.x; l.x = (_Float16)(v.x - (float)h.x);
    h.y = (_Float16)v.y; l.y = (_Float16)(v.y - (float)h.y);
    h.z = (_Float16)v.z; l.z = (_Float16)(v.z - (float)h.z);
    h.w = (_Float16)v.w; l.w = (_Float16)(v.w - (float)h.w);
    ((half4*)hi)[i] = h;
    ((half4*)lo)[i] = l;
}

__global__ void wt_split(const float* __restrict__ W, _Float16* __restrict__ bhi,
                         _Float16* __restrict__ blo, int K, int N, int padN) {
    int idx = blockIdx.x * 256 + threadIdx.x;
    if (idx >= padN * K) return;
    int n = idx / K, k = idx % K;
    float v = (n < N) ? W[(size_t)k * N + n] : 0.f;
    _Float16 h = (_Float16)v;
    bhi[idx] = h;
    blo[idx] = (_Float16)(v - (float)h);
}

// ---------------------------------------------------------------- MFMA GEMM
__global__ __launch_bounds__(256) void gemm_mfma(const _Float16* __restrict__ Ahi,
                                                 const _Float16* __restrict__ Alo,
                                                 const _Float16* __restrict__ Bthi,
                                                 const _Float16* __restrict__ Btlo,
                                                 float* __restrict__ C,
                                                 _Float16* __restrict__ Ch,
                                                 const float* __restrict__ a_src,
                                                 const float* __restrict__ a_dst,
                                                 float* __restrict__ als,
                                                 float* __restrict__ ald,
                                                 int M, int N, int K) {
    __shared__ _Float16 Ah[2][128 * 32];
    int t = threadIdx.x;
    int wave = t >> 6, lane = t & 63;
    int row0 = blockIdx.x * 128, col0 = blockIdx.y * 128;
    int wr = wave >> 1, wc = wave & 1;

    f32x4 acc[4][4];
    #pragma unroll
    for (int i = 0; i < 4; i++)
        #pragma unroll
        for (int j = 0; j < 4; j++)
            acc[i][j] = (f32x4)0.f;

    auto lds_off = [](int m, int g0) -> int {
        int P = m >> 1;
        int gp = ((m & 1) << 2) | g0;
        return P * 64 + ((gp ^ (P & 7)) << 3);
    };

    for (int k0 = 0; k0 < K; k0 += 32) {
        __syncthreads();
        #pragma unroll
        for (int i = 0; i < 2; i++) {
            int s = t + i * 256;
            int r = s >> 2, g0 = s & 3;
            int grow = row0 + r;
            half8 vh = {}, vl = {};
            if (grow < M) {
                vh = *(const half8*)(Ahi + (size_t)grow * K + k0 + g0 * 8);
                vl = *(const half8*)(Alo + (size_t)grow * K + k0 + g0 * 8);
            }
            int off = lds_off(r, g0);
            *(half8*)(&Ah[0][off]) = vh;
            *(half8*)(&Ah[1][off]) = vl;
        }
        __syncthreads();

        half8 bh[4], bl[4];
        #pragma unroll
        for (int nf = 0; nf < 4; nf++) {
            int n = col0 + wc * 64 + nf * 16 + (lane & 15);
            size_t bo = (size_t)n * K + k0 + (lane >> 4) * 8;
            bh[nf] = *(const half8*)(Bthi + bo);
            bl[nf] = *(const half8*)(Btlo + bo);
        }
        half8 ah[4], al[4];
        #pragma unroll
        for (int mf = 0; mf < 4; mf++) {
            int m = wr * 64 + mf * 16 + (lane & 15);
            int off = lds_off(m, lane >> 4);
            ah[mf] = *(half8*)(&Ah[0][off]);
            al[mf] = *(half8*)(&Ah[1][off]);
        }
        #pragma unroll
        for (int mf = 0; mf < 4; mf++)
            #pragma unroll
            for (int nf = 0; nf < 4; nf++) {
                acc[mf][nf] = __builtin_amdgcn_mfma_f32_16x16x32_f16(
                    ah[mf], bh[nf], acc[mf][nf], 0, 0, 0);
                acc[mf][nf] = __builtin_amdgcn_mfma_f32_16x16x32_f16(
                    ah[mf], bl[nf], acc[mf][nf], 0, 0, 0);
                acc[mf][nf] = __builtin_amdgcn_mfma_f32_16x16x32_f16(
                    al[mf], bh[nf], acc[mf][nf], 0, 0, 0);
            }
    }

    #pragma unroll
    for (int mf = 0; mf < 4; mf++)
        #pragma unroll
        for (int nf = 0; nf < 4; nf++) {
            int col = col0 + wc * 64 + nf * 16 + (lane & 15);
            if (col >= N) continue;
            #pragma unroll
            for (int q = 0; q < 4; q++) {
                int row = row0 + wr * 64 + mf * 16 + (lane >> 4) * 4 + q;
                if (row < M) {
                    float v = acc[mf][nf][q];
                    if (C) C[(size_t)row * N + col] = v;
                    Ch[(size_t)row * N + col] = (_Float16)v;
                }
            }
        }

    if (a_src) {
        int hblk = blockIdx.y * 2 + wc;
        float asv[4], adv[4];
        #pragma unroll
        for (int nf = 0; nf < 4; nf++) {
            int cih = nf * 16 + (lane & 15);
            asv[nf] = a_src[hblk * 64 + cih];
            adv[nf] = a_dst[hblk * 64 + cih];
        }
        #pragma unroll
        for (int mf = 0; mf < 4; mf++)
            #pragma unroll
            for (int q = 0; q < 4; q++) {
                float ss = 0.f, sd = 0.f;
                #pragma unroll
                for (int nf = 0; nf < 4; nf++) {
                    float v = acc[mf][nf][q];
                    ss = fmaf(v, asv[nf], ss);
                    sd = fmaf(v, adv[nf], sd);
                }
                #pragma unroll
                for (int off = 8; off >= 1; off >>= 1) {
                    ss += __shfl_xor(ss, off, 64);
                    sd += __shfl_xor(sd, off, 64);
                }
                int row = row0 + wr * 64 + mf * 16 + (lane >> 4) * 4 + q;
                if ((lane & 15) == 0 && row < M) {
                    als[row * 4 + hblk] = ss;
                    ald[row * 4 + hblk] = sd;
                }
            }
    }
}

// ---------------------------------------------------------------- attention coefs (layer 3 only)
template <int C>
__global__ __launch_bounds__(256) void coef_kernel(const float* __restrict__ h,
                                                   const float* __restrict__ a_src,
                                                   const float* __restrict__ a_dst,
                                                   float* __restrict__ als,
                                                   float* __restrict__ ald, int n) {
    int wave = threadIdx.x >> 6;
    int lane = threadIdx.x & 63;
    int node = blockIdx.x * 4 + wave;
    if (node >= n) return;
    const float* hr = h + (size_t)node * (4 * C);
    float ps[4], pd[4];
    #pragma unroll
    for (int hh = 0; hh < 4; hh++) {
        float hv = (lane < C) ? hr[hh * C + lane] : 0.f;
        float as_ = (lane < C) ? a_src[hh * C + lane] : 0.f;
        float ad_ = (lane < C) ? a_dst[hh * C + lane] : 0.f;
        ps[hh] = hv * as_;
        pd[hh] = hv * ad_;
    }
    #pragma unroll
    for (int off = 32; off >= 1; off >>= 1) {
        #pragma unroll
        for (int hh = 0; hh < 4; hh++) {
            ps[hh] += __shfl_xor(ps[hh], off, 64);
            pd[hh] += __shfl_xor(pd[hh], off, 64);
        }
    }
    if (lane == 0) {
        #pragma unroll
        for (int hh = 0; hh < 4; hh++) {
            als[node * 4 + hh] = ps[hh];
            ald[node * 4 + hh] = pd[hh];
        }
    }
}

// ---------------------------------------------------------------- fused softmax + aggregation
// 2 nodes per wave (half-wave each). Lane owns 8 consecutive channels (16B).
// Softmax without max-subtraction (logits ≲ 20 << 88): ex = exp(l), den
// accumulated per lane in-register. Single pass over edges, 8-edge batches,
// next-batch csr/als prefetch.
// MODE 0: x1 = elu(v+bias)          -> hi/lo fp16 planes
// MODE 1: x2 = elu(v+bias+res)      -> hi/lo planes
// MODE 2: out = mean_h(v)+bias      -> fp32 d_out (C=40)
template <int C, int MODE>
__global__ __launch_bounds__(256) void agg_kernel(const __half* __restrict__ hhp,
                                                  const float* __restrict__ als,
                                                  const float* __restrict__ ald,
                                                  const int* __restrict__ row_off,
                                                  const int* __restrict__ csr_src,
                                                  const float* __restrict__ bias,
                                                  const _Float16* __restrict__ rh,
                                                  const _Float16* __restrict__ rl,
                                                  float* __restrict__ outf,
                                                  _Float16* __restrict__ oh,
                                                  _Float16* __restrict__ ol, int n) {
    constexpr int HC = 4 * C;          // halves per row (256 or 160)
    constexpr int LPN = HC / 8;        // lanes per node (32 or 20)
    constexpr int LPH = C / 8;         // lanes per head (8 or 5)
    const _Float16* hh = (const _Float16*)hhp;

    int t = threadIdx.x;
    int wave = t >> 6, lane = t & 63;
    int l = lane & 31;
    int node = (blockIdx.x * 4 + wave) * 2 + (lane >> 5);
    bool nact = node < n;
    bool lact = nact && (l < LPN);
    int g = (l < LPN) ? (l / LPH) : 0;

    int rs = 0, cnt = 0;
    if (lact) {
        rs = row_off[node];
        cnt = row_off[node + 1] - rs;
    }
    float aldg = lact ? ald[node * 4 + g] : 0.f;

    float acc[8] = {};
    float den = 0.f;

    if (cnt > 0) {
        int sA[8];
        float avA[8];
        #pragma unroll
        for (int q = 0; q < 8; q++) {
            int idx = q < cnt ? q : cnt - 1;
            sA[q] = csr_src[rs + idx];
        }
        #pragma unroll
        for (int q = 0; q < 8; q++) avA[q] = als[sA[q] * 4 + g];

        for (int base = 0; base < cnt; base += 8) {
            // issue row gathers for current batch
            half8 hv[8];
            #pragma unroll
            for (int q = 0; q < 8; q++)
                hv[q] = *(const half8*)(hh + (size_t)sA[q] * HC + l * 8);

            // prefetch next batch csr + als
            int sB[8];
            float avB[8];
            if (base + 8 < cnt) {
                #pragma unroll
                for (int q = 0; q < 8; q++) {
                    int idx = base + 8 + q; if (idx >= cnt) idx = cnt - 1;
                    sB[q] = csr_src[rs + idx];
                }
                #pragma unroll
                for (int q = 0; q < 8; q++) avB[q] = als[sB[q] * 4 + g];
            }

            // softmax weights for current batch
            float ex[8];
            #pragma unroll
            for (int q = 0; q < 8; q++) {
                float lg = avA[q] + aldg;
                lg = (lg > 0.f) ? lg : NEG_SLOPE * lg;
                float e = __expf(lg);
                ex[q] = (base + q < cnt) ? e : 0.f;
                den += ex[q];
            }
            // accumulate
            #pragma unroll
            for (int q = 0; q < 8; q++) {
                #pragma unroll
                for (int k = 0; k < 8; k++)
                    acc[k] = fmaf(ex[q], (float)hv[q][k], acc[k]);
            }
            #pragma unroll
            for (int q = 0; q < 8; q++) { sA[q] = sB[q]; avA[q] = avB[q]; }
        }
    }

    float inv = 1.f / (den + 1e-16f);
    float v[8];
    #pragma unroll
    for (int k = 0; k < 8; k++) v[k] = acc[k] * inv;

    if (MODE == 2) {
        // mean over heads: channel c in lane l<5; heads at lanes l+5k
        float vs[8];
        #pragma unroll
        for (int k = 0; k < 8; k++) vs[k] = v[k];
        #pragma unroll
        for (int k2 = 1; k2 < 4; k2++) {
            #pragma unroll
            for (int k = 0; k < 8; k++)
                vs[k] += __shfl(v[k], lane + 5 * k2, 64);
        }
        if (nact && l < 5) {
            float b[8];
            *(float4*)&b[0] = *(const float4*)(bias + l * 8);
            *(float4*)&b[4] = *(const float4*)(bias + l * 8 + 4);
            float o[8];
            #pragma unroll
            for (int k = 0; k < 8; k++) o[k] = vs[k] * 0.25f + b[k];
            *(float4*)(outf + (size_t)node * C + l * 8)     = make_float4(o[0], o[1], o[2], o[3]);
            *(float4*)(outf + (size_t)node * C + l * 8 + 4) = make_float4(o[4], o[5], o[6], o[7]);
        }
    } else {
        if (lact) {
            float b[8];
            *(float4*)&b[0] = *(const float4*)(bias + l * 8);
            *(float4*)&b[4] = *(const float4*)(bias + l * 8 + 4);
            float o[8];
            #pragma unroll
            for (int k = 0; k < 8; k++) o[k] = v[k] + b[k];
            if (MODE == 1) {
                size_t ridx = (size_t)node * HC + l * 8;
                half8 r_h = *(const half8*)(rh + ridx);
                half8 r_l = *(const half8*)(rl + ridx);
                #pragma unroll
                for (int k = 0; k < 8; k++) o[k] += (float)r_h[k] + (float)r_l[k];
            }
            #pragma unroll
            for (int k = 0; k < 8; k++) o[k] = (o[k] > 0.f) ? o[k] : expm1f(o[k]);
            half8 hv8, lv8;
            #pragma unroll
            for (int k = 0; k < 8; k++) {
                hv8[k] = (_Float16)o[k];
                lv8[k] = (_Float16)(o[k] - (float)hv8[k]);
            }
            size_t oidx = (size_t)node * HC + l * 8;
            *(half8*)(oh + oidx) = hv8;
            *(half8*)(ol + oidx) = lv8;
        }
    }
}

// ---------------------------------------------------------------- launch
extern "C" void kernel_launch(void* const* d_in, const int* in_sizes, int n_in,
                              void* d_out, int out_size, void* d_ws, size_t ws_size,
                              hipStream_t stream) {
    const float* x   = (const float*)d_in[0];
    const int*   ei  = (const int*)d_in[1];
    const float* W1  = (const float*)d_in[2];
    const float* a1s = (const float*)d_in[3];
    const float* a1d = (const float*)d_in[4];
    const float* b1  = (const float*)d_in[5];
    const float* W2  = (const float*)d_in[6];
    const float* a2s = (const float*)d_in[7];
    const float* a2d = (const float*)d_in[8];
    const float* b2  = (const float*)d_in[9];
    const float* W3  = (const float*)d_in[10];
    const float* a3s = (const float*)d_in[11];
    const float* a3d = (const float*)d_in[12];
    const float* b3  = (const float*)d_in[13];
    float* out = (float*)d_out;

    int N = in_sizes[0] / 128;
    int E = in_sizes[1] / 2;

    char* ws = (char*)d_ws;
    size_t off = 0;
    auto alloc = [&](size_t bytes) -> void* {
        void* p = ws + off;
        off += (bytes + 255) & ~(size_t)255;
        return p;
    };
    float*    hbuf  = (float*)alloc((size_t)N * 256 * 4);      // layer-3 fp32 C
    _Float16* hhalf = (_Float16*)alloc((size_t)N * 256 * 2);
    _Float16* pA_hi = (_Float16*)alloc((size_t)N * 256 * 2);   // x planes / x2 planes
    _Float16* pA_lo = (_Float16*)alloc((size_t)N * 256 * 2);
    _Float16* pB_hi = (_Float16*)alloc((size_t)N * 256 * 2);   // x1 planes
    _Float16* pB_lo = (_Float16*)alloc((size_t)N * 256 * 2);
    float*    als   = (float*)alloc((size_t)N * 4 * 4);
    float*    ald   = (float*)alloc((size_t)N * 4 * 4);
    _Float16* bt1h  = (_Float16*)alloc(256 * 128 * 2);
    _Float16* bt1l  = (_Float16*)alloc(256 * 128 * 2);
    _Float16* bt2h  = (_Float16*)alloc(256 * 256 * 2);
    _Float16* bt2l  = (_Float16*)alloc(256 * 256 * 2);
    _Float16* bt3h  = (_Float16*)alloc(256 * 256 * 2);
    _Float16* bt3l  = (_Float16*)alloc(256 * 256 * 2);
    int* deg     = (int*)alloc((size_t)N * 4);
    int* row_off = (int*)alloc((size_t)(N + 1) * 4);
    int* cursor  = (int*)alloc((size_t)N * 4);
    int* csr     = (int*)alloc((size_t)(E + N) * 4);
    int* bsums   = (int*)alloc(1024 * 4);

    int tot = E + N;
    int nb = (N + 1023) / 1024;
    hipMemsetAsync(deg, 0, (size_t)N * 4, stream);
    degree_kernel<<<(tot + 255) / 256, 256, 0, stream>>>(ei, E, N, deg);
    scan_block<<<nb, 1024, 0, stream>>>(deg, row_off, bsums, N);
    scan_sums<<<1, 64, 0, stream>>>(bsums, nb, row_off, N);
    scan_add<<<nb, 1024, 0, stream>>>(row_off, bsums, cursor, N);
    scatter_kernel<<<(tot + 255) / 256, 256, 0, stream>>>(ei, E, N, cursor, csr);

    {
        int n4 = N * 128 / 4;
        split_f32x4<<<(n4 + 255) / 256, 256, 0, stream>>>(x, pA_hi, pA_lo, n4);
        wt_split<<<(256 * 128 + 255) / 256, 256, 0, stream>>>(W1, bt1h, bt1l, 128, 256, 256);
        wt_split<<<(256 * 256 + 255) / 256, 256, 0, stream>>>(W2, bt2h, bt2l, 256, 256, 256);
        wt_split<<<(256 * 256 + 255) / 256, 256, 0, stream>>>(W3, bt3h, bt3l, 256, 160, 256);
    }

    int nodeBlocks4 = (N + 3) / 4;   // coef: 4 nodes/block
    int nodeBlocks8 = (N + 7) / 8;   // agg: 8 nodes/block (2 per wave)
    dim3 blk(256);
    dim3 ggrid((N + 127) / 128, 2);

    // layer 1: h = x @ W1 (K=128); coef fused; no fp32 C
    gemm_mfma<<<ggrid, blk, 0, stream>>>(pA_hi, pA_lo, bt1h, bt1l, nullptr, hhalf,
                                         a1s, a1d, als, ald, N, 256, 128);
    agg_kernel<64, 0><<<nodeBlocks8, blk, 0, stream>>>((const __half*)hhalf, als, ald,
        row_off, csr, b1, nullptr, nullptr, nullptr, pB_hi, pB_lo, N);

    // layer 2: h = x1 @ W2 (K=256); coef fused; residual = x1 planes
    gemm_mfma<<<ggrid, blk, 0, stream>>>(pB_hi, pB_lo, bt2h, bt2l, nullptr, hhalf,
                                         a2s, a2d, als, ald, N, 256, 256);
    agg_kernel<64, 1><<<nodeBlocks8, blk, 0, stream>>>((const __half*)hhalf, als, ald,
        row_off, csr, b2, pB_hi, pB_lo, nullptr, pA_hi, pA_lo, N);

    // layer 3: h = x2 @ W3 (K=256, N=160); unfused coef (heads straddle tiles)
    gemm_mfma<<<ggrid, blk, 0, stream>>>(pA_hi, pA_lo, bt3h, bt3l, hbuf, hhalf,
                                         nullptr, nullptr, nullptr, nullptr, N, 160, 256);
    coef_kernel<40><<<nodeBlocks4, blk, 0, stream>>>(hbuf, a3s, a3d, als, ald, N);
    agg_kernel<40, 2><<<nodeBlocks8, blk, 0, stream>>>((const __half*)hhalf, als, ald,
        row_off, csr, b3, nullptr, nullptr, out, nullptr, nullptr, N);
}

// Round 8
// 488.696 us; speedup vs baseline: 1.6545x; 1.0082x over previous
//
#include <hip/hip_runtime.h>
#include <hip/hip_bf16.h>
#include <hip/hip_fp16.h>
#include <math.h>

#define NEG_SLOPE 0.2f

typedef _Float16 half8 __attribute__((ext_vector_type(8)));
typedef _Float16 half4 __attribute__((ext_vector_type(4)));
typedef float f32x4 __attribute__((ext_vector_type(4)));

// ---------------------------------------------------------------- CSR build
__global__ void degree_kernel(const int* __restrict__ ei, int E, int n,
                              int* __restrict__ deg) {
    int e = blockIdx.x * 256 + threadIdx.x;
    int tot = E + n;
    if (e >= tot) return;
    int d = (e < E) ? ei[E + e] : (e - E);
    atomicAdd(&deg[d], 1);
}

__global__ __launch_bounds__(1024) void scan_block(const int* __restrict__ deg,
                                                   int* __restrict__ row_off,
                                                   int* __restrict__ bsums, int n) {
    __shared__ int tmp[1024];
    int t = threadIdx.x;
    int idx = blockIdx.x * 1024 + t;
    int v = (idx < n) ? deg[idx] : 0;
    tmp[t] = v;
    __syncthreads();
    #pragma unroll
    for (int off = 1; off < 1024; off <<= 1) {
        int x = (t >= off) ? tmp[t - off] : 0;
        __syncthreads();
        tmp[t] += x;
        __syncthreads();
    }
    if (idx < n) row_off[idx] = tmp[t] - v;
    if (t == 1023) bsums[blockIdx.x] = tmp[1023];
}

__global__ __launch_bounds__(64) void scan_sums(int* __restrict__ bsums, int nb,
                                                int* __restrict__ row_off, int n) {
    int lane = threadIdx.x;
    int carry = 0;
    for (int base = 0; base < nb; base += 64) {
        int i = base + lane;
        int o = (i < nb) ? bsums[i] : 0;
        int v = o;
        #pragma unroll
        for (int off = 1; off < 64; off <<= 1) {
            int x = __shfl_up(v, off, 64);
            if (lane >= off) v += x;
        }
        if (i < nb) bsums[i] = carry + v - o;
        int tot = __shfl(v, 63, 64);
        carry += tot;
    }
    if (lane == 0) row_off[n] = carry;
}

__global__ __launch_bounds__(1024) void scan_add(int* __restrict__ row_off,
                                                 const int* __restrict__ bsums,
                                                 int* __restrict__ cursor, int n) {
    int idx = blockIdx.x * 1024 + threadIdx.x;
    if (idx < n) {
        int v = row_off[idx] + bsums[blockIdx.x];
        row_off[idx] = v;
        cursor[idx] = v;
    }
}

__global__ void scatter_kernel(const int* __restrict__ ei, int E, int n,
                               int* __restrict__ cursor, int* __restrict__ csr_src) {
    int e = blockIdx.x * 256 + threadIdx.x;
    int tot = E + n;
    if (e >= tot) return;
    int s, d;
    if (e < E) { s = ei[e]; d = ei[E + e]; } else { s = d = e - E; }
    int pos = atomicAdd(&cursor[d], 1);
    csr_src[pos] = s;
}

// ---------------------------------------------------------------- splits
__global__ void split_f32x4(const float* __restrict__ src, _Float16* __restrict__ hi,
                            _Float16* __restrict__ lo, int n4) {
    int i = blockIdx.x * 256 + threadIdx.x;
    if (i >= n4) return;
    float4 v = ((const float4*)src)[i];
    half4 h, l;
    h.x = (_Float16)v.x; l.x = (_Float16)(v.x - (float)h.x);
    h.y = (_Float16)v.y; l.y = (_Float16)(v.y - (float)h.y);
    h.z = (_Float16)v.z; l.z = (_Float16)(v.z - (float)h.z);
    h.w = (_Float16)v.w; l.w = (_Float16)(v.w - (float)h.w);
    ((half4*)hi)[i] = h;
    ((half4*)lo)[i] = l;
}

__global__ void wt_split(const float* __restrict__ W, _Float16* __restrict__ bhi,
                         _Float16* __restrict__ blo, int K, int N, int padN) {
    int idx = blockIdx.x * 256 + threadIdx.x;
    if (idx >= padN * K) return;
    int n = idx / K, k = idx % K;
    float v = (n < N) ? W[(size_t)k * N + n] : 0.f;
    _Float16 h = (_Float16)v;
    bhi[idx] = h;
    blo[idx] = (_Float16)(v - (float)h);
}

// ---------------------------------------------------------------- MFMA GEMM
// 3-term fp16-split, fp32 acc, 128x128 tile, 4 waves 2x2, BK=32.
// Double-buffered A staging: next-tile global loads issued before current
// tile's MFMA, one barrier per K-step. Optional fused coef epilogue (C=64).
__global__ __launch_bounds__(256) void gemm_mfma(const _Float16* __restrict__ Ahi,
                                                 const _Float16* __restrict__ Alo,
                                                 const _Float16* __restrict__ Bthi,
                                                 const _Float16* __restrict__ Btlo,
                                                 _Float16* __restrict__ Ch,
                                                 const float* __restrict__ a_src,
                                                 const float* __restrict__ a_dst,
                                                 float* __restrict__ als,
                                                 float* __restrict__ ald,
                                                 int M, int N, int K) {
    __shared__ _Float16 Ah[2][2][128 * 32];   // [dbuf][plane][slot]
    int t = threadIdx.x;
    int wave = t >> 6, lane = t & 63;
    int row0 = blockIdx.x * 128, col0 = blockIdx.y * 128;
    int wr = wave >> 1, wc = wave & 1;

    f32x4 acc[4][4];
    #pragma unroll
    for (int i = 0; i < 4; i++)
        #pragma unroll
        for (int j = 0; j < 4; j++)
            acc[i][j] = (f32x4)0.f;

    auto lds_off = [](int m, int g0) -> int {
        int P = m >> 1;
        int gp = ((m & 1) << 2) | g0;
        return P * 64 + ((gp ^ (P & 7)) << 3);
    };

    // per-thread staging slots
    int s0 = t, s1 = t + 256;
    int r0 = s0 >> 2, g00 = s0 & 3;
    int r1 = s1 >> 2, g01 = s1 & 3;
    int off0 = lds_off(r0, g00), off1 = lds_off(r1, g01);
    bool m0ok = (row0 + r0) < M, m1ok = (row0 + r1) < M;
    const _Float16* a0h = Ahi + (size_t)(row0 + r0) * K + g00 * 8;
    const _Float16* a0l = Alo + (size_t)(row0 + r0) * K + g00 * 8;
    const _Float16* a1h = Ahi + (size_t)(row0 + r1) * K + g01 * 8;
    const _Float16* a1l = Alo + (size_t)(row0 + r1) * K + g01 * 8;

    half8 svh0, svl0, svh1, svl1;
    auto stage_load = [&](int k0) {
        svh0 = svl0 = svh1 = svl1 = (half8)(_Float16)0.f;
        if (m0ok) { svh0 = *(const half8*)(a0h + k0); svl0 = *(const half8*)(a0l + k0); }
        if (m1ok) { svh1 = *(const half8*)(a1h + k0); svl1 = *(const half8*)(a1l + k0); }
    };
    auto stage_write = [&](int buf) {
        *(half8*)(&Ah[buf][0][off0]) = svh0;
        *(half8*)(&Ah[buf][1][off0]) = svl0;
        *(half8*)(&Ah[buf][0][off1]) = svh1;
        *(half8*)(&Ah[buf][1][off1]) = svl1;
    };

    int nk = K >> 5;
    stage_load(0);
    stage_write(0);
    __syncthreads();

    // hoisted B row bases
    const _Float16* bhp[4];
    const _Float16* blp[4];
    #pragma unroll
    for (int nf = 0; nf < 4; nf++) {
        int n = col0 + wc * 64 + nf * 16 + (lane & 15);
        bhp[nf] = Bthi + (size_t)n * K + (lane >> 4) * 8;
        blp[nf] = Btlo + (size_t)n * K + (lane >> 4) * 8;
    }

    for (int kt = 0; kt < nk; kt++) {
        int cur = kt & 1;
        if (kt + 1 < nk) stage_load((kt + 1) << 5);   // overlap with MFMA below

        int k0 = kt << 5;
        half8 bh[4], bl[4];
        #pragma unroll
        for (int nf = 0; nf < 4; nf++) {
            bh[nf] = *(const half8*)(bhp[nf] + k0);
            bl[nf] = *(const half8*)(blp[nf] + k0);
        }
        half8 ah[4], al[4];
        #pragma unroll
        for (int mf = 0; mf < 4; mf++) {
            int m = wr * 64 + mf * 16 + (lane & 15);
            int off = lds_off(m, lane >> 4);
            ah[mf] = *(half8*)(&Ah[cur][0][off]);
            al[mf] = *(half8*)(&Ah[cur][1][off]);
        }
        #pragma unroll
        for (int mf = 0; mf < 4; mf++)
            #pragma unroll
            for (int nf = 0; nf < 4; nf++) {
                acc[mf][nf] = __builtin_amdgcn_mfma_f32_16x16x32_f16(
                    ah[mf], bh[nf], acc[mf][nf], 0, 0, 0);
                acc[mf][nf] = __builtin_amdgcn_mfma_f32_16x16x32_f16(
                    ah[mf], bl[nf], acc[mf][nf], 0, 0, 0);
                acc[mf][nf] = __builtin_amdgcn_mfma_f32_16x16x32_f16(
                    al[mf], bh[nf], acc[mf][nf], 0, 0, 0);
            }
        if (kt + 1 < nk) {
            stage_write(cur ^ 1);      // compiler inserts vmcnt waits
            __syncthreads();
        }
    }

    // store fp16 shadow: C/D layout col = lane&15, row = (lane>>4)*4 + q
    #pragma unroll
    for (int mf = 0; mf < 4; mf++)
        #pragma unroll
        for (int nf = 0; nf < 4; nf++) {
            int col = col0 + wc * 64 + nf * 16 + (lane & 15);
            if (col >= N) continue;
            #pragma unroll
            for (int q = 0; q < 4; q++) {
                int row = row0 + wr * 64 + mf * 16 + (lane >> 4) * 4 + q;
                if (row < M)
                    Ch[(size_t)row * N + col] = (_Float16)acc[mf][nf][q];
            }
        }

    // fused attention coefficients (C=64 layers)
    if (a_src) {
        int hblk = blockIdx.y * 2 + wc;
        float asv[4], adv[4];
        #pragma unroll
        for (int nf = 0; nf < 4; nf++) {
            int cih = nf * 16 + (lane & 15);
            asv[nf] = a_src[hblk * 64 + cih];
            adv[nf] = a_dst[hblk * 64 + cih];
        }
        #pragma unroll
        for (int mf = 0; mf < 4; mf++)
            #pragma unroll
            for (int q = 0; q < 4; q++) {
                float ss = 0.f, sd = 0.f;
                #pragma unroll
                for (int nf = 0; nf < 4; nf++) {
                    float v = acc[mf][nf][q];
                    ss = fmaf(v, asv[nf], ss);
                    sd = fmaf(v, adv[nf], sd);
                }
                #pragma unroll
                for (int off = 8; off >= 1; off >>= 1) {
                    ss += __shfl_xor(ss, off, 64);
                    sd += __shfl_xor(sd, off, 64);
                }
                int row = row0 + wr * 64 + mf * 16 + (lane >> 4) * 4 + q;
                if ((lane & 15) == 0 && row < M) {
                    als[row * 4 + hblk] = ss;
                    ald[row * 4 + hblk] = sd;
                }
            }
    }
}

// ---------------------------------------------------------------- attention coefs (layer 3, fp16 h)
template <int C>
__global__ __launch_bounds__(256) void coef_kernel(const _Float16* __restrict__ h,
                                                   const float* __restrict__ a_src,
                                                   const float* __restrict__ a_dst,
                                                   float* __restrict__ als,
                                                   float* __restrict__ ald, int n) {
    int wave = threadIdx.x >> 6;
    int lane = threadIdx.x & 63;
    int node = blockIdx.x * 4 + wave;
    if (node >= n) return;
    const _Float16* hr = h + (size_t)node * (4 * C);
    float ps[4], pd[4];
    #pragma unroll
    for (int hh = 0; hh < 4; hh++) {
        float hv = (lane < C) ? (float)hr[hh * C + lane] : 0.f;
        float as_ = (lane < C) ? a_src[hh * C + lane] : 0.f;
        float ad_ = (lane < C) ? a_dst[hh * C + lane] : 0.f;
        ps[hh] = hv * as_;
        pd[hh] = hv * ad_;
    }
    #pragma unroll
    for (int off = 32; off >= 1; off >>= 1) {
        #pragma unroll
        for (int hh = 0; hh < 4; hh++) {
            ps[hh] += __shfl_xor(ps[hh], off, 64);
            pd[hh] += __shfl_xor(pd[hh], off, 64);
        }
    }
    if (lane == 0) {
        #pragma unroll
        for (int hh = 0; hh < 4; hh++) {
            als[node * 4 + hh] = ps[hh];
            ald[node * 4 + hh] = pd[hh];
        }
    }
}

// ---------------------------------------------------------------- fused softmax + aggregation
// Persistent grid-stride over node pairs; 2 nodes per wave, lane owns 8
// channels (16B). No max-subtraction. 8-edge batches with csr/als prefetch.
template <int C, int MODE>
__global__ __launch_bounds__(256) void agg_kernel(const __half* __restrict__ hhp,
                                                  const float* __restrict__ als,
                                                  const float* __restrict__ ald,
                                                  const int* __restrict__ row_off,
                                                  const int* __restrict__ csr_src,
                                                  const float* __restrict__ bias,
                                                  const _Float16* __restrict__ rh,
                                                  const _Float16* __restrict__ rl,
                                                  float* __restrict__ outf,
                                                  _Float16* __restrict__ oh,
                                                  _Float16* __restrict__ ol, int n) {
    constexpr int HC = 4 * C;          // halves per row (256 or 160)
    constexpr int LPN = HC / 8;        // lanes per node (32 or 20)
    constexpr int LPH = C / 8;         // lanes per head (8 or 5)
    const _Float16* hh = (const _Float16*)hhp;

    int t = threadIdx.x;
    int wave = t >> 6, lane = t & 63;
    int l = lane & 31;
    int pairs = (n + 1) >> 1;

    for (int p = blockIdx.x * 4 + wave; p < pairs; p += gridDim.x * 4) {
        int node = p * 2 + (lane >> 5);
        bool nact = node < n;
        bool lact = nact && (l < LPN);
        int g = (l < LPN) ? (l / LPH) : 0;

        int rs = 0, cnt = 0;
        if (lact) {
            rs = row_off[node];
            cnt = row_off[node + 1] - rs;
        }
        float aldg = lact ? ald[node * 4 + g] : 0.f;

        float acc[8] = {};
        float den = 0.f;

        if (cnt > 0) {
            int sA[8];
            float avA[8];
            #pragma unroll
            for (int q = 0; q < 8; q++) {
                int idx = q < cnt ? q : cnt - 1;
                sA[q] = csr_src[rs + idx];
            }
            #pragma unroll
            for (int q = 0; q < 8; q++) avA[q] = als[sA[q] * 4 + g];

            for (int base = 0; base < cnt; base += 8) {
                half8 hv[8];
                #pragma unroll
                for (int q = 0; q < 8; q++)
                    hv[q] = *(const half8*)(hh + (size_t)sA[q] * HC + l * 8);

                int sB[8];
                float avB[8];
                if (base + 8 < cnt) {
                    #pragma unroll
                    for (int q = 0; q < 8; q++) {
                        int idx = base + 8 + q; if (idx >= cnt) idx = cnt - 1;
                        sB[q] = csr_src[rs + idx];
                    }
                    #pragma unroll
                    for (int q = 0; q < 8; q++) avB[q] = als[sB[q] * 4 + g];
                }

                float ex[8];
                #pragma unroll
                for (int q = 0; q < 8; q++) {
                    float lg = avA[q] + aldg;
                    lg = (lg > 0.f) ? lg : NEG_SLOPE * lg;
                    float e = __expf(lg);
                    ex[q] = (base + q < cnt) ? e : 0.f;
                    den += ex[q];
                }
                #pragma unroll
                for (int q = 0; q < 8; q++) {
                    #pragma unroll
                    for (int k = 0; k < 8; k++)
                        acc[k] = fmaf(ex[q], (float)hv[q][k], acc[k]);
                }
                #pragma unroll
                for (int q = 0; q < 8; q++) { sA[q] = sB[q]; avA[q] = avB[q]; }
            }
        }

        float inv = 1.f / (den + 1e-16f);
        float v[8];
        #pragma unroll
        for (int k = 0; k < 8; k++) v[k] = acc[k] * inv;

        if (MODE == 2) {
            float vs[8];
            #pragma unroll
            for (int k = 0; k < 8; k++) vs[k] = v[k];
            #pragma unroll
            for (int k2 = 1; k2 < 4; k2++) {
                #pragma unroll
                for (int k = 0; k < 8; k++)
                    vs[k] += __shfl(v[k], lane + 5 * k2, 64);
            }
            if (nact && l < 5) {
                float b[8];
                *(float4*)&b[0] = *(const float4*)(bias + l * 8);
                *(float4*)&b[4] = *(const float4*)(bias + l * 8 + 4);
                float o[8];
                #pragma unroll
                for (int k = 0; k < 8; k++) o[k] = vs[k] * 0.25f + b[k];
                *(float4*)(outf + (size_t)node * C + l * 8)     = make_float4(o[0], o[1], o[2], o[3]);
                *(float4*)(outf + (size_t)node * C + l * 8 + 4) = make_float4(o[4], o[5], o[6], o[7]);
            }
        } else {
            if (lact) {
                float b[8];
                *(float4*)&b[0] = *(const float4*)(bias + l * 8);
                *(float4*)&b[4] = *(const float4*)(bias + l * 8 + 4);
                float o[8];
                #pragma unroll
                for (int k = 0; k < 8; k++) o[k] = v[k] + b[k];
                if (MODE == 1) {
                    size_t ridx = (size_t)node * HC + l * 8;
                    half8 r_h = *(const half8*)(rh + ridx);
                    half8 r_l = *(const half8*)(rl + ridx);
                    #pragma unroll
                    for (int k = 0; k < 8; k++) o[k] += (float)r_h[k] + (float)r_l[k];
                }
                #pragma unroll
                for (int k = 0; k < 8; k++) o[k] = (o[k] > 0.f) ? o[k] : expm1f(o[k]);
                half8 hv8, lv8;
                #pragma unroll
                for (int k = 0; k < 8; k++) {
                    hv8[k] = (_Float16)o[k];
                    lv8[k] = (_Float16)(o[k] - (float)hv8[k]);
                }
                size_t oidx = (size_t)node * HC + l * 8;
                *(half8*)(oh + oidx) = hv8;
                *(half8*)(ol + oidx) = lv8;
            }
        }
    }
}

// ---------------------------------------------------------------- launch
extern "C" void kernel_launch(void* const* d_in, const int* in_sizes, int n_in,
                              void* d_out, int out_size, void* d_ws, size_t ws_size,
                              hipStream_t stream) {
    const float* x   = (const float*)d_in[0];
    const int*   ei  = (const int*)d_in[1];
    const float* W1  = (const float*)d_in[2];
    const float* a1s = (const float*)d_in[3];
    const float* a1d = (const float*)d_in[4];
    const float* b1  = (const float*)d_in[5];
    const float* W2  = (const float*)d_in[6];
    const float* a2s = (const float*)d_in[7];
    const float* a2d = (const float*)d_in[8];
    const float* b2  = (const float*)d_in[9];
    const float* W3  = (const float*)d_in[10];
    const float* a3s = (const float*)d_in[11];
    const float* a3d = (const float*)d_in[12];
    const float* b3  = (const float*)d_in[13];
    float* out = (float*)d_out;

    int N = in_sizes[0] / 128;
    int E = in_sizes[1] / 2;

    char* ws = (char*)d_ws;
    size_t off = 0;
    auto alloc = [&](size_t bytes) -> void* {
        void* p = ws + off;
        off += (bytes + 255) & ~(size_t)255;
        return p;
    };
    _Float16* hhalf = (_Float16*)alloc((size_t)N * 256 * 2);
    _Float16* pA_hi = (_Float16*)alloc((size_t)N * 256 * 2);   // x planes / x2 planes
    _Float16* pA_lo = (_Float16*)alloc((size_t)N * 256 * 2);
    _Float16* pB_hi = (_Float16*)alloc((size_t)N * 256 * 2);   // x1 planes
    _Float16* pB_lo = (_Float16*)alloc((size_t)N * 256 * 2);
    float*    als   = (float*)alloc((size_t)N * 4 * 4);
    float*    ald   = (float*)alloc((size_t)N * 4 * 4);
    _Float16* bt1h  = (_Float16*)alloc(256 * 128 * 2);
    _Float16* bt1l  = (_Float16*)alloc(256 * 128 * 2);
    _Float16* bt2h  = (_Float16*)alloc(256 * 256 * 2);
    _Float16* bt2l  = (_Float16*)alloc(256 * 256 * 2);
    _Float16* bt3h  = (_Float16*)alloc(256 * 256 * 2);
    _Float16* bt3l  = (_Float16*)alloc(256 * 256 * 2);
    int* deg     = (int*)alloc((size_t)N * 4);
    int* row_off = (int*)alloc((size_t)(N + 1) * 4);
    int* cursor  = (int*)alloc((size_t)N * 4);
    int* csr     = (int*)alloc((size_t)(E + N) * 4);
    int* bsums   = (int*)alloc(1024 * 4);

    int tot = E + N;
    int nb = (N + 1023) / 1024;
    hipMemsetAsync(deg, 0, (size_t)N * 4, stream);
    degree_kernel<<<(tot + 255) / 256, 256, 0, stream>>>(ei, E, N, deg);
    scan_block<<<nb, 1024, 0, stream>>>(deg, row_off, bsums, N);
    scan_sums<<<1, 64, 0, stream>>>(bsums, nb, row_off, N);
    scan_add<<<nb, 1024, 0, stream>>>(row_off, bsums, cursor, N);
    scatter_kernel<<<(tot + 255) / 256, 256, 0, stream>>>(ei, E, N, cursor, csr);

    {
        int n4 = N * 128 / 4;
        split_f32x4<<<(n4 + 255) / 256, 256, 0, stream>>>(x, pA_hi, pA_lo, n4);
        wt_split<<<(256 * 128 + 255) / 256, 256, 0, stream>>>(W1, bt1h, bt1l, 128, 256, 256);
        wt_split<<<(256 * 256 + 255) / 256, 256, 0, stream>>>(W2, bt2h, bt2l, 256, 256, 256);
        wt_split<<<(256 * 256 + 255) / 256, 256, 0, stream>>>(W3, bt3h, bt3l, 256, 160, 256);
    }

    int nodeBlocks4 = (N + 3) / 4;   // coef: 4 nodes/block
    int pairs = (N + 1) / 2;
    int aggBlocks = (pairs + 3) / 4;
    if (aggBlocks > 2048) aggBlocks = 2048;
    dim3 blk(256);
    dim3 ggrid((N + 127) / 128, 2);

    // layer 1: h = x @ W1 (K=128); coef fused
    gemm_mfma<<<ggrid, blk, 0, stream>>>(pA_hi, pA_lo, bt1h, bt1l, hhalf,
                                         a1s, a1d, als, ald, N, 256, 128);
    agg_kernel<64, 0><<<aggBlocks, blk, 0, stream>>>((const __half*)hhalf, als, ald,
        row_off, csr, b1, nullptr, nullptr, nullptr, pB_hi, pB_lo, N);

    // layer 2: h = x1 @ W2 (K=256); coef fused; residual = x1 planes
    gemm_mfma<<<ggrid, blk, 0, stream>>>(pB_hi, pB_lo, bt2h, bt2l, hhalf,
                                         a2s, a2d, als, ald, N, 256, 256);
    agg_kernel<64, 1><<<aggBlocks, blk, 0, stream>>>((const __half*)hhalf, als, ald,
        row_off, csr, b2, pB_hi, pB_lo, nullptr, pA_hi, pA_lo, N);

    // layer 3: h = x2 @ W3 (K=256, N=160); coef from fp16 shadow
    gemm_mfma<<<ggrid, blk, 0, stream>>>(pA_hi, pA_lo, bt3h, bt3l, hhalf,
                                         nullptr, nullptr, nullptr, nullptr, N, 160, 256);
    coef_kernel<40><<<nodeBlocks4, blk, 0, stream>>>(hhalf, a3s, a3d, als, ald, N);
    agg_kernel<40, 2><<<aggBlocks, blk, 0, stream>>>((const __half*)hhalf, als, ald,
        row_off, csr, b3, nullptr, nullptr, out, nullptr, nullptr, N);
}

// Round 9
// 459.628 us; speedup vs baseline: 1.7591x; 1.0632x over previous
//
#include <hip/hip_runtime.h>
#include <hip/hip_bf16.h>
#include <hip/hip_fp16.h>
#include <math.h>

#define NEG_SLOPE 0.2f

typedef _Float16 half8 __attribute__((ext_vector_type(8)));
typedef _Float16 half4 __attribute__((ext_vector_type(4)));
typedef float f32x4 __attribute__((ext_vector_type(4)));

// ---------------------------------------------------------------- CSR build
__global__ void degree_kernel(const int* __restrict__ ei, int E, int n,
                              int* __restrict__ deg) {
    int e = blockIdx.x * 256 + threadIdx.x;
    int tot = E + n;
    if (e >= tot) return;
    int d = (e < E) ? ei[E + e] : (e - E);
    atomicAdd(&deg[d], 1);
}

__global__ __launch_bounds__(1024) void scan_block(const int* __restrict__ deg,
                                                   int* __restrict__ row_off,
                                                   int* __restrict__ bsums, int n) {
    __shared__ int tmp[1024];
    int t = threadIdx.x;
    int idx = blockIdx.x * 1024 + t;
    int v = (idx < n) ? deg[idx] : 0;
    tmp[t] = v;
    __syncthreads();
    #pragma unroll
    for (int off = 1; off < 1024; off <<= 1) {
        int x = (t >= off) ? tmp[t - off] : 0;
        __syncthreads();
        tmp[t] += x;
        __syncthreads();
    }
    if (idx < n) row_off[idx] = tmp[t] - v;
    if (t == 1023) bsums[blockIdx.x] = tmp[1023];
}

__global__ __launch_bounds__(64) void scan_sums(int* __restrict__ bsums, int nb,
                                                int* __restrict__ row_off, int n) {
    int lane = threadIdx.x;
    int carry = 0;
    for (int base = 0; base < nb; base += 64) {
        int i = base + lane;
        int o = (i < nb) ? bsums[i] : 0;
        int v = o;
        #pragma unroll
        for (int off = 1; off < 64; off <<= 1) {
            int x = __shfl_up(v, off, 64);
            if (lane >= off) v += x;
        }
        if (i < nb) bsums[i] = carry + v - o;
        int tot = __shfl(v, 63, 64);
        carry += tot;
    }
    if (lane == 0) row_off[n] = carry;
}

__global__ __launch_bounds__(1024) void scan_add(int* __restrict__ row_off,
                                                 const int* __restrict__ bsums,
                                                 int* __restrict__ cursor, int n) {
    int idx = blockIdx.x * 1024 + threadIdx.x;
    if (idx < n) {
        int v = row_off[idx] + bsums[blockIdx.x];
        row_off[idx] = v;
        cursor[idx] = v;
    }
}

__global__ void scatter_kernel(const int* __restrict__ ei, int E, int n,
                               int* __restrict__ cursor, int* __restrict__ csr_src) {
    int e = blockIdx.x * 256 + threadIdx.x;
    int tot = E + n;
    if (e >= tot) return;
    int s, d;
    if (e < E) { s = ei[e]; d = ei[E + e]; } else { s = d = e - E; }
    int pos = atomicAdd(&cursor[d], 1);
    csr_src[pos] = s;
}

// ---------------------------------------------------------------- splits
__global__ void split_f32x4(const float* __restrict__ src, _Float16* __restrict__ hi,
                            _Float16* __restrict__ lo, int n4) {
    int i = blockIdx.x * 256 + threadIdx.x;
    if (i >= n4) return;
    float4 v = ((const float4*)src)[i];
    half4 h, l;
    h.x = (_Float16)v.x; l.x = (_Float16)(v.x - (float)h.x);
    h.y = (_Float16)v.y; l.y = (_Float16)(v.y - (float)h.y);
    h.z = (_Float16)v.z; l.z = (_Float16)(v.z - (float)h.z);
    h.w = (_Float16)v.w; l.w = (_Float16)(v.w - (float)h.w);
    ((half4*)hi)[i] = h;
    ((half4*)lo)[i] = l;
}

// one launch for all three weight transposes/splits
__global__ void wt_split_all(const float* __restrict__ W1, const float* __restrict__ W2,
                             const float* __restrict__ W3,
                             _Float16* __restrict__ b1h, _Float16* __restrict__ b1l,
                             _Float16* __restrict__ b2h, _Float16* __restrict__ b2l,
                             _Float16* __restrict__ b3h, _Float16* __restrict__ b3l) {
    int idx = blockIdx.x * 256 + threadIdx.x;
    const float* W; _Float16 *bh, *bl; int K, N, li;
    if (idx < 256 * 128) {
        W = W1; bh = b1h; bl = b1l; K = 128; N = 256; li = idx;
    } else if (idx < 256 * 128 + 256 * 256) {
        W = W2; bh = b2h; bl = b2l; K = 256; N = 256; li = idx - 256 * 128;
    } else if (idx < 256 * 128 + 2 * 256 * 256) {
        W = W3; bh = b3h; bl = b3l; K = 256; N = 160; li = idx - 256 * 128 - 256 * 256;
    } else return;
    int n = li / K, k = li % K;
    float v = (n < N) ? W[(size_t)k * N + n] : 0.f;
    _Float16 h = (_Float16)v;
    bh[li] = h;
    bl[li] = (_Float16)(v - (float)h);
}

// ---------------------------------------------------------------- MFMA GEMM
// 3-term fp16-split, fp32 acc. BM=64, BN=256 (full width -> A read once),
// BK=32, 4 waves (wave = 64-col panel = head for C=64 layers). K-templated
// full unroll; A LDS double-buffered; B register-prefetched 1 step ahead.
template <int NK, bool FUSE>
__global__ __launch_bounds__(256, 1) void gemm_mfma(const _Float16* __restrict__ Ahi,
                                                    const _Float16* __restrict__ Alo,
                                                    const _Float16* __restrict__ Bthi,
                                                    const _Float16* __restrict__ Btlo,
                                                    _Float16* __restrict__ Ch,
                                                    const float* __restrict__ a_src,
                                                    const float* __restrict__ a_dst,
                                                    float* __restrict__ als,
                                                    float* __restrict__ ald,
                                                    int M, int N) {
    constexpr int K = NK * 32;
    __shared__ _Float16 Ah[2][2][64 * 32];
    int t = threadIdx.x;
    int wave = t >> 6, lane = t & 63;
    int row0 = blockIdx.x * 64;

    auto lds_off = [](int m, int g0) -> int {
        int P = m >> 1;
        int gp = ((m & 1) << 2) | g0;
        return P * 64 + ((gp ^ (P & 7)) << 3);
    };

    // staging: one 4-granule slot per thread per plane
    int r0 = t >> 2, g0 = t & 3;
    int off0 = lds_off(r0, g0);
    bool mok = (row0 + r0) < M;
    const _Float16* aph = Ahi + (size_t)(row0 + r0) * K + g0 * 8;
    const _Float16* apl = Alo + (size_t)(row0 + r0) * K + g0 * 8;

    half8 svh, svl;
    auto stage_load = [&](int k0) {
        svh = svl = (half8)(_Float16)0.f;
        if (mok) { svh = *(const half8*)(aph + k0); svl = *(const half8*)(apl + k0); }
    };
    auto stage_write = [&](int buf) {
        *(half8*)(&Ah[buf][0][off0]) = svh;
        *(half8*)(&Ah[buf][1][off0]) = svl;
    };

    const _Float16* bhp[4];
    const _Float16* blp[4];
    #pragma unroll
    for (int nf = 0; nf < 4; nf++) {
        int n = wave * 64 + nf * 16 + (lane & 15);
        bhp[nf] = Bthi + (size_t)n * K + (lane >> 4) * 8;
        blp[nf] = Btlo + (size_t)n * K + (lane >> 4) * 8;
    }

    f32x4 acc[4][4];
    #pragma unroll
    for (int i = 0; i < 4; i++)
        #pragma unroll
        for (int j = 0; j < 4; j++)
            acc[i][j] = (f32x4)0.f;

    stage_load(0);
    stage_write(0);
    half8 bh[4], bl[4];
    #pragma unroll
    for (int nf = 0; nf < 4; nf++) {
        bh[nf] = *(const half8*)(bhp[nf]);
        bl[nf] = *(const half8*)(blp[nf]);
    }
    __syncthreads();

    #pragma unroll
    for (int kt = 0; kt < NK; kt++) {
        int cur = kt & 1;
        half8 bh2[4], bl2[4];
        if (kt + 1 < NK) {
            stage_load((kt + 1) * 32);
            #pragma unroll
            for (int nf = 0; nf < 4; nf++) {
                bh2[nf] = *(const half8*)(bhp[nf] + (kt + 1) * 32);
                bl2[nf] = *(const half8*)(blp[nf] + (kt + 1) * 32);
            }
        }
        half8 ah[4], al[4];
        #pragma unroll
        for (int mf = 0; mf < 4; mf++) {
            int m = mf * 16 + (lane & 15);
            int off = lds_off(m, lane >> 4);
            ah[mf] = *(half8*)(&Ah[cur][0][off]);
            al[mf] = *(half8*)(&Ah[cur][1][off]);
        }
        #pragma unroll
        for (int mf = 0; mf < 4; mf++)
            #pragma unroll
            for (int nf = 0; nf < 4; nf++) {
                acc[mf][nf] = __builtin_amdgcn_mfma_f32_16x16x32_f16(
                    ah[mf], bh[nf], acc[mf][nf], 0, 0, 0);
                acc[mf][nf] = __builtin_amdgcn_mfma_f32_16x16x32_f16(
                    ah[mf], bl[nf], acc[mf][nf], 0, 0, 0);
                acc[mf][nf] = __builtin_amdgcn_mfma_f32_16x16x32_f16(
                    al[mf], bh[nf], acc[mf][nf], 0, 0, 0);
            }
        if (kt + 1 < NK) {
            stage_write(cur ^ 1);
            __syncthreads();
            #pragma unroll
            for (int nf = 0; nf < 4; nf++) { bh[nf] = bh2[nf]; bl[nf] = bl2[nf]; }
        }
    }

    // fp16 store: C/D layout col = lane&15, row = (lane>>4)*4 + q
    #pragma unroll
    for (int mf = 0; mf < 4; mf++)
        #pragma unroll
        for (int nf = 0; nf < 4; nf++) {
            int col = wave * 64 + nf * 16 + (lane & 15);
            if (col >= N) continue;
            #pragma unroll
            for (int q = 0; q < 4; q++) {
                int row = row0 + mf * 16 + (lane >> 4) * 4 + q;
                if (row < M)
                    Ch[(size_t)row * N + col] = (_Float16)acc[mf][nf][q];
            }
        }

    // fused attention coefficients (C=64 layers): head = wave
    if (FUSE) {
        float asv[4], adv[4];
        #pragma unroll
        for (int nf = 0; nf < 4; nf++) {
            int cih = nf * 16 + (lane & 15);
            asv[nf] = a_src[wave * 64 + cih];
            adv[nf] = a_dst[wave * 64 + cih];
        }
        #pragma unroll
        for (int mf = 0; mf < 4; mf++)
            #pragma unroll
            for (int q = 0; q < 4; q++) {
                float ss = 0.f, sd = 0.f;
                #pragma unroll
                for (int nf = 0; nf < 4; nf++) {
                    float v = acc[mf][nf][q];
                    ss = fmaf(v, asv[nf], ss);
                    sd = fmaf(v, adv[nf], sd);
                }
                #pragma unroll
                for (int off = 8; off >= 1; off >>= 1) {
                    ss += __shfl_xor(ss, off, 64);
                    sd += __shfl_xor(sd, off, 64);
                }
                int row = row0 + mf * 16 + (lane >> 4) * 4 + q;
                if ((lane & 15) == 0 && row < M) {
                    als[row * 4 + wave] = ss;
                    ald[row * 4 + wave] = sd;
                }
            }
    }
}

// ---------------------------------------------------------------- attention coefs (layer 3, fp16 h)
template <int C>
__global__ __launch_bounds__(256) void coef_kernel(const _Float16* __restrict__ h,
                                                   const float* __restrict__ a_src,
                                                   const float* __restrict__ a_dst,
                                                   float* __restrict__ als,
                                                   float* __restrict__ ald, int n) {
    int wave = threadIdx.x >> 6;
    int lane = threadIdx.x & 63;
    int node = blockIdx.x * 4 + wave;
    if (node >= n) return;
    const _Float16* hr = h + (size_t)node * (4 * C);
    float ps[4], pd[4];
    #pragma unroll
    for (int hh = 0; hh < 4; hh++) {
        float hv = (lane < C) ? (float)hr[hh * C + lane] : 0.f;
        float as_ = (lane < C) ? a_src[hh * C + lane] : 0.f;
        float ad_ = (lane < C) ? a_dst[hh * C + lane] : 0.f;
        ps[hh] = hv * as_;
        pd[hh] = hv * ad_;
    }
    #pragma unroll
    for (int off = 32; off >= 1; off >>= 1) {
        #pragma unroll
        for (int hh = 0; hh < 4; hh++) {
            ps[hh] += __shfl_xor(ps[hh], off, 64);
            pd[hh] += __shfl_xor(pd[hh], off, 64);
        }
    }
    if (lane == 0) {
        #pragma unroll
        for (int hh = 0; hh < 4; hh++) {
            als[node * 4 + hh] = ps[hh];
            ald[node * 4 + hh] = pd[hh];
        }
    }
}

// ---------------------------------------------------------------- fused softmax + aggregation
// 2 nodes per wave, lane owns 8 channels (16B). No max-subtraction.
// 8-edge batches with csr/als prefetch. (At the random-gather fabric floor.)
template <int C, int MODE>
__global__ __launch_bounds__(256) void agg_kernel(const __half* __restrict__ hhp,
                                                  const float* __restrict__ als,
                                                  const float* __restrict__ ald,
                                                  const int* __restrict__ row_off,
                                                  const int* __restrict__ csr_src,
                                                  const float* __restrict__ bias,
                                                  const _Float16* __restrict__ rh,
                                                  const _Float16* __restrict__ rl,
                                                  float* __restrict__ outf,
                                                  _Float16* __restrict__ oh,
                                                  _Float16* __restrict__ ol, int n) {
    constexpr int HC = 4 * C;          // halves per row (256 or 160)
    constexpr int LPN = HC / 8;        // lanes per node (32 or 20)
    constexpr int LPH = C / 8;         // lanes per head (8 or 5)
    const _Float16* hh = (const _Float16*)hhp;

    int t = threadIdx.x;
    int wave = t >> 6, lane = t & 63;
    int l = lane & 31;
    int node = (blockIdx.x * 4 + wave) * 2 + (lane >> 5);
    bool nact = node < n;
    bool lact = nact && (l < LPN);
    int g = (l < LPN) ? (l / LPH) : 0;

    int rs = 0, cnt = 0;
    if (lact) {
        rs = row_off[node];
        cnt = row_off[node + 1] - rs;
    }
    float aldg = lact ? ald[node * 4 + g] : 0.f;

    float acc[8] = {};
    float den = 0.f;

    if (cnt > 0) {
        int sA[8];
        float avA[8];
        #pragma unroll
        for (int q = 0; q < 8; q++) {
            int idx = q < cnt ? q : cnt - 1;
            sA[q] = csr_src[rs + idx];
        }
        #pragma unroll
        for (int q = 0; q < 8; q++) avA[q] = als[sA[q] * 4 + g];

        for (int base = 0; base < cnt; base += 8) {
            half8 hv[8];
            #pragma unroll
            for (int q = 0; q < 8; q++)
                hv[q] = *(const half8*)(hh + (size_t)sA[q] * HC + l * 8);

            int sB[8];
            float avB[8];
            if (base + 8 < cnt) {
                #pragma unroll
                for (int q = 0; q < 8; q++) {
                    int idx = base + 8 + q; if (idx >= cnt) idx = cnt - 1;
                    sB[q] = csr_src[rs + idx];
                }
                #pragma unroll
                for (int q = 0; q < 8; q++) avB[q] = als[sB[q] * 4 + g];
            }

            float ex[8];
            #pragma unroll
            for (int q = 0; q < 8; q++) {
                float lg = avA[q] + aldg;
                lg = (lg > 0.f) ? lg : NEG_SLOPE * lg;
                float e = __expf(lg);
                ex[q] = (base + q < cnt) ? e : 0.f;
                den += ex[q];
            }
            #pragma unroll
            for (int q = 0; q < 8; q++) {
                #pragma unroll
                for (int k = 0; k < 8; k++)
                    acc[k] = fmaf(ex[q], (float)hv[q][k], acc[k]);
            }
            #pragma unroll
            for (int q = 0; q < 8; q++) { sA[q] = sB[q]; avA[q] = avB[q]; }
        }
    }

    float inv = 1.f / (den + 1e-16f);
    float v[8];
    #pragma unroll
    for (int k = 0; k < 8; k++) v[k] = acc[k] * inv;

    if (MODE == 2) {
        float vs[8];
        #pragma unroll
        for (int k = 0; k < 8; k++) vs[k] = v[k];
        #pragma unroll
        for (int k2 = 1; k2 < 4; k2++) {
            #pragma unroll
            for (int k = 0; k < 8; k++)
                vs[k] += __shfl(v[k], lane + 5 * k2, 64);
        }
        if (nact && l < 5) {
            float b[8];
            *(float4*)&b[0] = *(const float4*)(bias + l * 8);
            *(float4*)&b[4] = *(const float4*)(bias + l * 8 + 4);
            float o[8];
            #pragma unroll
            for (int k = 0; k < 8; k++) o[k] = vs[k] * 0.25f + b[k];
            *(float4*)(outf + (size_t)node * C + l * 8)     = make_float4(o[0], o[1], o[2], o[3]);
            *(float4*)(outf + (size_t)node * C + l * 8 + 4) = make_float4(o[4], o[5], o[6], o[7]);
        }
    } else {
        if (lact) {
            float b[8];
            *(float4*)&b[0] = *(const float4*)(bias + l * 8);
            *(float4*)&b[4] = *(const float4*)(bias + l * 8 + 4);
            float o[8];
            #pragma unroll
            for (int k = 0; k < 8; k++) o[k] = v[k] + b[k];
            if (MODE == 1) {
                size_t ridx = (size_t)node * HC + l * 8;
                half8 r_h = *(const half8*)(rh + ridx);
                half8 r_l = *(const half8*)(rl + ridx);
                #pragma unroll
                for (int k = 0; k < 8; k++) o[k] += (float)r_h[k] + (float)r_l[k];
            }
            #pragma unroll
            for (int k = 0; k < 8; k++) o[k] = (o[k] > 0.f) ? o[k] : expm1f(o[k]);
            half8 hv8, lv8;
            #pragma unroll
            for (int k = 0; k < 8; k++) {
                hv8[k] = (_Float16)o[k];
                lv8[k] = (_Float16)(o[k] - (float)hv8[k]);
            }
            size_t oidx = (size_t)node * HC + l * 8;
            *(half8*)(oh + oidx) = hv8;
            *(half8*)(ol + oidx) = lv8;
        }
    }
}

// ---------------------------------------------------------------- launch
extern "C" void kernel_launch(void* const* d_in, const int* in_sizes, int n_in,
                              void* d_out, int out_size, void* d_ws, size_t ws_size,
                              hipStream_t stream) {
    const float* x   = (const float*)d_in[0];
    const int*   ei  = (const int*)d_in[1];
    const float* W1  = (const float*)d_in[2];
    const float* a1s = (const float*)d_in[3];
    const float* a1d = (const float*)d_in[4];
    const float* b1  = (const float*)d_in[5];
    const float* W2  = (const float*)d_in[6];
    const float* a2s = (const float*)d_in[7];
    const float* a2d = (const float*)d_in[8];
    const float* b2  = (const float*)d_in[9];
    const float* W3  = (const float*)d_in[10];
    const float* a3s = (const float*)d_in[11];
    const float* a3d = (const float*)d_in[12];
    const float* b3  = (const float*)d_in[13];
    float* out = (float*)d_out;

    int N = in_sizes[0] / 128;
    int E = in_sizes[1] / 2;

    char* ws = (char*)d_ws;
    size_t off = 0;
    auto alloc = [&](size_t bytes) -> void* {
        void* p = ws + off;
        off += (bytes + 255) & ~(size_t)255;
        return p;
    };
    _Float16* hhalf = (_Float16*)alloc((size_t)N * 256 * 2);
    _Float16* pA_hi = (_Float16*)alloc((size_t)N * 256 * 2);   // x planes / x2 planes
    _Float16* pA_lo = (_Float16*)alloc((size_t)N * 256 * 2);
    _Float16* pB_hi = (_Float16*)alloc((size_t)N * 256 * 2);   // x1 planes
    _Float16* pB_lo = (_Float16*)alloc((size_t)N * 256 * 2);
    float*    als   = (float*)alloc((size_t)N * 4 * 4);
    float*    ald   = (float*)alloc((size_t)N * 4 * 4);
    _Float16* bt1h  = (_Float16*)alloc(256 * 128 * 2);
    _Float16* bt1l  = (_Float16*)alloc(256 * 128 * 2);
    _Float16* bt2h  = (_Float16*)alloc(256 * 256 * 2);
    _Float16* bt2l  = (_Float16*)alloc(256 * 256 * 2);
    _Float16* bt3h  = (_Float16*)alloc(256 * 256 * 2);
    _Float16* bt3l  = (_Float16*)alloc(256 * 256 * 2);
    int* deg     = (int*)alloc((size_t)N * 4);
    int* row_off = (int*)alloc((size_t)(N + 1) * 4);
    int* cursor  = (int*)alloc((size_t)N * 4);
    int* csr     = (int*)alloc((size_t)(E + N) * 4);
    int* bsums   = (int*)alloc(1024 * 4);

    int tot = E + N;
    int nb = (N + 1023) / 1024;
    hipMemsetAsync(deg, 0, (size_t)N * 4, stream);
    degree_kernel<<<(tot + 255) / 256, 256, 0, stream>>>(ei, E, N, deg);
    scan_block<<<nb, 1024, 0, stream>>>(deg, row_off, bsums, N);
    scan_sums<<<1, 64, 0, stream>>>(bsums, nb, row_off, N);
    scan_add<<<nb, 1024, 0, stream>>>(row_off, bsums, cursor, N);
    scatter_kernel<<<(tot + 255) / 256, 256, 0, stream>>>(ei, E, N, cursor, csr);

    {
        int n4 = N * 128 / 4;
        split_f32x4<<<(n4 + 255) / 256, 256, 0, stream>>>(x, pA_hi, pA_lo, n4);
        int wtot = 256 * 128 + 2 * 256 * 256;
        wt_split_all<<<(wtot + 255) / 256, 256, 0, stream>>>(W1, W2, W3,
            bt1h, bt1l, bt2h, bt2l, bt3h, bt3l);
    }

    int nodeBlocks4 = (N + 3) / 4;   // coef: 4 nodes/block
    int pairs = (N + 1) / 2;
    int aggBlocks = (pairs + 3) / 4; // agg: 4 waves/block, 2 nodes/wave
    dim3 blk(256);
    dim3 ggrid((N + 63) / 64);       // GEMM: BM=64, BN=256 full width

    // layer 1: h = x @ W1 (K=128); coef fused
    gemm_mfma<4, true><<<ggrid, blk, 0, stream>>>(pA_hi, pA_lo, bt1h, bt1l, hhalf,
                                                  a1s, a1d, als, ald, N, 256);
    agg_kernel<64, 0><<<aggBlocks, blk, 0, stream>>>((const __half*)hhalf, als, ald,
        row_off, csr, b1, nullptr, nullptr, nullptr, pB_hi, pB_lo, N);

    // layer 2: h = x1 @ W2 (K=256); coef fused; residual = x1 planes
    gemm_mfma<8, true><<<ggrid, blk, 0, stream>>>(pB_hi, pB_lo, bt2h, bt2l, hhalf,
                                                  a2s, a2d, als, ald, N, 256);
    agg_kernel<64, 1><<<aggBlocks, blk, 0, stream>>>((const __half*)hhalf, als, ald,
        row_off, csr, b2, pB_hi, pB_lo, nullptr, pA_hi, pA_lo, N);

    // layer 3: h = x2 @ W3 (K=256, N=160); coef from fp16 shadow
    gemm_mfma<8, false><<<ggrid, blk, 0, stream>>>(pA_hi, pA_lo, bt3h, bt3l, hhalf,
                                                   nullptr, nullptr, nullptr, nullptr, N, 160);
    coef_kernel<40><<<nodeBlocks4, blk, 0, stream>>>(hhalf, a3s, a3d, als, ald, N);
    agg_kernel<40, 2><<<aggBlocks, blk, 0, stream>>>((const __half*)hhalf, als, ald,
        row_off, csr, b3, nullptr, nullptr, out, nullptr, nullptr, N);
}

// Round 10
// 450.712 us; speedup vs baseline: 1.7939x; 1.0198x over previous
//
#include <hip/hip_runtime.h>
#include <hip/hip_bf16.h>
#include <hip/hip_fp16.h>
#include <math.h>

#define NEG_SLOPE 0.2f

typedef _Float16 half8 __attribute__((ext_vector_type(8)));
typedef _Float16 half4 __attribute__((ext_vector_type(4)));
typedef float f32x4 __attribute__((ext_vector_type(4)));

// ---------------------------------------------------------------- fused prep
// blocks [0, nbSplit)              : x -> hi/lo fp16 planes
// blocks [nbSplit, nbSplit+nbWt)   : W1/W2/W3 -> transposed hi/lo planes
// blocks [nbSplit+nbWt, ...)       : degree histogram (deg pre-zeroed)
__global__ __launch_bounds__(256) void prep_kernel(
        const float* __restrict__ x, _Float16* __restrict__ xhi,
        _Float16* __restrict__ xlo, int n4,
        const float* __restrict__ W1, const float* __restrict__ W2,
        const float* __restrict__ W3,
        _Float16* __restrict__ b1h, _Float16* __restrict__ b1l,
        _Float16* __restrict__ b2h, _Float16* __restrict__ b2l,
        _Float16* __restrict__ b3h, _Float16* __restrict__ b3l,
        const int* __restrict__ ei, int E, int n, int* __restrict__ deg,
        int nbSplit, int nbWt) {
    int b = blockIdx.x;
    if (b < nbSplit) {
        int i = b * 256 + threadIdx.x;
        if (i >= n4) return;
        float4 v = ((const float4*)x)[i];
        half4 h, l;
        h.x = (_Float16)v.x; l.x = (_Float16)(v.x - (float)h.x);
        h.y = (_Float16)v.y; l.y = (_Float16)(v.y - (float)h.y);
        h.z = (_Float16)v.z; l.z = (_Float16)(v.z - (float)h.z);
        h.w = (_Float16)v.w; l.w = (_Float16)(v.w - (float)h.w);
        ((half4*)xhi)[i] = h;
        ((half4*)xlo)[i] = l;
    } else if (b < nbSplit + nbWt) {
        int idx = (b - nbSplit) * 256 + threadIdx.x;
        const float* W; _Float16 *bh, *bl; int K, N, li;
        if (idx < 256 * 128) {
            W = W1; bh = b1h; bl = b1l; K = 128; N = 256; li = idx;
        } else if (idx < 256 * 128 + 256 * 256) {
            W = W2; bh = b2h; bl = b2l; K = 256; N = 256; li = idx - 256 * 128;
        } else if (idx < 256 * 128 + 2 * 256 * 256) {
            W = W3; bh = b3h; bl = b3l; K = 256; N = 160; li = idx - 256 * 128 - 256 * 256;
        } else return;
        int nn = li / K, k = li % K;
        float v = (nn < N) ? W[(size_t)k * N + nn] : 0.f;
        _Float16 h = (_Float16)v;
        bh[li] = h;
        bl[li] = (_Float16)(v - (float)h);
    } else {
        int e = (b - nbSplit - nbWt) * 256 + threadIdx.x;
        int tot = E + n;
        if (e >= tot) return;
        int d = (e < E) ? ei[E + e] : (e - E);
        atomicAdd(&deg[d], 1);
    }
}

// ---------------------------------------------------------------- scan / scatter
__global__ __launch_bounds__(1024) void scan_block(const int* __restrict__ deg,
                                                   int* __restrict__ row_off,
                                                   int* __restrict__ bsums, int n) {
    __shared__ int tmp[1024];
    int t = threadIdx.x;
    int idx = blockIdx.x * 1024 + t;
    int v = (idx < n) ? deg[idx] : 0;
    tmp[t] = v;
    __syncthreads();
    #pragma unroll
    for (int off = 1; off < 1024; off <<= 1) {
        int x = (t >= off) ? tmp[t - off] : 0;
        __syncthreads();
        tmp[t] += x;
        __syncthreads();
    }
    if (idx < n) row_off[idx] = tmp[t] - v;
    if (t == 1023) bsums[blockIdx.x] = tmp[1023];
}

__global__ __launch_bounds__(64) void scan_sums(int* __restrict__ bsums, int nb,
                                                int* __restrict__ row_off, int n) {
    int lane = threadIdx.x;
    int carry = 0;
    for (int base = 0; base < nb; base += 64) {
        int i = base + lane;
        int o = (i < nb) ? bsums[i] : 0;
        int v = o;
        #pragma unroll
        for (int off = 1; off < 64; off <<= 1) {
            int x = __shfl_up(v, off, 64);
            if (lane >= off) v += x;
        }
        if (i < nb) bsums[i] = carry + v - o;
        int tot = __shfl(v, 63, 64);
        carry += tot;
    }
    if (lane == 0) row_off[n] = carry;
}

__global__ __launch_bounds__(1024) void scan_add(int* __restrict__ row_off,
                                                 const int* __restrict__ bsums,
                                                 int* __restrict__ cursor, int n) {
    int idx = blockIdx.x * 1024 + threadIdx.x;
    if (idx < n) {
        int v = row_off[idx] + bsums[blockIdx.x];
        row_off[idx] = v;
        cursor[idx] = v;
    }
}

__global__ void scatter_kernel(const int* __restrict__ ei, int E, int n,
                               int* __restrict__ cursor, int* __restrict__ csr_src) {
    int e = blockIdx.x * 256 + threadIdx.x;
    int tot = E + n;
    if (e >= tot) return;
    int s, d;
    if (e < E) { s = ei[e]; d = ei[E + e]; } else { s = d = e - E; }
    int pos = atomicAdd(&cursor[d], 1);
    csr_src[pos] = s;
}

// ---------------------------------------------------------------- MFMA GEMM
// 3-term fp16-split, fp32 acc. BM=64, BN=256 (A read once), BK=32, 4 waves
// (wave = 64-col panel = head for C=64). K-templated full unroll; A LDS
// double-buffered via reg staging; B loaded JIT per K-step (no reg prefetch
// -> ~190 VGPR -> 2-3 waves/SIMD latency hiding).
template <int NK, bool FUSE>
__global__ __launch_bounds__(256) void gemm_mfma(const _Float16* __restrict__ Ahi,
                                                 const _Float16* __restrict__ Alo,
                                                 const _Float16* __restrict__ Bthi,
                                                 const _Float16* __restrict__ Btlo,
                                                 _Float16* __restrict__ Ch,
                                                 const float* __restrict__ a_src,
                                                 const float* __restrict__ a_dst,
                                                 float* __restrict__ als,
                                                 float* __restrict__ ald,
                                                 int M, int N) {
    constexpr int K = NK * 32;
    __shared__ _Float16 Ah[2][2][64 * 32];
    int t = threadIdx.x;
    int wave = t >> 6, lane = t & 63;
    int row0 = blockIdx.x * 64;

    auto lds_off = [](int m, int g0) -> int {
        int P = m >> 1;
        int gp = ((m & 1) << 2) | g0;
        return P * 64 + ((gp ^ (P & 7)) << 3);
    };

    int r0 = t >> 2, g0 = t & 3;
    int off0 = lds_off(r0, g0);
    bool mok = (row0 + r0) < M;
    const _Float16* aph = Ahi + (size_t)(row0 + r0) * K + g0 * 8;
    const _Float16* apl = Alo + (size_t)(row0 + r0) * K + g0 * 8;

    half8 svh, svl;
    auto stage_load = [&](int k0) {
        svh = svl = (half8)(_Float16)0.f;
        if (mok) { svh = *(const half8*)(aph + k0); svl = *(const half8*)(apl + k0); }
    };
    auto stage_write = [&](int buf) {
        *(half8*)(&Ah[buf][0][off0]) = svh;
        *(half8*)(&Ah[buf][1][off0]) = svl;
    };

    const _Float16* bhp[4];
    const _Float16* blp[4];
    #pragma unroll
    for (int nf = 0; nf < 4; nf++) {
        int n = wave * 64 + nf * 16 + (lane & 15);
        bhp[nf] = Bthi + (size_t)n * K + (lane >> 4) * 8;
        blp[nf] = Btlo + (size_t)n * K + (lane >> 4) * 8;
    }

    f32x4 acc[4][4];
    #pragma unroll
    for (int i = 0; i < 4; i++)
        #pragma unroll
        for (int j = 0; j < 4; j++)
            acc[i][j] = (f32x4)0.f;

    stage_load(0);
    stage_write(0);
    __syncthreads();

    #pragma unroll
    for (int kt = 0; kt < NK; kt++) {
        int cur = kt & 1;
        int k0 = kt * 32;
        // B for current step first (so MFMA's vmcnt wait doesn't drain A stage)
        half8 bh[4], bl[4];
        #pragma unroll
        for (int nf = 0; nf < 4; nf++) {
            bh[nf] = *(const half8*)(bhp[nf] + k0);
            bl[nf] = *(const half8*)(blp[nf] + k0);
        }
        // next A tile staging loads overlap the MFMA below
        if (kt + 1 < NK) stage_load((kt + 1) * 32);

        half8 ah[4], al[4];
        #pragma unroll
        for (int mf = 0; mf < 4; mf++) {
            int m = mf * 16 + (lane & 15);
            int off = lds_off(m, lane >> 4);
            ah[mf] = *(half8*)(&Ah[cur][0][off]);
            al[mf] = *(half8*)(&Ah[cur][1][off]);
        }
        #pragma unroll
        for (int mf = 0; mf < 4; mf++)
            #pragma unroll
            for (int nf = 0; nf < 4; nf++) {
                acc[mf][nf] = __builtin_amdgcn_mfma_f32_16x16x32_f16(
                    ah[mf], bh[nf], acc[mf][nf], 0, 0, 0);
                acc[mf][nf] = __builtin_amdgcn_mfma_f32_16x16x32_f16(
                    ah[mf], bl[nf], acc[mf][nf], 0, 0, 0);
                acc[mf][nf] = __builtin_amdgcn_mfma_f32_16x16x32_f16(
                    al[mf], bh[nf], acc[mf][nf], 0, 0, 0);
            }
        if (kt + 1 < NK) {
            stage_write(cur ^ 1);
            __syncthreads();
        }
    }

    // fp16 store: C/D layout col = lane&15, row = (lane>>4)*4 + q
    #pragma unroll
    for (int mf = 0; mf < 4; mf++)
        #pragma unroll
        for (int nf = 0; nf < 4; nf++) {
            int col = wave * 64 + nf * 16 + (lane & 15);
            if (col >= N) continue;
            #pragma unroll
            for (int q = 0; q < 4; q++) {
                int row = row0 + mf * 16 + (lane >> 4) * 4 + q;
                if (row < M)
                    Ch[(size_t)row * N + col] = (_Float16)acc[mf][nf][q];
            }
        }

    // fused attention coefficients (C=64 layers): head = wave
    if (FUSE) {
        float asv[4], adv[4];
        #pragma unroll
        for (int nf = 0; nf < 4; nf++) {
            int cih = nf * 16 + (lane & 15);
            asv[nf] = a_src[wave * 64 + cih];
            adv[nf] = a_dst[wave * 64 + cih];
        }
        #pragma unroll
        for (int mf = 0; mf < 4; mf++)
            #pragma unroll
            for (int q = 0; q < 4; q++) {
                float ss = 0.f, sd = 0.f;
                #pragma unroll
                for (int nf = 0; nf < 4; nf++) {
                    float v = acc[mf][nf][q];
                    ss = fmaf(v, asv[nf], ss);
                    sd = fmaf(v, adv[nf], sd);
                }
                #pragma unroll
                for (int off = 8; off >= 1; off >>= 1) {
                    ss += __shfl_xor(ss, off, 64);
                    sd += __shfl_xor(sd, off, 64);
                }
                int row = row0 + mf * 16 + (lane >> 4) * 4 + q;
                if ((lane & 15) == 0 && row < M) {
                    als[row * 4 + wave] = ss;
                    ald[row * 4 + wave] = sd;
                }
            }
    }
}

// ---------------------------------------------------------------- attention coefs (layer 3, fp16 h)
template <int C>
__global__ __launch_bounds__(256) void coef_kernel(const _Float16* __restrict__ h,
                                                   const float* __restrict__ a_src,
                                                   const float* __restrict__ a_dst,
                                                   float* __restrict__ als,
                                                   float* __restrict__ ald, int n) {
    int wave = threadIdx.x >> 6;
    int lane = threadIdx.x & 63;
    int node = blockIdx.x * 4 + wave;
    if (node >= n) return;
    const _Float16* hr = h + (size_t)node * (4 * C);
    float ps[4], pd[4];
    #pragma unroll
    for (int hh = 0; hh < 4; hh++) {
        float hv = (lane < C) ? (float)hr[hh * C + lane] : 0.f;
        float as_ = (lane < C) ? a_src[hh * C + lane] : 0.f;
        float ad_ = (lane < C) ? a_dst[hh * C + lane] : 0.f;
        ps[hh] = hv * as_;
        pd[hh] = hv * ad_;
    }
    #pragma unroll
    for (int off = 32; off >= 1; off >>= 1) {
        #pragma unroll
        for (int hh = 0; hh < 4; hh++) {
            ps[hh] += __shfl_xor(ps[hh], off, 64);
            pd[hh] += __shfl_xor(pd[hh], off, 64);
        }
    }
    if (lane == 0) {
        #pragma unroll
        for (int hh = 0; hh < 4; hh++) {
            als[node * 4 + hh] = ps[hh];
            ald[node * 4 + hh] = pd[hh];
        }
    }
}

// ---------------------------------------------------------------- fused softmax + aggregation
// 2 nodes per wave, lane owns 8 channels (16B). No max-subtraction.
// 8-edge batches with csr/als prefetch. (At the random-gather fabric floor.)
template <int C, int MODE>
__global__ __launch_bounds__(256) void agg_kernel(const __half* __restrict__ hhp,
                                                  const float* __restrict__ als,
                                                  const float* __restrict__ ald,
                                                  const int* __restrict__ row_off,
                                                  const int* __restrict__ csr_src,
                                                  const float* __restrict__ bias,
                                                  const _Float16* __restrict__ rh,
                                                  const _Float16* __restrict__ rl,
                                                  float* __restrict__ outf,
                                                  _Float16* __restrict__ oh,
                                                  _Float16* __restrict__ ol, int n) {
    constexpr int HC = 4 * C;          // halves per row (256 or 160)
    constexpr int LPN = HC / 8;        // lanes per node (32 or 20)
    constexpr int LPH = C / 8;         // lanes per head (8 or 5)
    const _Float16* hh = (const _Float16*)hhp;

    int t = threadIdx.x;
    int wave = t >> 6, lane = t & 63;
    int l = lane & 31;
    int node = (blockIdx.x * 4 + wave) * 2 + (lane >> 5);
    bool nact = node < n;
    bool lact = nact && (l < LPN);
    int g = (l < LPN) ? (l / LPH) : 0;

    int rs = 0, cnt = 0;
    if (lact) {
        rs = row_off[node];
        cnt = row_off[node + 1] - rs;
    }
    float aldg = lact ? ald[node * 4 + g] : 0.f;

    float acc[8] = {};
    float den = 0.f;

    if (cnt > 0) {
        int sA[8];
        float avA[8];
        #pragma unroll
        for (int q = 0; q < 8; q++) {
            int idx = q < cnt ? q : cnt - 1;
            sA[q] = csr_src[rs + idx];
        }
        #pragma unroll
        for (int q = 0; q < 8; q++) avA[q] = als[sA[q] * 4 + g];

        for (int base = 0; base < cnt; base += 8) {
            half8 hv[8];
            #pragma unroll
            for (int q = 0; q < 8; q++)
                hv[q] = *(const half8*)(hh + (size_t)sA[q] * HC + l * 8);

            int sB[8];
            float avB[8];
            if (base + 8 < cnt) {
                #pragma unroll
                for (int q = 0; q < 8; q++) {
                    int idx = base + 8 + q; if (idx >= cnt) idx = cnt - 1;
                    sB[q] = csr_src[rs + idx];
                }
                #pragma unroll
                for (int q = 0; q < 8; q++) avB[q] = als[sB[q] * 4 + g];
            }

            float ex[8];
            #pragma unroll
            for (int q = 0; q < 8; q++) {
                float lg = avA[q] + aldg;
                lg = (lg > 0.f) ? lg : NEG_SLOPE * lg;
                float e = __expf(lg);
                ex[q] = (base + q < cnt) ? e : 0.f;
                den += ex[q];
            }
            #pragma unroll
            for (int q = 0; q < 8; q++) {
                #pragma unroll
                for (int k = 0; k < 8; k++)
                    acc[k] = fmaf(ex[q], (float)hv[q][k], acc[k]);
            }
            #pragma unroll
            for (int q = 0; q < 8; q++) { sA[q] = sB[q]; avA[q] = avB[q]; }
        }
    }

    float inv = 1.f / (den + 1e-16f);
    float v[8];
    #pragma unroll
    for (int k = 0; k < 8; k++) v[k] = acc[k] * inv;

    if (MODE == 2) {
        float vs[8];
        #pragma unroll
        for (int k = 0; k < 8; k++) vs[k] = v[k];
        #pragma unroll
        for (int k2 = 1; k2 < 4; k2++) {
            #pragma unroll
            for (int k = 0; k < 8; k++)
                vs[k] += __shfl(v[k], lane + 5 * k2, 64);
        }
        if (nact && l < 5) {
            float b[8];
            *(float4*)&b[0] = *(const float4*)(bias + l * 8);
            *(float4*)&b[4] = *(const float4*)(bias + l * 8 + 4);
            float o[8];
            #pragma unroll
            for (int k = 0; k < 8; k++) o[k] = vs[k] * 0.25f + b[k];
            *(float4*)(outf + (size_t)node * C + l * 8)     = make_float4(o[0], o[1], o[2], o[3]);
            *(float4*)(outf + (size_t)node * C + l * 8 + 4) = make_float4(o[4], o[5], o[6], o[7]);
        }
    } else {
        if (lact) {
            float b[8];
            *(float4*)&b[0] = *(const float4*)(bias + l * 8);
            *(float4*)&b[4] = *(const float4*)(bias + l * 8 + 4);
            float o[8];
            #pragma unroll
            for (int k = 0; k < 8; k++) o[k] = v[k] + b[k];
            if (MODE == 1) {
                size_t ridx = (size_t)node * HC + l * 8;
                half8 r_h = *(const half8*)(rh + ridx);
                half8 r_l = *(const half8*)(rl + ridx);
                #pragma unroll
                for (int k = 0; k < 8; k++) o[k] += (float)r_h[k] + (float)r_l[k];
            }
            #pragma unroll
            for (int k = 0; k < 8; k++) o[k] = (o[k] > 0.f) ? o[k] : expm1f(o[k]);
            half8 hv8, lv8;
            #pragma unroll
            for (int k = 0; k < 8; k++) {
                hv8[k] = (_Float16)o[k];
                lv8[k] = (_Float16)(o[k] - (float)hv8[k]);
            }
            size_t oidx = (size_t)node * HC + l * 8;
            *(half8*)(oh + oidx) = hv8;
            *(half8*)(ol + oidx) = lv8;
        }
    }
}

// ---------------------------------------------------------------- launch
extern "C" void kernel_launch(void* const* d_in, const int* in_sizes, int n_in,
                              void* d_out, int out_size, void* d_ws, size_t ws_size,
                              hipStream_t stream) {
    const float* x   = (const float*)d_in[0];
    const int*   ei  = (const int*)d_in[1];
    const float* W1  = (const float*)d_in[2];
    const float* a1s = (const float*)d_in[3];
    const float* a1d = (const float*)d_in[4];
    const float* b1  = (const float*)d_in[5];
    const float* W2  = (const float*)d_in[6];
    const float* a2s = (const float*)d_in[7];
    const float* a2d = (const float*)d_in[8];
    const float* b2  = (const float*)d_in[9];
    const float* W3  = (const float*)d_in[10];
    const float* a3s = (const float*)d_in[11];
    const float* a3d = (const float*)d_in[12];
    const float* b3  = (const float*)d_in[13];
    float* out = (float*)d_out;

    int N = in_sizes[0] / 128;
    int E = in_sizes[1] / 2;

    char* ws = (char*)d_ws;
    size_t off = 0;
    auto alloc = [&](size_t bytes) -> void* {
        void* p = ws + off;
        off += (bytes + 255) & ~(size_t)255;
        return p;
    };
    _Float16* hhalf = (_Float16*)alloc((size_t)N * 256 * 2);
    _Float16* pA_hi = (_Float16*)alloc((size_t)N * 256 * 2);   // x planes / x2 planes
    _Float16* pA_lo = (_Float16*)alloc((size_t)N * 256 * 2);
    _Float16* pB_hi = (_Float16*)alloc((size_t)N * 256 * 2);   // x1 planes
    _Float16* pB_lo = (_Float16*)alloc((size_t)N * 256 * 2);
    float*    als   = (float*)alloc((size_t)N * 4 * 4);
    float*    ald   = (float*)alloc((size_t)N * 4 * 4);
    _Float16* bt1h  = (_Float16*)alloc(256 * 128 * 2);
    _Float16* bt1l  = (_Float16*)alloc(256 * 128 * 2);
    _Float16* bt2h  = (_Float16*)alloc(256 * 256 * 2);
    _Float16* bt2l  = (_Float16*)alloc(256 * 256 * 2);
    _Float16* bt3h  = (_Float16*)alloc(256 * 256 * 2);
    _Float16* bt3l  = (_Float16*)alloc(256 * 256 * 2);
    int* deg     = (int*)alloc((size_t)N * 4);
    int* row_off = (int*)alloc((size_t)(N + 1) * 4);
    int* cursor  = (int*)alloc((size_t)N * 4);
    int* csr     = (int*)alloc((size_t)(E + N) * 4);
    int* bsums   = (int*)alloc(1024 * 4);

    int tot = E + N;
    int nb = (N + 1023) / 1024;
    int n4 = N * 128 / 4;
    int nbSplit = (n4 + 255) / 256;
    int wtot = 256 * 128 + 2 * 256 * 256;
    int nbWt = (wtot + 255) / 256;
    int nbDeg = (tot + 255) / 256;

    hipMemsetAsync(deg, 0, (size_t)N * 4, stream);
    prep_kernel<<<nbSplit + nbWt + nbDeg, 256, 0, stream>>>(
        x, pA_hi, pA_lo, n4, W1, W2, W3,
        bt1h, bt1l, bt2h, bt2l, bt3h, bt3l,
        ei, E, N, deg, nbSplit, nbWt);
    scan_block<<<nb, 1024, 0, stream>>>(deg, row_off, bsums, N);
    scan_sums<<<1, 64, 0, stream>>>(bsums, nb, row_off, N);
    scan_add<<<nb, 1024, 0, stream>>>(row_off, bsums, cursor, N);
    scatter_kernel<<<(tot + 255) / 256, 256, 0, stream>>>(ei, E, N, cursor, csr);

    int nodeBlocks4 = (N + 3) / 4;   // coef: 4 nodes/block
    int pairs = (N + 1) / 2;
    int aggBlocks = (pairs + 3) / 4; // agg: 4 waves/block, 2 nodes/wave
    dim3 blk(256);
    dim3 ggrid((N + 63) / 64);       // GEMM: BM=64, BN=256 full width

    // layer 1: h = x @ W1 (K=128); coef fused
    gemm_mfma<4, true><<<ggrid, blk, 0, stream>>>(pA_hi, pA_lo, bt1h, bt1l, hhalf,
                                                  a1s, a1d, als, ald, N, 256);
    agg_kernel<64, 0><<<aggBlocks, blk, 0, stream>>>((const __half*)hhalf, als, ald,
        row_off, csr, b1, nullptr, nullptr, nullptr, pB_hi, pB_lo, N);

    // layer 2: h = x1 @ W2 (K=256); coef fused; residual = x1 planes
    gemm_mfma<8, true><<<ggrid, blk, 0, stream>>>(pB_hi, pB_lo, bt2h, bt2l, hhalf,
                                                  a2s, a2d, als, ald, N, 256);
    agg_kernel<64, 1><<<aggBlocks, blk, 0, stream>>>((const __half*)hhalf, als, ald,
        row_off, csr, b2, pB_hi, pB_lo, nullptr, pA_hi, pA_lo, N);

    // layer 3: h = x2 @ W3 (K=256, N=160); coef from fp16 shadow
    gemm_mfma<8, false><<<ggrid, blk, 0, stream>>>(pA_hi, pA_lo, bt3h, bt3l, hhalf,
                                                   nullptr, nullptr, nullptr, nullptr, N, 160);
    coef_kernel<40><<<nodeBlocks4, blk, 0, stream>>>(hhalf, a3s, a3d, als, ald, N);
    agg_kernel<40, 2><<<aggBlocks, blk, 0, stream>>>((const __half*)hhalf, als, ald,
        row_off, csr, b3, nullptr, nullptr, out, nullptr, nullptr, N);
}

// Round 11
// 434.306 us; speedup vs baseline: 1.8617x; 1.0378x over previous
//
#include <hip/hip_runtime.h>
#include <hip/hip_bf16.h>
#include <hip/hip_fp16.h>
#include <math.h>

#define NEG_SLOPE 0.2f

typedef _Float16 half8 __attribute__((ext_vector_type(8)));
typedef _Float16 half4 __attribute__((ext_vector_type(4)));
typedef float f32x4 __attribute__((ext_vector_type(4)));

// ---------------------------------------------------------------- fused prep
// blocks [0, nbSplit)              : x -> fp16 (single plane)
// blocks [nbSplit, nbSplit+nbWt)   : W1/W2/W3 -> transposed hi/lo planes
// blocks [nbSplit+nbWt, ...)       : degree histogram (deg pre-zeroed)
__global__ __launch_bounds__(256) void prep_kernel(
        const float* __restrict__ x, _Float16* __restrict__ xh, int n4,
        const float* __restrict__ W1, const float* __restrict__ W2,
        const float* __restrict__ W3,
        _Float16* __restrict__ b1h, _Float16* __restrict__ b1l,
        _Float16* __restrict__ b2h, _Float16* __restrict__ b2l,
        _Float16* __restrict__ b3h, _Float16* __restrict__ b3l,
        const int* __restrict__ ei, int E, int n, int* __restrict__ deg,
        int nbSplit, int nbWt) {
    int b = blockIdx.x;
    if (b < nbSplit) {
        int i = b * 256 + threadIdx.x;
        if (i >= n4) return;
        float4 v = ((const float4*)x)[i];
        half4 h;
        h.x = (_Float16)v.x; h.y = (_Float16)v.y;
        h.z = (_Float16)v.z; h.w = (_Float16)v.w;
        ((half4*)xh)[i] = h;
    } else if (b < nbSplit + nbWt) {
        int idx = (b - nbSplit) * 256 + threadIdx.x;
        const float* W; _Float16 *bh, *bl; int K, N, li;
        if (idx < 256 * 128) {
            W = W1; bh = b1h; bl = b1l; K = 128; N = 256; li = idx;
        } else if (idx < 256 * 128 + 256 * 256) {
            W = W2; bh = b2h; bl = b2l; K = 256; N = 256; li = idx - 256 * 128;
        } else if (idx < 256 * 128 + 2 * 256 * 256) {
            W = W3; bh = b3h; bl = b3l; K = 256; N = 160; li = idx - 256 * 128 - 256 * 256;
        } else return;
        int nn = li / K, k = li % K;
        float v = (nn < N) ? W[(size_t)k * N + nn] : 0.f;
        _Float16 h = (_Float16)v;
        bh[li] = h;
        bl[li] = (_Float16)(v - (float)h);
    } else {
        int e = (b - nbSplit - nbWt) * 256 + threadIdx.x;
        int tot = E + n;
        if (e >= tot) return;
        int d = (e < E) ? ei[E + e] : (e - E);
        atomicAdd(&deg[d], 1);
    }
}

// ---------------------------------------------------------------- scan / scatter
__global__ __launch_bounds__(1024) void scan_block(const int* __restrict__ deg,
                                                   int* __restrict__ row_off,
                                                   int* __restrict__ bsums, int n) {
    __shared__ int tmp[1024];
    int t = threadIdx.x;
    int idx = blockIdx.x * 1024 + t;
    int v = (idx < n) ? deg[idx] : 0;
    tmp[t] = v;
    __syncthreads();
    #pragma unroll
    for (int off = 1; off < 1024; off <<= 1) {
        int x = (t >= off) ? tmp[t - off] : 0;
        __syncthreads();
        tmp[t] += x;
        __syncthreads();
    }
    if (idx < n) row_off[idx] = tmp[t] - v;
    if (t == 1023) bsums[blockIdx.x] = tmp[1023];
}

__global__ __launch_bounds__(64) void scan_sums(int* __restrict__ bsums, int nb,
                                                int* __restrict__ row_off, int n) {
    int lane = threadIdx.x;
    int carry = 0;
    for (int base = 0; base < nb; base += 64) {
        int i = base + lane;
        int o = (i < nb) ? bsums[i] : 0;
        int v = o;
        #pragma unroll
        for (int off = 1; off < 64; off <<= 1) {
            int x = __shfl_up(v, off, 64);
            if (lane >= off) v += x;
        }
        if (i < nb) bsums[i] = carry + v - o;
        int tot = __shfl(v, 63, 64);
        carry += tot;
    }
    if (lane == 0) row_off[n] = carry;
}

__global__ __launch_bounds__(1024) void scan_add(int* __restrict__ row_off,
                                                 const int* __restrict__ bsums,
                                                 int* __restrict__ cursor, int n) {
    int idx = blockIdx.x * 1024 + threadIdx.x;
    if (idx < n) {
        int v = row_off[idx] + bsums[blockIdx.x];
        row_off[idx] = v;
        cursor[idx] = v;
    }
}

__global__ void scatter_kernel(const int* __restrict__ ei, int E, int n,
                               int* __restrict__ cursor, int* __restrict__ csr_src) {
    int e = blockIdx.x * 256 + threadIdx.x;
    int tot = E + n;
    if (e >= tot) return;
    int s, d;
    if (e < E) { s = ei[e]; d = ei[E + e]; } else { s = d = e - E; }
    int pos = atomicAdd(&cursor[d], 1);
    csr_src[pos] = s;
}

// ---------------------------------------------------------------- MFMA GEMM
// A fp16 single-plane; B split hi/lo -> 2-term MFMA (weight error 2^-22,
// input rounding 2^-11 spent from the error budget). BM=64, BN=256 (A read
// once), BK=32, 4 waves (wave = 64-col panel = head for C=64). K-templated
// full unroll; A LDS double-buffered via reg staging; B loaded JIT per step.
template <int NK, bool FUSE>
__global__ __launch_bounds__(256) void gemm_mfma(const _Float16* __restrict__ A16,
                                                 const _Float16* __restrict__ Bthi,
                                                 const _Float16* __restrict__ Btlo,
                                                 _Float16* __restrict__ Ch,
                                                 const float* __restrict__ a_src,
                                                 const float* __restrict__ a_dst,
                                                 float* __restrict__ als,
                                                 float* __restrict__ ald,
                                                 int M, int N) {
    constexpr int K = NK * 32;
    __shared__ _Float16 Ah[2][64 * 32];
    int t = threadIdx.x;
    int wave = t >> 6, lane = t & 63;
    int row0 = blockIdx.x * 64;

    auto lds_off = [](int m, int g0) -> int {
        int P = m >> 1;
        int gp = ((m & 1) << 2) | g0;
        return P * 64 + ((gp ^ (P & 7)) << 3);
    };

    int r0 = t >> 2, g0 = t & 3;
    int off0 = lds_off(r0, g0);
    bool mok = (row0 + r0) < M;
    const _Float16* aph = A16 + (size_t)(row0 + r0) * K + g0 * 8;

    half8 svh;
    auto stage_load = [&](int k0) {
        svh = (half8)(_Float16)0.f;
        if (mok) svh = *(const half8*)(aph + k0);
    };
    auto stage_write = [&](int buf) {
        *(half8*)(&Ah[buf][off0]) = svh;
    };

    const _Float16* bhp[4];
    const _Float16* blp[4];
    #pragma unroll
    for (int nf = 0; nf < 4; nf++) {
        int n = wave * 64 + nf * 16 + (lane & 15);
        bhp[nf] = Bthi + (size_t)n * K + (lane >> 4) * 8;
        blp[nf] = Btlo + (size_t)n * K + (lane >> 4) * 8;
    }

    f32x4 acc[4][4];
    #pragma unroll
    for (int i = 0; i < 4; i++)
        #pragma unroll
        for (int j = 0; j < 4; j++)
            acc[i][j] = (f32x4)0.f;

    stage_load(0);
    stage_write(0);
    __syncthreads();

    #pragma unroll
    for (int kt = 0; kt < NK; kt++) {
        int cur = kt & 1;
        int k0 = kt * 32;
        // B for current step first (so MFMA's vmcnt wait doesn't drain A stage)
        half8 bh[4], bl[4];
        #pragma unroll
        for (int nf = 0; nf < 4; nf++) {
            bh[nf] = *(const half8*)(bhp[nf] + k0);
            bl[nf] = *(const half8*)(blp[nf] + k0);
        }
        if (kt + 1 < NK) stage_load((kt + 1) * 32);

        half8 ah[4];
        #pragma unroll
        for (int mf = 0; mf < 4; mf++) {
            int m = mf * 16 + (lane & 15);
            int off = lds_off(m, lane >> 4);
            ah[mf] = *(half8*)(&Ah[cur][off]);
        }
        #pragma unroll
        for (int mf = 0; mf < 4; mf++)
            #pragma unroll
            for (int nf = 0; nf < 4; nf++) {
                acc[mf][nf] = __builtin_amdgcn_mfma_f32_16x16x32_f16(
                    ah[mf], bh[nf], acc[mf][nf], 0, 0, 0);
                acc[mf][nf] = __builtin_amdgcn_mfma_f32_16x16x32_f16(
                    ah[mf], bl[nf], acc[mf][nf], 0, 0, 0);
            }
        if (kt + 1 < NK) {
            stage_write(cur ^ 1);
            __syncthreads();
        }
    }

    // fp16 store: C/D layout col = lane&15, row = (lane>>4)*4 + q
    #pragma unroll
    for (int mf = 0; mf < 4; mf++)
        #pragma unroll
        for (int nf = 0; nf < 4; nf++) {
            int col = wave * 64 + nf * 16 + (lane & 15);
            if (col >= N) continue;
            #pragma unroll
            for (int q = 0; q < 4; q++) {
                int row = row0 + mf * 16 + (lane >> 4) * 4 + q;
                if (row < M)
                    Ch[(size_t)row * N + col] = (_Float16)acc[mf][nf][q];
            }
        }

    // fused attention coefficients (C=64 layers): head = wave
    if (FUSE) {
        float asv[4], adv[4];
        #pragma unroll
        for (int nf = 0; nf < 4; nf++) {
            int cih = nf * 16 + (lane & 15);
            asv[nf] = a_src[wave * 64 + cih];
            adv[nf] = a_dst[wave * 64 + cih];
        }
        #pragma unroll
        for (int mf = 0; mf < 4; mf++)
            #pragma unroll
            for (int q = 0; q < 4; q++) {
                float ss = 0.f, sd = 0.f;
                #pragma unroll
                for (int nf = 0; nf < 4; nf++) {
                    float v = acc[mf][nf][q];
                    ss = fmaf(v, asv[nf], ss);
                    sd = fmaf(v, adv[nf], sd);
                }
                #pragma unroll
                for (int off = 8; off >= 1; off >>= 1) {
                    ss += __shfl_xor(ss, off, 64);
                    sd += __shfl_xor(sd, off, 64);
                }
                int row = row0 + mf * 16 + (lane >> 4) * 4 + q;
                if ((lane & 15) == 0 && row < M) {
                    als[row * 4 + wave] = ss;
                    ald[row * 4 + wave] = sd;
                }
            }
    }
}

// ---------------------------------------------------------------- attention coefs (layer 3, fp16 h)
template <int C>
__global__ __launch_bounds__(256) void coef_kernel(const _Float16* __restrict__ h,
                                                   const float* __restrict__ a_src,
                                                   const float* __restrict__ a_dst,
                                                   float* __restrict__ als,
                                                   float* __restrict__ ald, int n) {
    int wave = threadIdx.x >> 6;
    int lane = threadIdx.x & 63;
    int node = blockIdx.x * 4 + wave;
    if (node >= n) return;
    const _Float16* hr = h + (size_t)node * (4 * C);
    float ps[4], pd[4];
    #pragma unroll
    for (int hh = 0; hh < 4; hh++) {
        float hv = (lane < C) ? (float)hr[hh * C + lane] : 0.f;
        float as_ = (lane < C) ? a_src[hh * C + lane] : 0.f;
        float ad_ = (lane < C) ? a_dst[hh * C + lane] : 0.f;
        ps[hh] = hv * as_;
        pd[hh] = hv * ad_;
    }
    #pragma unroll
    for (int off = 32; off >= 1; off >>= 1) {
        #pragma unroll
        for (int hh = 0; hh < 4; hh++) {
            ps[hh] += __shfl_xor(ps[hh], off, 64);
            pd[hh] += __shfl_xor(pd[hh], off, 64);
        }
    }
    if (lane == 0) {
        #pragma unroll
        for (int hh = 0; hh < 4; hh++) {
            als[node * 4 + hh] = ps[hh];
            ald[node * 4 + hh] = pd[hh];
        }
    }
}

// ---------------------------------------------------------------- fused softmax + aggregation
// 2 nodes per wave, lane owns 8 channels (16B). No max-subtraction.
// 8-edge batches with csr/als prefetch. Outputs a single fp16 plane.
template <int C, int MODE>
__global__ __launch_bounds__(256) void agg_kernel(const __half* __restrict__ hhp,
                                                  const float* __restrict__ als,
                                                  const float* __restrict__ ald,
                                                  const int* __restrict__ row_off,
                                                  const int* __restrict__ csr_src,
                                                  const float* __restrict__ bias,
                                                  const _Float16* __restrict__ rh,
                                                  float* __restrict__ outf,
                                                  _Float16* __restrict__ oh, int n) {
    constexpr int HC = 4 * C;          // halves per row (256 or 160)
    constexpr int LPN = HC / 8;        // lanes per node (32 or 20)
    constexpr int LPH = C / 8;         // lanes per head (8 or 5)
    const _Float16* hh = (const _Float16*)hhp;

    int t = threadIdx.x;
    int wave = t >> 6, lane = t & 63;
    int l = lane & 31;
    int node = (blockIdx.x * 4 + wave) * 2 + (lane >> 5);
    bool nact = node < n;
    bool lact = nact && (l < LPN);
    int g = (l < LPN) ? (l / LPH) : 0;

    int rs = 0, cnt = 0;
    if (lact) {
        rs = row_off[node];
        cnt = row_off[node + 1] - rs;
    }
    float aldg = lact ? ald[node * 4 + g] : 0.f;

    float acc[8] = {};
    float den = 0.f;

    if (cnt > 0) {
        int sA[8];
        float avA[8];
        #pragma unroll
        for (int q = 0; q < 8; q++) {
            int idx = q < cnt ? q : cnt - 1;
            sA[q] = csr_src[rs + idx];
        }
        #pragma unroll
        for (int q = 0; q < 8; q++) avA[q] = als[sA[q] * 4 + g];

        for (int base = 0; base < cnt; base += 8) {
            half8 hv[8];
            #pragma unroll
            for (int q = 0; q < 8; q++)
                hv[q] = *(const half8*)(hh + (size_t)sA[q] * HC + l * 8);

            int sB[8];
            float avB[8];
            if (base + 8 < cnt) {
                #pragma unroll
                for (int q = 0; q < 8; q++) {
                    int idx = base + 8 + q; if (idx >= cnt) idx = cnt - 1;
                    sB[q] = csr_src[rs + idx];
                }
                #pragma unroll
                for (int q = 0; q < 8; q++) avB[q] = als[sB[q] * 4 + g];
            }

            float ex[8];
            #pragma unroll
            for (int q = 0; q < 8; q++) {
                float lg = avA[q] + aldg;
                lg = (lg > 0.f) ? lg : NEG_SLOPE * lg;
                float e = __expf(lg);
                ex[q] = (base + q < cnt) ? e : 0.f;
                den += ex[q];
            }
            #pragma unroll
            for (int q = 0; q < 8; q++) {
                #pragma unroll
                for (int k = 0; k < 8; k++)
                    acc[k] = fmaf(ex[q], (float)hv[q][k], acc[k]);
            }
            #pragma unroll
            for (int q = 0; q < 8; q++) { sA[q] = sB[q]; avA[q] = avB[q]; }
        }
    }

    float inv = 1.f / (den + 1e-16f);
    float v[8];
    #pragma unroll
    for (int k = 0; k < 8; k++) v[k] = acc[k] * inv;

    if (MODE == 2) {
        float vs[8];
        #pragma unroll
        for (int k = 0; k < 8; k++) vs[k] = v[k];
        #pragma unroll
        for (int k2 = 1; k2 < 4; k2++) {
            #pragma unroll
            for (int k = 0; k < 8; k++)
                vs[k] += __shfl(v[k], lane + 5 * k2, 64);
        }
        if (nact && l < 5) {
            float b[8];
            *(float4*)&b[0] = *(const float4*)(bias + l * 8);
            *(float4*)&b[4] = *(const float4*)(bias + l * 8 + 4);
            float o[8];
            #pragma unroll
            for (int k = 0; k < 8; k++) o[k] = vs[k] * 0.25f + b[k];
            *(float4*)(outf + (size_t)node * C + l * 8)     = make_float4(o[0], o[1], o[2], o[3]);
            *(float4*)(outf + (size_t)node * C + l * 8 + 4) = make_float4(o[4], o[5], o[6], o[7]);
        }
    } else {
        if (lact) {
            float b[8];
            *(float4*)&b[0] = *(const float4*)(bias + l * 8);
            *(float4*)&b[4] = *(const float4*)(bias + l * 8 + 4);
            float o[8];
            #pragma unroll
            for (int k = 0; k < 8; k++) o[k] = v[k] + b[k];
            if (MODE == 1) {
                size_t ridx = (size_t)node * HC + l * 8;
                half8 r_h = *(const half8*)(rh + ridx);
                #pragma unroll
                for (int k = 0; k < 8; k++) o[k] += (float)r_h[k];
            }
            #pragma unroll
            for (int k = 0; k < 8; k++) o[k] = (o[k] > 0.f) ? o[k] : expm1f(o[k]);
            half8 hv8;
            #pragma unroll
            for (int k = 0; k < 8; k++) hv8[k] = (_Float16)o[k];
            *(half8*)(oh + (size_t)node * HC + l * 8) = hv8;
        }
    }
}

// ---------------------------------------------------------------- launch
extern "C" void kernel_launch(void* const* d_in, const int* in_sizes, int n_in,
                              void* d_out, int out_size, void* d_ws, size_t ws_size,
                              hipStream_t stream) {
    const float* x   = (const float*)d_in[0];
    const int*   ei  = (const int*)d_in[1];
    const float* W1  = (const float*)d_in[2];
    const float* a1s = (const float*)d_in[3];
    const float* a1d = (const float*)d_in[4];
    const float* b1  = (const float*)d_in[5];
    const float* W2  = (const float*)d_in[6];
    const float* a2s = (const float*)d_in[7];
    const float* a2d = (const float*)d_in[8];
    const float* b2  = (const float*)d_in[9];
    const float* W3  = (const float*)d_in[10];
    const float* a3s = (const float*)d_in[11];
    const float* a3d = (const float*)d_in[12];
    const float* b3  = (const float*)d_in[13];
    float* out = (float*)d_out;

    int N = in_sizes[0] / 128;
    int E = in_sizes[1] / 2;

    char* ws = (char*)d_ws;
    size_t off = 0;
    auto alloc = [&](size_t bytes) -> void* {
        void* p = ws + off;
        off += (bytes + 255) & ~(size_t)255;
        return p;
    };
    _Float16* hhalf = (_Float16*)alloc((size_t)N * 256 * 2);
    _Float16* pA    = (_Float16*)alloc((size_t)N * 256 * 2);   // x / x2 fp16
    _Float16* pB    = (_Float16*)alloc((size_t)N * 256 * 2);   // x1 fp16
    float*    als   = (float*)alloc((size_t)N * 4 * 4);
    float*    ald   = (float*)alloc((size_t)N * 4 * 4);
    _Float16* bt1h  = (_Float16*)alloc(256 * 128 * 2);
    _Float16* bt1l  = (_Float16*)alloc(256 * 128 * 2);
    _Float16* bt2h  = (_Float16*)alloc(256 * 256 * 2);
    _Float16* bt2l  = (_Float16*)alloc(256 * 256 * 2);
    _Float16* bt3h  = (_Float16*)alloc(256 * 256 * 2);
    _Float16* bt3l  = (_Float16*)alloc(256 * 256 * 2);
    int* deg     = (int*)alloc((size_t)N * 4);
    int* row_off = (int*)alloc((size_t)(N + 1) * 4);
    int* cursor  = (int*)alloc((size_t)N * 4);
    int* csr     = (int*)alloc((size_t)(E + N) * 4);
    int* bsums   = (int*)alloc(1024 * 4);

    int tot = E + N;
    int nb = (N + 1023) / 1024;
    int n4 = N * 128 / 4;
    int nbSplit = (n4 + 255) / 256;
    int wtot = 256 * 128 + 2 * 256 * 256;
    int nbWt = (wtot + 255) / 256;
    int nbDeg = (tot + 255) / 256;

    hipMemsetAsync(deg, 0, (size_t)N * 4, stream);
    prep_kernel<<<nbSplit + nbWt + nbDeg, 256, 0, stream>>>(
        x, pA, n4, W1, W2, W3,
        bt1h, bt1l, bt2h, bt2l, bt3h, bt3l,
        ei, E, N, deg, nbSplit, nbWt);
    scan_block<<<nb, 1024, 0, stream>>>(deg, row_off, bsums, N);
    scan_sums<<<1, 64, 0, stream>>>(bsums, nb, row_off, N);
    scan_add<<<nb, 1024, 0, stream>>>(row_off, bsums, cursor, N);
    scatter_kernel<<<(tot + 255) / 256, 256, 0, stream>>>(ei, E, N, cursor, csr);

    int nodeBlocks4 = (N + 3) / 4;   // coef: 4 nodes/block
    int pairs = (N + 1) / 2;
    int aggBlocks = (pairs + 3) / 4; // agg: 4 waves/block, 2 nodes/wave
    dim3 blk(256);
    dim3 ggrid((N + 63) / 64);       // GEMM: BM=64, BN=256 full width

    // layer 1: h = x @ W1 (K=128); coef fused
    gemm_mfma<4, true><<<ggrid, blk, 0, stream>>>(pA, bt1h, bt1l, hhalf,
                                                  a1s, a1d, als, ald, N, 256);
    agg_kernel<64, 0><<<aggBlocks, blk, 0, stream>>>((const __half*)hhalf, als, ald,
        row_off, csr, b1, nullptr, nullptr, pB, N);

    // layer 2: h = x1 @ W2 (K=256); coef fused; residual = x1 (fp16)
    gemm_mfma<8, true><<<ggrid, blk, 0, stream>>>(pB, bt2h, bt2l, hhalf,
                                                  a2s, a2d, als, ald, N, 256);
    agg_kernel<64, 1><<<aggBlocks, blk, 0, stream>>>((const __half*)hhalf, als, ald,
        row_off, csr, b2, pB, nullptr, pA, N);

    // layer 3: h = x2 @ W3 (K=256, N=160); coef from fp16 shadow
    gemm_mfma<8, false><<<ggrid, blk, 0, stream>>>(pA, bt3h, bt3l, hhalf,
                                                   nullptr, nullptr, nullptr, nullptr, N, 160);
    coef_kernel<40><<<nodeBlocks4, blk, 0, stream>>>(hhalf, a3s, a3d, als, ald, N);
    agg_kernel<40, 2><<<aggBlocks, blk, 0, stream>>>((const __half*)hhalf, als, ald,
        row_off, csr, b3, nullptr, out, nullptr, N);
}

// Round 12
// 433.105 us; speedup vs baseline: 1.8668x; 1.0028x over previous
//
#include <hip/hip_runtime.h>
#include <hip/hip_bf16.h>
#include <hip/hip_fp16.h>
#include <math.h>

#define NEG_SLOPE 0.2f

typedef _Float16 half8 __attribute__((ext_vector_type(8)));
typedef _Float16 half4 __attribute__((ext_vector_type(4)));
typedef float f32x4 __attribute__((ext_vector_type(4)));

// ---------------------------------------------------------------- fused prep
__global__ __launch_bounds__(256) void prep_kernel(
        const float* __restrict__ x, _Float16* __restrict__ xh, int n4,
        const float* __restrict__ W1, const float* __restrict__ W2,
        const float* __restrict__ W3,
        _Float16* __restrict__ b1h, _Float16* __restrict__ b1l,
        _Float16* __restrict__ b2h, _Float16* __restrict__ b2l,
        _Float16* __restrict__ b3h, _Float16* __restrict__ b3l,
        const int* __restrict__ ei, int E, int n, int* __restrict__ deg,
        int nbSplit, int nbWt) {
    int b = blockIdx.x;
    if (b < nbSplit) {
        int i = b * 256 + threadIdx.x;
        if (i >= n4) return;
        float4 v = ((const float4*)x)[i];
        half4 h;
        h.x = (_Float16)v.x; h.y = (_Float16)v.y;
        h.z = (_Float16)v.z; h.w = (_Float16)v.w;
        ((half4*)xh)[i] = h;
    } else if (b < nbSplit + nbWt) {
        int idx = (b - nbSplit) * 256 + threadIdx.x;
        const float* W; _Float16 *bh, *bl; int K, N, li;
        if (idx < 256 * 128) {
            W = W1; bh = b1h; bl = b1l; K = 128; N = 256; li = idx;
        } else if (idx < 256 * 128 + 256 * 256) {
            W = W2; bh = b2h; bl = b2l; K = 256; N = 256; li = idx - 256 * 128;
        } else if (idx < 256 * 128 + 2 * 256 * 256) {
            W = W3; bh = b3h; bl = b3l; K = 256; N = 160; li = idx - 256 * 128 - 256 * 256;
        } else return;
        int nn = li / K, k = li % K;
        float v = (nn < N) ? W[(size_t)k * N + nn] : 0.f;
        _Float16 h = (_Float16)v;
        bh[li] = h;
        bl[li] = (_Float16)(v - (float)h);
    } else {
        int e = (b - nbSplit - nbWt) * 256 + threadIdx.x;
        int tot = E + n;
        if (e >= tot) return;
        int d = (e < E) ? ei[E + e] : (e - E);
        atomicAdd(&deg[d], 1);
    }
}

// ---------------------------------------------------------------- scan / scatter
__global__ __launch_bounds__(1024) void scan_block(const int* __restrict__ deg,
                                                   int* __restrict__ row_off,
                                                   int* __restrict__ bsums, int n) {
    __shared__ int tmp[1024];
    int t = threadIdx.x;
    int idx = blockIdx.x * 1024 + t;
    int v = (idx < n) ? deg[idx] : 0;
    tmp[t] = v;
    __syncthreads();
    #pragma unroll
    for (int off = 1; off < 1024; off <<= 1) {
        int x = (t >= off) ? tmp[t - off] : 0;
        __syncthreads();
        tmp[t] += x;
        __syncthreads();
    }
    if (idx < n) row_off[idx] = tmp[t] - v;
    if (t == 1023) bsums[blockIdx.x] = tmp[1023];
}

// inline-lookback scan_add: carry = sum of preceding block sums (nb <= ~49)
__global__ __launch_bounds__(1024) void scan_add(int* __restrict__ row_off,
                                                 const int* __restrict__ bsums,
                                                 int* __restrict__ cursor,
                                                 int n, int total) {
    __shared__ int carry_s;
    int b = blockIdx.x;
    if (threadIdx.x == 0) {
        int c = 0;
        for (int i = 0; i < b; i++) c += bsums[i];
        carry_s = c;
        if (b == 0) row_off[n] = total;
    }
    __syncthreads();
    int idx = b * 1024 + threadIdx.x;
    if (idx < n) {
        int v = row_off[idx] + carry_s;
        row_off[idx] = v;
        cursor[idx] = v;
    }
}

__global__ void scatter_kernel(const int* __restrict__ ei, int E, int n,
                               int* __restrict__ cursor, int* __restrict__ csr_src) {
    int e = blockIdx.x * 256 + threadIdx.x;
    int tot = E + n;
    if (e >= tot) return;
    int s, d;
    if (e < E) { s = ei[e]; d = ei[E + e]; } else { s = d = e - E; }
    int pos = atomicAdd(&cursor[d], 1);
    csr_src[pos] = s;
}

// ---------------------------------------------------------------- MFMA GEMM
// A fp16 single-plane; B split hi/lo -> 2-term MFMA. BM=64, BN=256 (A read
// once), BK=32, 4 waves (wave = 64-col panel = head for C=64).
// A staged via global_load_lds width=16: linear LDS dest (slot = tid),
// inverse-swizzled per-lane global source, swizzled ds_read (rule #21).
template <int NK, bool FUSE>
__global__ __launch_bounds__(256) void gemm_mfma(const _Float16* __restrict__ A16,
                                                 const _Float16* __restrict__ Bthi,
                                                 const _Float16* __restrict__ Btlo,
                                                 _Float16* __restrict__ Ch,
                                                 const float* __restrict__ a_src,
                                                 const float* __restrict__ a_dst,
                                                 float* __restrict__ als,
                                                 float* __restrict__ ald,
                                                 int M, int N) {
    constexpr int K = NK * 32;
    __shared__ _Float16 Ah[2][2048];   // [dbuf][64 rows x 32 halves] = 4KB each
    int t = threadIdx.x;
    int wave = t >> 6, lane = t & 63;
    int row0 = blockIdx.x * 64;

    // read-side swizzled offset (halves) for (row m, 16B-granule g0)
    auto lds_off = [](int m, int g0) -> int {
        int P = m >> 1;
        int gp = ((m & 1) << 2) | g0;
        return P * 64 + ((gp ^ (P & 7)) << 3);
    };

    // write side: thread t's gload_lds lands at linear slot t (16B units).
    // Inverse swizzle: slot t holds granule (m = 2P + (gp>>2), g0 = gp&3),
    // P = t>>3, gp = (t&7) ^ (P&7).
    int Pw = t >> 3;
    int gpw = (t & 7) ^ (Pw & 7);
    int m_w = 2 * Pw + (gpw >> 2);
    int g0w = gpw & 3;
    int grow = row0 + m_w;
    if (grow >= M) grow = M - 1;          // clamp: garbage rows never stored
    const _Float16* srcp = A16 + (size_t)grow * K + g0w * 8;

    auto stage = [&](int buf, int k0) {
        __builtin_amdgcn_global_load_lds(
            (const __attribute__((address_space(1))) void*)(srcp + k0),
            (__attribute__((address_space(3))) void*)(&Ah[buf][(size_t)wave * 512]),
            16, 0, 0);
    };

    const _Float16* bhp[4];
    const _Float16* blp[4];
    #pragma unroll
    for (int nf = 0; nf < 4; nf++) {
        int n = wave * 64 + nf * 16 + (lane & 15);
        bhp[nf] = Bthi + (size_t)n * K + (lane >> 4) * 8;
        blp[nf] = Btlo + (size_t)n * K + (lane >> 4) * 8;
    }

    f32x4 acc[4][4];
    #pragma unroll
    for (int i = 0; i < 4; i++)
        #pragma unroll
        for (int j = 0; j < 4; j++)
            acc[i][j] = (f32x4)0.f;

    stage(0, 0);
    __syncthreads();                       // vmcnt drained -> buf0 ready

    #pragma unroll
    for (int kt = 0; kt < NK; kt++) {
        int cur = kt & 1;
        if (kt + 1 < NK) stage(cur ^ 1, (kt + 1) * 32);   // async into other buf

        int k0 = kt * 32;
        half8 bh[4], bl[4];
        #pragma unroll
        for (int nf = 0; nf < 4; nf++) {
            bh[nf] = *(const half8*)(bhp[nf] + k0);
            bl[nf] = *(const half8*)(blp[nf] + k0);
        }
        half8 ah[4];
        #pragma unroll
        for (int mf = 0; mf < 4; mf++) {
            int m = mf * 16 + (lane & 15);
            int off = lds_off(m, lane >> 4);
            ah[mf] = *(half8*)(&Ah[cur][off]);
        }
        #pragma unroll
        for (int mf = 0; mf < 4; mf++)
            #pragma unroll
            for (int nf = 0; nf < 4; nf++) {
                acc[mf][nf] = __builtin_amdgcn_mfma_f32_16x16x32_f16(
                    ah[mf], bh[nf], acc[mf][nf], 0, 0, 0);
                acc[mf][nf] = __builtin_amdgcn_mfma_f32_16x16x32_f16(
                    ah[mf], bl[nf], acc[mf][nf], 0, 0, 0);
            }
        if (kt + 1 < NK) __syncthreads();  // stage complete + readers done
    }

    // fp16 store: C/D layout col = lane&15, row = (lane>>4)*4 + q
    #pragma unroll
    for (int mf = 0; mf < 4; mf++)
        #pragma unroll
        for (int nf = 0; nf < 4; nf++) {
            int col = wave * 64 + nf * 16 + (lane & 15);
            if (col >= N) continue;
            #pragma unroll
            for (int q = 0; q < 4; q++) {
                int row = row0 + mf * 16 + (lane >> 4) * 4 + q;
                if (row < M)
                    Ch[(size_t)row * N + col] = (_Float16)acc[mf][nf][q];
            }
        }

    // fused attention coefficients (C=64 layers): head = wave
    if (FUSE) {
        float asv[4], adv[4];
        #pragma unroll
        for (int nf = 0; nf < 4; nf++) {
            int cih = nf * 16 + (lane & 15);
            asv[nf] = a_src[wave * 64 + cih];
            adv[nf] = a_dst[wave * 64 + cih];
        }
        #pragma unroll
        for (int mf = 0; mf < 4; mf++)
            #pragma unroll
            for (int q = 0; q < 4; q++) {
                float ss = 0.f, sd = 0.f;
                #pragma unroll
                for (int nf = 0; nf < 4; nf++) {
                    float v = acc[mf][nf][q];
                    ss = fmaf(v, asv[nf], ss);
                    sd = fmaf(v, adv[nf], sd);
                }
                #pragma unroll
                for (int off = 8; off >= 1; off >>= 1) {
                    ss += __shfl_xor(ss, off, 64);
                    sd += __shfl_xor(sd, off, 64);
                }
                int row = row0 + mf * 16 + (lane >> 4) * 4 + q;
                if ((lane & 15) == 0 && row < M) {
                    als[row * 4 + wave] = ss;
                    ald[row * 4 + wave] = sd;
                }
            }
    }
}

// ---------------------------------------------------------------- attention coefs (layer 3, fp16 h)
template <int C>
__global__ __launch_bounds__(256) void coef_kernel(const _Float16* __restrict__ h,
                                                   const float* __restrict__ a_src,
                                                   const float* __restrict__ a_dst,
                                                   float* __restrict__ als,
                                                   float* __restrict__ ald, int n) {
    int wave = threadIdx.x >> 6;
    int lane = threadIdx.x & 63;
    int node = blockIdx.x * 4 + wave;
    if (node >= n) return;
    const _Float16* hr = h + (size_t)node * (4 * C);
    float ps[4], pd[4];
    #pragma unroll
    for (int hh = 0; hh < 4; hh++) {
        float hv = (lane < C) ? (float)hr[hh * C + lane] : 0.f;
        float as_ = (lane < C) ? a_src[hh * C + lane] : 0.f;
        float ad_ = (lane < C) ? a_dst[hh * C + lane] : 0.f;
        ps[hh] = hv * as_;
        pd[hh] = hv * ad_;
    }
    #pragma unroll
    for (int off = 32; off >= 1; off >>= 1) {
        #pragma unroll
        for (int hh = 0; hh < 4; hh++) {
            ps[hh] += __shfl_xor(ps[hh], off, 64);
            pd[hh] += __shfl_xor(pd[hh], off, 64);
        }
    }
    if (lane == 0) {
        #pragma unroll
        for (int hh = 0; hh < 4; hh++) {
            als[node * 4 + hh] = ps[hh];
            ald[node * 4 + hh] = pd[hh];
        }
    }
}

// ---------------------------------------------------------------- fused softmax + aggregation
template <int C, int MODE>
__global__ __launch_bounds__(256) void agg_kernel(const __half* __restrict__ hhp,
                                                  const float* __restrict__ als,
                                                  const float* __restrict__ ald,
                                                  const int* __restrict__ row_off,
                                                  const int* __restrict__ csr_src,
                                                  const float* __restrict__ bias,
                                                  const _Float16* __restrict__ rh,
                                                  float* __restrict__ outf,
                                                  _Float16* __restrict__ oh, int n) {
    constexpr int HC = 4 * C;          // halves per row (256 or 160)
    constexpr int LPN = HC / 8;        // lanes per node (32 or 20)
    constexpr int LPH = C / 8;         // lanes per head (8 or 5)
    const _Float16* hh = (const _Float16*)hhp;

    int t = threadIdx.x;
    int wave = t >> 6, lane = t & 63;
    int l = lane & 31;
    int node = (blockIdx.x * 4 + wave) * 2 + (lane >> 5);
    bool nact = node < n;
    bool lact = nact && (l < LPN);
    int g = (l < LPN) ? (l / LPH) : 0;

    int rs = 0, cnt = 0;
    if (lact) {
        rs = row_off[node];
        cnt = row_off[node + 1] - rs;
    }
    float aldg = lact ? ald[node * 4 + g] : 0.f;

    float acc[8] = {};
    float den = 0.f;

    if (cnt > 0) {
        int sA[8];
        float avA[8];
        #pragma unroll
        for (int q = 0; q < 8; q++) {
            int idx = q < cnt ? q : cnt - 1;
            sA[q] = csr_src[rs + idx];
        }
        #pragma unroll
        for (int q = 0; q < 8; q++) avA[q] = als[sA[q] * 4 + g];

        for (int base = 0; base < cnt; base += 8) {
            half8 hv[8];
            #pragma unroll
            for (int q = 0; q < 8; q++)
                hv[q] = *(const half8*)(hh + (size_t)sA[q] * HC + l * 8);

            int sB[8];
            float avB[8];
            if (base + 8 < cnt) {
                #pragma unroll
                for (int q = 0; q < 8; q++) {
                    int idx = base + 8 + q; if (idx >= cnt) idx = cnt - 1;
                    sB[q] = csr_src[rs + idx];
                }
                #pragma unroll
                for (int q = 0; q < 8; q++) avB[q] = als[sB[q] * 4 + g];
            }

            float ex[8];
            #pragma unroll
            for (int q = 0; q < 8; q++) {
                float lg = avA[q] + aldg;
                lg = (lg > 0.f) ? lg : NEG_SLOPE * lg;
                float e = __expf(lg);
                ex[q] = (base + q < cnt) ? e : 0.f;
                den += ex[q];
            }
            #pragma unroll
            for (int q = 0; q < 8; q++) {
                #pragma unroll
                for (int k = 0; k < 8; k++)
                    acc[k] = fmaf(ex[q], (float)hv[q][k], acc[k]);
            }
            #pragma unroll
            for (int q = 0; q < 8; q++) { sA[q] = sB[q]; avA[q] = avB[q]; }
        }
    }

    float inv = 1.f / (den + 1e-16f);
    float v[8];
    #pragma unroll
    for (int k = 0; k < 8; k++) v[k] = acc[k] * inv;

    if (MODE == 2) {
        float vs[8];
        #pragma unroll
        for (int k = 0; k < 8; k++) vs[k] = v[k];
        #pragma unroll
        for (int k2 = 1; k2 < 4; k2++) {
            #pragma unroll
            for (int k = 0; k < 8; k++)
                vs[k] += __shfl(v[k], lane + 5 * k2, 64);
        }
        if (nact && l < 5) {
            float b[8];
            *(float4*)&b[0] = *(const float4*)(bias + l * 8);
            *(float4*)&b[4] = *(const float4*)(bias + l * 8 + 4);
            float o[8];
            #pragma unroll
            for (int k = 0; k < 8; k++) o[k] = vs[k] * 0.25f + b[k];
            *(float4*)(outf + (size_t)node * C + l * 8)     = make_float4(o[0], o[1], o[2], o[3]);
            *(float4*)(outf + (size_t)node * C + l * 8 + 4) = make_float4(o[4], o[5], o[6], o[7]);
        }
    } else {
        if (lact) {
            float b[8];
            *(float4*)&b[0] = *(const float4*)(bias + l * 8);
            *(float4*)&b[4] = *(const float4*)(bias + l * 8 + 4);
            float o[8];
            #pragma unroll
            for (int k = 0; k < 8; k++) o[k] = v[k] + b[k];
            if (MODE == 1) {
                size_t ridx = (size_t)node * HC + l * 8;
                half8 r_h = *(const half8*)(rh + ridx);
                #pragma unroll
                for (int k = 0; k < 8; k++) o[k] += (float)r_h[k];
            }
            #pragma unroll
            for (int k = 0; k < 8; k++) o[k] = (o[k] > 0.f) ? o[k] : expm1f(o[k]);
            half8 hv8;
            #pragma unroll
            for (int k = 0; k < 8; k++) hv8[k] = (_Float16)o[k];
            *(half8*)(oh + (size_t)node * HC + l * 8) = hv8;
        }
    }
}

// ---------------------------------------------------------------- launch
extern "C" void kernel_launch(void* const* d_in, const int* in_sizes, int n_in,
                              void* d_out, int out_size, void* d_ws, size_t ws_size,
                              hipStream_t stream) {
    const float* x   = (const float*)d_in[0];
    const int*   ei  = (const int*)d_in[1];
    const float* W1  = (const float*)d_in[2];
    const float* a1s = (const float*)d_in[3];
    const float* a1d = (const float*)d_in[4];
    const float* b1  = (const float*)d_in[5];
    const float* W2  = (const float*)d_in[6];
    const float* a2s = (const float*)d_in[7];
    const float* a2d = (const float*)d_in[8];
    const float* b2  = (const float*)d_in[9];
    const float* W3  = (const float*)d_in[10];
    const float* a3s = (const float*)d_in[11];
    const float* a3d = (const float*)d_in[12];
    const float* b3  = (const float*)d_in[13];
    float* out = (float*)d_out;

    int N = in_sizes[0] / 128;
    int E = in_sizes[1] / 2;

    char* ws = (char*)d_ws;
    size_t off = 0;
    auto alloc = [&](size_t bytes) -> void* {
        void* p = ws + off;
        off += (bytes + 255) & ~(size_t)255;
        return p;
    };
    _Float16* hhalf = (_Float16*)alloc((size_t)N * 256 * 2);
    _Float16* pA    = (_Float16*)alloc((size_t)N * 256 * 2);   // x / x2 fp16
    _Float16* pB    = (_Float16*)alloc((size_t)N * 256 * 2);   // x1 fp16
    float*    als   = (float*)alloc((size_t)N * 4 * 4);
    float*    ald   = (float*)alloc((size_t)N * 4 * 4);
    _Float16* bt1h  = (_Float16*)alloc(256 * 128 * 2);
    _Float16* bt1l  = (_Float16*)alloc(256 * 128 * 2);
    _Float16* bt2h  = (_Float16*)alloc(256 * 256 * 2);
    _Float16* bt2l  = (_Float16*)alloc(256 * 256 * 2);
    _Float16* bt3h  = (_Float16*)alloc(256 * 256 * 2);
    _Float16* bt3l  = (_Float16*)alloc(256 * 256 * 2);
    int* deg     = (int*)alloc((size_t)N * 4);
    int* row_off = (int*)alloc((size_t)(N + 1) * 4);
    int* cursor  = (int*)alloc((size_t)N * 4);
    int* csr     = (int*)alloc((size_t)(E + N) * 4);
    int* bsums   = (int*)alloc(1024 * 4);

    int tot = E + N;
    int nb = (N + 1023) / 1024;
    int n4 = N * 128 / 4;
    int nbSplit = (n4 + 255) / 256;
    int wtot = 256 * 128 + 2 * 256 * 256;
    int nbWt = (wtot + 255) / 256;
    int nbDeg = (tot + 255) / 256;

    hipMemsetAsync(deg, 0, (size_t)N * 4, stream);
    prep_kernel<<<nbSplit + nbWt + nbDeg, 256, 0, stream>>>(
        x, pA, n4, W1, W2, W3,
        bt1h, bt1l, bt2h, bt2l, bt3h, bt3l,
        ei, E, N, deg, nbSplit, nbWt);
    scan_block<<<nb, 1024, 0, stream>>>(deg, row_off, bsums, N);
    scan_add<<<nb, 1024, 0, stream>>>(row_off, bsums, cursor, N, tot);
    scatter_kernel<<<(tot + 255) / 256, 256, 0, stream>>>(ei, E, N, cursor, csr);

    int nodeBlocks4 = (N + 3) / 4;   // coef: 4 nodes/block
    int pairs = (N + 1) / 2;
    int aggBlocks = (pairs + 3) / 4; // agg: 4 waves/block, 2 nodes/wave
    dim3 blk(256);
    dim3 ggrid((N + 63) / 64);       // GEMM: BM=64, BN=256 full width

    // layer 1: h = x @ W1 (K=128); coef fused
    gemm_mfma<4, true><<<ggrid, blk, 0, stream>>>(pA, bt1h, bt1l, hhalf,
                                                  a1s, a1d, als, ald, N, 256);
    agg_kernel<64, 0><<<aggBlocks, blk, 0, stream>>>((const __half*)hhalf, als, ald,
        row_off, csr, b1, nullptr, nullptr, pB, N);

    // layer 2: h = x1 @ W2 (K=256); coef fused; residual = x1 (fp16)
    gemm_mfma<8, true><<<ggrid, blk, 0, stream>>>(pB, bt2h, bt2l, hhalf,
                                                  a2s, a2d, als, ald, N, 256);
    agg_kernel<64, 1><<<aggBlocks, blk, 0, stream>>>((const __half*)hhalf, als, ald,
        row_off, csr, b2, pB, nullptr, pA, N);

    // layer 3: h = x2 @ W3 (K=256, N=160); coef from fp16 shadow
    gemm_mfma<8, false><<<ggrid, blk, 0, stream>>>(pA, bt3h, bt3l, hhalf,
                                                   nullptr, nullptr, nullptr, nullptr, N, 160);
    coef_kernel<40><<<nodeBlocks4, blk, 0, stream>>>(hhalf, a3s, a3d, als, ald, N);
    agg_kernel<40, 2><<<aggBlocks, blk, 0, stream>>>((const __half*)hhalf, als, ald,
        row_off, csr, b3, nullptr, out, nullptr, N);
}